// Round 5
// baseline (3708.653 us; speedup 1.0000x reference)
//
#include <hip/hip_runtime.h>

// ---------------------------------------------------------------------------
// FeatureMapApproximator: VMamba-style block. B=1, C=512, H=W=64, L=4096,
// d_inner=1024, K=4 dirs, N=16 states, dt_rank=32.
// All inputs f32 (per reference dtypes), intermediates f32 in d_ws (~189 MB
// with region reuse), output f32.
// ---------------------------------------------------------------------------

#define NT 4096   // pixels (and GEMM N)

__device__ __forceinline__ float geluf(float x){ return 0.5f*x*(1.f+erff(x*0.70710678118654752f)); }
__device__ __forceinline__ float sigmf(float x){ return 1.f/(1.f+__expf(-x)); }
__device__ __forceinline__ float softplusf(float x){ return (x>20.f)? x : __logf(1.f+__expf(x)); }

// ---------------------------------------------------------------------------
// Generic tiled GEMM: out[m][n] = epi( sum_k A[m][k]*B[k][n] + bias[m] )
// Tiles: TM=64, TN=64, TK=32, 256 threads, 4x4 acc per thread.
// BMODE 0: B f32 channel-major (K rows of length 4096); rev => n -> 4095-n,
//          shuf => channel-shuffle row remap.
// BMODE 1: B = f32 concat(feat, lat) channel-major (K=1024, split at 512).
// BMODE 2: B f32 NHWC: B[k][n] = Bf[n*ldb + k].
// BMODE 3: implicit im2col 3x3 pad1 from Bf (1024,4096); k = c*9+ky*3+kx.
// EPI 0 none | 1 gelu | 2 softplus | 4 +f32 res | 5 concat*sigmoid
// TRANSW: write out[n*64+m] (requires M==64, EPI 0, no bias) via LDS bounce.
// ---------------------------------------------------------------------------
template<int BMODE, int EPI, bool TRANSW>
__launch_bounds__(256)
__global__ void k_gemm(int M, int K, int lda, int ldb,
    const float* __restrict__ A, const float* __restrict__ bias,
    const float* __restrict__ Bf, const float* __restrict__ Bc0,
    const float* __restrict__ Bc1, int rev, int shuf,
    const float* __restrict__ resf, float* __restrict__ out)
{
  __shared__ float smem[4352];           // 2 x [32][68] (or 64x68 for TRANSW)
  float* As = smem;
  float* Bs = smem + 2176;
  const int t  = threadIdx.x;
  const int n0 = blockIdx.x*64, m0 = blockIdx.y*64;
  float acc[4][4] = {};

  for (int k0=0; k0<K; k0+=32){
    __syncthreads();
    { // stage A (f32 weights, row-major M x K)
      int m = t>>2, kk0 = (t&3)*8;
      float av[8] = {0,0,0,0,0,0,0,0};
      if (m0+m < M){
        const float* pa = A + (size_t)(m0+m)*lda + k0 + kk0;
        float4 a0 = *(const float4*)pa; float4 a1 = *(const float4*)(pa+4);
        av[0]=a0.x; av[1]=a0.y; av[2]=a0.z; av[3]=a0.w;
        av[4]=a1.x; av[5]=a1.y; av[6]=a1.z; av[7]=a1.w;
      }
      #pragma unroll
      for (int j=0;j<8;j++) As[(kk0+j)*68 + m] = av[j];
    }
    if (BMODE==2){
      int n = t>>2, kk0 = (t&3)*8;
      const float* p = Bf + (size_t)(n0+n)*ldb + k0 + kk0;
      float4 x0 = *(const float4*)p; float4 x1 = *(const float4*)(p+4);
      Bs[(kk0+0)*68+n]=x0.x; Bs[(kk0+1)*68+n]=x0.y; Bs[(kk0+2)*68+n]=x0.z; Bs[(kk0+3)*68+n]=x0.w;
      Bs[(kk0+4)*68+n]=x1.x; Bs[(kk0+5)*68+n]=x1.y; Bs[(kk0+6)*68+n]=x1.z; Bs[(kk0+7)*68+n]=x1.w;
    } else {
      int kk = t>>3, n8 = (t&7)*8;
      float bv[8];
      if (BMODE==0){
        int r = k0+kk; if (shuf) r = (r&7)*64 + (r>>3);
        const float* p = Bf + (size_t)r*NT;
        if (!rev){
          float4 x0 = *(const float4*)(p + n0+n8); float4 x1 = *(const float4*)(p + n0+n8+4);
          bv[0]=x0.x;bv[1]=x0.y;bv[2]=x0.z;bv[3]=x0.w;bv[4]=x1.x;bv[5]=x1.y;bv[6]=x1.z;bv[7]=x1.w;
        } else {
          const float* q = p + (4088 - n0 - n8);
          float4 x0 = *(const float4*)q; float4 x1 = *(const float4*)(q+4);
          bv[0]=x1.w;bv[1]=x1.z;bv[2]=x1.y;bv[3]=x1.x;bv[4]=x0.w;bv[5]=x0.z;bv[6]=x0.y;bv[7]=x0.x;
        }
      } else if (BMODE==1){
        int c = k0+kk;
        const float* p = (c<512) ? (Bc0 + (size_t)c*NT) : (Bc1 + (size_t)(c-512)*NT);
        float4 x0 = *(const float4*)(p + n0+n8); float4 x1 = *(const float4*)(p + n0+n8+4);
        bv[0]=x0.x;bv[1]=x0.y;bv[2]=x0.z;bv[3]=x0.w;bv[4]=x1.x;bv[5]=x1.y;bv[6]=x1.z;bv[7]=x1.w;
      } else { // BMODE==3
        int k = k0+kk; int c = k/9; int t9 = k - c*9; int qy = t9/3;
        int dy = qy-1, dx = t9 - qy*3 - 1;
        int y = (n0>>6) + dy;               // n-tile is one image row
        bool yok = (y>=0)&&(y<64);
        const float* p = Bf + (size_t)c*NT + y*64;
        #pragma unroll
        for (int j=0;j<8;j++){
          int x = n8 + j + dx;
          bv[j] = (yok && x>=0 && x<64) ? p[x] : 0.f;
        }
      }
      *(float4*)&Bs[kk*68 + n8]   = make_float4(bv[0],bv[1],bv[2],bv[3]);
      *(float4*)&Bs[kk*68 + n8+4] = make_float4(bv[4],bv[5],bv[6],bv[7]);
    }
    __syncthreads();
    int ti = t>>4, tj = t&15;
    #pragma unroll
    for (int kk=0; kk<32; kk++){
      float4 a4 = *(const float4*)&As[kk*68 + ti*4];
      float4 b4 = *(const float4*)&Bs[kk*68 + tj*4];
      float aa[4] = {a4.x,a4.y,a4.z,a4.w};
      float bb[4] = {b4.x,b4.y,b4.z,b4.w};
      #pragma unroll
      for (int i=0;i<4;i++)
        #pragma unroll
        for (int j=0;j<4;j++) acc[i][j] += aa[i]*bb[j];
    }
  }

  int ti = t>>4, tj = t&15;
  if (!TRANSW){
    #pragma unroll
    for (int i=0;i<4;i++){
      int m = m0 + ti*4 + i;
      if (m >= M) continue;
      float bi = bias ? bias[m] : 0.f;
      float o4[4];
      #pragma unroll
      for (int j=0;j<4;j++){
        int n = n0 + tj*4 + j;
        float v = acc[i][j] + bi;
        if (EPI==1) v = geluf(v);
        else if (EPI==2) v = softplusf(v);
        else if (EPI==4) v = v + resf[(size_t)m*NT + n];
        else if (EPI==5){
          float cv = (m<512)? Bc0[(size_t)m*NT+n] : Bc1[(size_t)(m-512)*NT+n];
          v = cv * sigmf(v);
        }
        o4[j] = v;
      }
      *(float4*)&out[(size_t)m*NT + n0 + tj*4] = make_float4(o4[0],o4[1],o4[2],o4[3]);
    }
  } else {
    __syncthreads();
    #pragma unroll
    for (int i=0;i<4;i++)
      #pragma unroll
      for (int j=0;j<4;j++)
        smem[(tj*4+j)*68 + (ti*4+i)] = acc[i][j];
    __syncthreads();
    int nl = t>>2, c0 = (t&3)*16;
    #pragma unroll
    for (int g4=0; g4<4; g4++){
      float4 v = *(const float4*)&smem[nl*68 + c0 + g4*4];
      *(float4*)&out[(size_t)(n0+nl)*64 + c0 + g4*4] = v;
    }
  }
}

// ---------------------------------------------------------------------------
// Depthwise 3x3 conv (dilated), optional SiLU. grid = C*16, block 256.
template<int DIL, int ACT>
__global__ void k_dwconv(const float* __restrict__ in, const float* __restrict__ w,
                         const float* __restrict__ b, float* __restrict__ out){
  int bid = blockIdx.x;
  int c = bid >> 4, yb = bid & 15;
  int t = threadIdx.x;
  int y = yb*4 + (t>>6), x = t&63;
  const float* pin = in + (size_t)c*NT;
  float acc = b[c];
  #pragma unroll
  for (int ky=0; ky<3; ky++){
    int yy = y + DIL*(ky-1);
    if (yy<0 || yy>=64) continue;
    #pragma unroll
    for (int kx=0; kx<3; kx++){
      int xx = x + DIL*(kx-1);
      if (xx<0 || xx>=64) continue;
      acc += w[c*9 + ky*3 + kx] * pin[yy*64+xx];
    }
  }
  if (ACT==1) acc = acc * sigmf(acc);
  out[(size_t)c*NT + y*64 + x] = acc;
}

// ---------------------------------------------------------------------------
// Global LayerNorm over 512*4096 elems: partial -> final -> apply(gelu)
__global__ void k_red_part(const float* __restrict__ h, float* __restrict__ part){
  __shared__ float ls[256], lq[256];
  int t = threadIdx.x; size_t base = (size_t)blockIdx.x*4096 + t;
  float s=0, q=0;
  #pragma unroll
  for (int i=0;i<16;i++){ float v = h[base + i*256]; s+=v; q+=v*v; }
  ls[t]=s; lq[t]=q; __syncthreads();
  for (int off=128; off; off>>=1){ if (t<off){ ls[t]+=ls[t+off]; lq[t]+=lq[t+off]; } __syncthreads(); }
  if (t==0){ part[blockIdx.x] = ls[0]; part[512 + blockIdx.x] = lq[0]; }
}
__global__ void k_red_fin(const float* __restrict__ part, float* __restrict__ stats){
  __shared__ float ls[256], lq[256];
  int t = threadIdx.x;
  ls[t] = part[t] + part[t+256];
  lq[t] = part[512+t] + part[768+t];
  __syncthreads();
  for (int off=128; off; off>>=1){ if (t<off){ ls[t]+=ls[t+off]; lq[t]+=lq[t+off]; } __syncthreads(); }
  if (t==0){
    float mu = ls[0] * (1.f/2097152.f);
    float var = lq[0]*(1.f/2097152.f) - mu*mu;
    stats[0]=mu; stats[1]=rsqrtf(var + 1e-5f);
  }
}
__global__ void k_ln_gelu(const float* __restrict__ h, const float* __restrict__ g,
                          const float* __restrict__ b, const float* __restrict__ stats,
                          float* __restrict__ out){
  size_t idx = ((size_t)blockIdx.x*256 + threadIdx.x)*4;
  float mu = stats[0], rs = stats[1];
  float4 hv = *(const float4*)(h + idx);
  float4 gv = *(const float4*)(g + idx);
  float4 bv = *(const float4*)(b + idx);
  float4 o;
  o.x = geluf((hv.x-mu)*rs*gv.x+bv.x);
  o.y = geluf((hv.y-mu)*rs*gv.y+bv.y);
  o.z = geluf((hv.z-mu)*rs*gv.z+bv.z);
  o.w = geluf((hv.w-mu)*rs*gv.w+bv.w);
  *(float4*)(out + idx) = o;
}

// ---------------------------------------------------------------------------
// Per-pixel LN over C=512 (stats), then apply+transpose to NHWC xn(4096,512)
__global__ void k_ln1_stats(const float* __restrict__ fused, float* __restrict__ mu1,
                            float* __restrict__ rs1){
  __shared__ float ss[256], sq[256];
  int t = threadIdx.x; int ci = t>>6; int pj = t&63;
  int pos = blockIdx.x*64 + pj;
  float s=0,q=0;
  for (int c=ci; c<512; c+=4){ float v = fused[(size_t)c*NT + pos]; s+=v; q+=v*v; }
  ss[t]=s; sq[t]=q; __syncthreads();
  if (ci==0){
    float S = ss[pj]+ss[64+pj]+ss[128+pj]+ss[192+pj];
    float Q = sq[pj]+sq[64+pj]+sq[128+pj]+sq[192+pj];
    float mu = S*(1.f/512.f);
    mu1[pos]=mu; rs1[pos]=rsqrtf(Q*(1.f/512.f) - mu*mu + 1e-5f);
  }
}
__global__ void k_ln1_apply(const float* __restrict__ fused, const float* __restrict__ g,
                            const float* __restrict__ b, const float* __restrict__ mu1,
                            const float* __restrict__ rs1, float* __restrict__ xn){
  __shared__ float tile[64*65];
  int t = threadIdx.x;
  int p0 = blockIdx.x*64, c0 = blockIdx.y*64;
  for (int it=0; it<16; it++){
    int idx = t + it*256; int yy = idx>>6, xx = idx&63;  // yy=c-local, xx=p-local
    tile[yy*65+xx] = fused[(size_t)(c0+yy)*NT + p0+xx];
  }
  __syncthreads();
  for (int it=0; it<16; it++){
    int idx = t + it*256; int r = idx>>6, s = idx&63;    // r=p-local, s=c-local
    float v = tile[s*65+r];
    int pos = p0+r, c = c0+s;
    xn[(size_t)pos*512 + c] = (v - mu1[pos])*rs1[pos]*g[c] + b[c];
  }
}

// ---------------------------------------------------------------------------
// Per-channel 64x64 transpose: out[d][w*64+h] = in[d][h*64+w]. grid=1024.
__global__ void k_transpose64(const float* __restrict__ in, float* __restrict__ out){
  __shared__ float tile[64*65];
  int d = blockIdx.x; int t = threadIdx.x;
  const float* p = in + (size_t)d*NT; float* q = out + (size_t)d*NT;
  for (int it=0; it<16; it++){
    int idx = t+it*256; int yy = idx>>6, xx = idx&63;
    tile[yy*65+xx] = p[idx];
  }
  __syncthreads();
  for (int it=0; it<16; it++){
    int idx = t+it*256; int w = idx>>6, hh = idx&63;
    q[idx] = tile[hh*65+w];
  }
}

// ---------------------------------------------------------------------------
__global__ void k_zero(float* __restrict__ p){
  size_t i = ((size_t)blockIdx.x*256 + threadIdx.x)*4;
  *(float4*)(p+i) = make_float4(0,0,0,0);
}

// ---------------------------------------------------------------------------
// Selective scan: 256 blocks x 1 wave. Wave = 16 d x 4 n-groups (4 states ea).
// delta (k,d,l) in scan order; u from xc/xcT (rev for k>=2); B/C from
// xdblT (k, l, 64) cols 32..47 / 48..63. Adds y + D*u into ycomb(l,d)
// at the direction-remapped position via atomicAdd.
__launch_bounds__(64)
__global__ void k_scan(const float* __restrict__ delta, const float* __restrict__ xc,
                       const float* __restrict__ xcT, const float* __restrict__ xdblT,
                       const float* __restrict__ A_logs,
                       const float* __restrict__ Ds, float* __restrict__ ycomb){
  int bid = blockIdx.x;
  int k = bid >> 6;
  int dbase = (bid & 63)*16;
  int lane = threadIdx.x;
  int dsub = lane & 15, ngrp = lane >> 4;
  int d = dbase + dsub;
  const float* up = ((k&1)? xcT : xc) + (size_t)d*NT;
  const float* dp = delta + ((size_t)(k*1024 + d))*NT;
  const float* bc = xdblT + (size_t)k*NT*64;
  float A[4], h[4]={0,0,0,0};
  #pragma unroll
  for (int j=0;j<4;j++) A[j] = -__expf(A_logs[(size_t)(k*1024+d)*16 + ngrp*4 + j]);
  float Dv = Ds[k*1024+d];
  const bool rv = (k>=2);
  for (int l0=0; l0<NT; l0+=4){
    float4 dv4 = *(const float4*)(dp + l0);
    float4 uraw = rv ? *(const float4*)(up + (4092-l0)) : *(const float4*)(up + l0);
    float dts[4] = {dv4.x,dv4.y,dv4.z,dv4.w};
    float us[4];
    if (rv){ us[0]=uraw.w; us[1]=uraw.z; us[2]=uraw.y; us[3]=uraw.x; }
    else   { us[0]=uraw.x; us[1]=uraw.y; us[2]=uraw.z; us[3]=uraw.w; }
    #pragma unroll
    for (int s=0;s<4;s++){
      int l = l0+s;
      float dt = dts[s], u = us[s];
      float4 B4 = *(const float4*)(bc + (size_t)l*64 + 32 + ngrp*4);
      float4 C4 = *(const float4*)(bc + (size_t)l*64 + 48 + ngrp*4);
      float xbu = dt*u;
      float Bv[4]={B4.x,B4.y,B4.z,B4.w}, Cv[4]={C4.x,C4.y,C4.z,C4.w};
      float ys = 0.f;
      #pragma unroll
      for (int j=0;j<4;j++){
        float dA = __expf(dt*A[j]);
        h[j] = dA*h[j] + xbu*Bv[j];
        ys += h[j]*Cv[j];
      }
      ys += __shfl_xor(ys, 16);
      ys += __shfl_xor(ys, 32);
      if (ngrp==0){
        int pos;
        if (k==0) pos = l;
        else if (k==1) pos = ((l&63)<<6) | (l>>6);
        else if (k==2) pos = 4095-l;
        else { int tt = 4095-l; pos = ((tt&63)<<6) | (tt>>6); }
        atomicAdd(&ycomb[(size_t)pos*1024 + d], ys + Dv*u);
      }
    }
  }
}

// ---------------------------------------------------------------------------
// Combine: per-pixel LN over 1024 dirs-summed y, gate with silu(z) -> yact(l,d)
__global__ void k_combine(const float* __restrict__ ycomb, const float* __restrict__ xz,
                          const float* __restrict__ g, const float* __restrict__ b,
                          float* __restrict__ yact){
  int pos = blockIdx.x, t = threadIdx.x;
  float v[4]; float s=0,q=0;
  #pragma unroll
  for (int i=0;i<4;i++){ v[i] = ycomb[(size_t)pos*1024 + t + i*256]; s+=v[i]; q+=v[i]*v[i]; }
  #pragma unroll
  for (int off=32; off>=1; off>>=1){ s += __shfl_xor(s,off); q += __shfl_xor(q,off); }
  __shared__ float red[8];
  int wid = t>>6;
  if ((t&63)==0){ red[wid*2]=s; red[wid*2+1]=q; }
  __syncthreads();
  float S = red[0]+red[2]+red[4]+red[6];
  float Q = red[1]+red[3]+red[5]+red[7];
  float mu = S*(1.f/1024.f), rs = rsqrtf(Q*(1.f/1024.f) - mu*mu + 1e-5f);
  #pragma unroll
  for (int i=0;i<4;i++){
    int dd = t + i*256;
    float z = xz[(size_t)(1024+dd)*NT + pos];
    float yv = (v[i]-mu)*rs*g[dd] + b[dd];
    yact[(size_t)pos*1024 + dd] = yv * (z * sigmf(z));
  }
}

// ---------------------------------------------------------------------------
// Final: out = avgblur3x3(attn) + fused, f32. grid=512*16.
__global__ void k_blur(const float* __restrict__ attn, const float* __restrict__ fused,
                       float* __restrict__ outp){
  int bid = blockIdx.x; int c = bid>>4, yb = bid&15; int t = threadIdx.x;
  int y = yb*4 + (t>>6), x = t&63;
  const float* p = attn + (size_t)c*NT;
  float s = 0;
  #pragma unroll
  for (int dy=-1; dy<=1; dy++){
    int yy = y+dy; if (yy<0||yy>=64) continue;
    #pragma unroll
    for (int dx=-1; dx<=1; dx++){
      int xx = x+dx; if (xx<0||xx>=64) continue;
      s += p[yy*64+xx];
    }
  }
  float val = s*(1.f/9.f) + fused[(size_t)c*NT + y*64 + x];
  outp[(size_t)c*NT + y*64 + x] = val;
}

// ---------------------------------------------------------------------------
extern "C" void kernel_launch(void* const* d_in, const int* in_sizes, int n_in,
                              void* d_out, int out_size, void* d_ws, size_t ws_size,
                              hipStream_t stream){
  const float* feat = (const float*)d_in[0];
  const float* lat  = (const float*)d_in[1];
  const float* fg_w1= (const float*)d_in[2];
  const float* fg_b1= (const float*)d_in[3];
  const float* fg_w2= (const float*)d_in[4];
  const float* fg_b2= (const float*)d_in[5];
  const float* fb_w1= (const float*)d_in[6];
  const float* ln_g = (const float*)d_in[7];
  const float* ln_b = (const float*)d_in[8];
  const float* dw_w = (const float*)d_in[9];
  const float* dw_b = (const float*)d_in[10];
  const float* pw1_w= (const float*)d_in[11];
  const float* pw1_b= (const float*)d_in[12];
  const float* pw2_w= (const float*)d_in[13];
  const float* pw2_b= (const float*)d_in[14];
  const float* ln1_g= (const float*)d_in[15];
  const float* ln1_b= (const float*)d_in[16];
  const float* inpw = (const float*)d_in[17];
  const float* dc_w = (const float*)d_in[18];
  const float* dc_b = (const float*)d_in[19];
  const float* xpw  = (const float*)d_in[20];
  const float* dtw  = (const float*)d_in[21];
  const float* dtb  = (const float*)d_in[22];
  const float* Alog = (const float*)d_in[23];
  const float* Dsp  = (const float*)d_in[24];
  const float* ong  = (const float*)d_in[25];
  const float* onb  = (const float*)d_in[26];
  const float* opw  = (const float*)d_in[27];
  float* outp = (float*)d_out;
  (void)in_sizes; (void)n_in; (void)out_size; (void)ws_size;

  // ---- workspace regions with reuse (sizes in floats) ------------------
  float* Wp = (float*)d_ws;
  size_t off = 0;
  auto alloc = [&](size_t n){ float* p = Wp + off; off += n; return p; };
  float* S0    = alloc((size_t)1024*NT);   // wf -> xn -> yact
  float* S1    = alloc((size_t)512*NT);    // h -> h3 -> attn
  float* P0    = alloc((size_t)512*NT);    // fused (persistent)
  float* P1    = alloc((size_t)2048*NT);   // h2 (front) -> xz
  float* P2    = alloc((size_t)1024*NT);   // h4 (front) -> xc
  float* P3    = alloc((size_t)1024*NT);   // xcT
  float* P4    = alloc((size_t)4*NT*64);   // xdblT
  float* P5    = alloc((size_t)4*1024*NT); // delta
  float* P6    = alloc((size_t)1024*NT);   // g1 (front) -> ycomb
  float* part  = alloc(1024);
  float* stats = alloc(4);
  float* mu1   = alloc(4096);
  float* rs1   = alloc(4096);
  // total ~47.2M floats = 189 MB

  float* wf    = S0;
  float* h     = S1;
  float* h2    = P1;
  float* h3    = S1;
  float* h4    = P2;
  float* fused = P0;
  float* xn    = S0;
  float* xz    = P1;
  float* xc    = P2;
  float* xcT   = P3;
  float* xdblT = P4;
  float* delta = P5;
  float* g1    = P6;
  float* ycomb = P6;
  float* yact  = S0;
  float* attn  = S1;

  // 1) g1 = gelu(fg1(concat))            M=32, K=1024
  hipLaunchKernelGGL((k_gemm<1,1,false>), dim3(64,1), dim3(256), 0, stream,
      32, 1024, 1024, 0, fg_w1, fg_b1, nullptr, feat, lat, 0,0, nullptr, g1);
  // 2) wf = concat * sigmoid(fg2(g1))    M=1024, K=32
  hipLaunchKernelGGL((k_gemm<0,5,false>), dim3(64,16), dim3(256), 0, stream,
      1024, 32, 32, 0, fg_w2, fg_b2, g1, feat, lat, 0,0, nullptr, wf);
  // 3) h = conv3x3(wf, fb_w1)            M=512, K=9216 (implicit im2col)
  hipLaunchKernelGGL((k_gemm<3,0,false>), dim3(64,8), dim3(256), 0, stream,
      512, 9216, 9216, 0, fb_w1, nullptr, wf, nullptr,nullptr, 0,0, nullptr, h);
  // 4) h2 = gelu(LN_global(h))
  hipLaunchKernelGGL(k_red_part, dim3(512), dim3(256), 0, stream, h, part);
  hipLaunchKernelGGL(k_red_fin,  dim3(1),   dim3(256), 0, stream, part, stats);
  hipLaunchKernelGGL(k_ln_gelu,  dim3(2048),dim3(256), 0, stream, h, ln_g, ln_b, stats, h2);
  // 5) h3 = dwconv3x3 dil2(h2)
  hipLaunchKernelGGL((k_dwconv<2,0>), dim3(512*16), dim3(256), 0, stream, h2, dw_w, dw_b, h3);
  // 6) h4 = gelu(pw1(h3))
  hipLaunchKernelGGL((k_gemm<0,1,false>), dim3(64,8), dim3(256), 0, stream,
      512, 512, 512, 0, pw1_w, pw1_b, h3, nullptr,nullptr, 0,0, nullptr, h4);
  // 7) fused = pw2(shuffle(h4)) + feature
  hipLaunchKernelGGL((k_gemm<0,4,false>), dim3(64,8), dim3(256), 0, stream,
      512, 512, 512, 0, pw2_w, pw2_b, h4, nullptr,nullptr, 0,1, feat, fused);
  // 8) xn = LN_c(fused^T) (NHWC)
  hipLaunchKernelGGL(k_ln1_stats, dim3(64), dim3(256), 0, stream, fused, mu1, rs1);
  hipLaunchKernelGGL(k_ln1_apply, dim3(64,8), dim3(256), 0, stream, fused, ln1_g, ln1_b, mu1, rs1, xn);
  // 9) xz = xn @ in_proj^T               M=2048, K=512, B NHWC
  hipLaunchKernelGGL((k_gemm<2,0,false>), dim3(64,32), dim3(256), 0, stream,
      2048, 512, 512, 512, inpw, nullptr, xn, nullptr,nullptr, 0,0, nullptr, xz);
  // 10) xc = silu(dwconv3x3(xp))
  hipLaunchKernelGGL((k_dwconv<1,1>), dim3(1024*16), dim3(256), 0, stream, xz, dc_w, dc_b, xc);
  // 11) xcT
  hipLaunchKernelGGL(k_transpose64, dim3(1024), dim3(256), 0, stream, xc, xcT);
  // 12) xdblT[k] = (x_proj_w[k] @ xs[k])^T   M=64, K=1024, transposed write
  for (int k=0;k<4;k++){
    hipLaunchKernelGGL((k_gemm<0,0,true>), dim3(64,1), dim3(256), 0, stream,
        64, 1024, 1024, 0, xpw + (size_t)k*64*1024, nullptr, (k&1)? xcT : xc,
        nullptr,nullptr, (k>=2)?1:0, 0, nullptr, xdblT + (size_t)k*NT*64);
  }
  // 13) delta[k] = softplus(dt_w[k] @ dts[k] + dt_b[k])   M=1024, K=32, B NHWC(ld 64)
  for (int k=0;k<4;k++){
    hipLaunchKernelGGL((k_gemm<2,2,false>), dim3(64,16), dim3(256), 0, stream,
        1024, 32, 32, 64, dtw + (size_t)k*1024*32, dtb + (size_t)k*1024,
        xdblT + (size_t)k*NT*64, nullptr,nullptr, 0,0, nullptr,
        delta + (size_t)k*1024*NT);
  }
  // 14) ycomb = 0
  hipLaunchKernelGGL(k_zero, dim3(4096), dim3(256), 0, stream, ycomb);
  // 15) selective scan (4 dirs), += into ycomb(l,d)
  hipLaunchKernelGGL(k_scan, dim3(256), dim3(64), 0, stream,
      delta, xc, xcT, xdblT, Alog, Dsp, ycomb);
  // 16) yact = out_norm(ycomb) * silu(z)
  hipLaunchKernelGGL(k_combine, dim3(4096), dim3(256), 0, stream, ycomb, xz, ong, onb, yact);
  // 17) attn = fused + yact @ out_proj^T   M=512, K=1024, B NHWC
  hipLaunchKernelGGL((k_gemm<2,4,false>), dim3(64,8), dim3(256), 0, stream,
      512, 1024, 1024, 1024, opw, nullptr, yact, nullptr,nullptr, 0,0, fused, attn);
  // 18) out = blur3x3(attn) + fused  -> f32
  hipLaunchKernelGGL(k_blur, dim3(512*16), dim3(256), 0, stream, attn, fused, outp);
}

// Round 6
// 1990.860 us; speedup vs baseline: 1.8628x; 1.8628x over previous
//
#include <hip/hip_runtime.h>

// ---------------------------------------------------------------------------
// FeatureMapApproximator: VMamba-style block. B=1, C=512, H=W=64, L=4096,
// d_inner=1024, K=4 dirs, N=16 states, dt_rank=32.
// All f32. Scan is chunked (16 chunks x 256 steps) for occupancy.
// ---------------------------------------------------------------------------

#define NT 4096   // pixels (and GEMM N)
#define NCH 16    // scan chunks
#define CHL 256   // chunk length

__device__ __forceinline__ float geluf(float x){ return 0.5f*x*(1.f+erff(x*0.70710678118654752f)); }
__device__ __forceinline__ float sigmf(float x){ return 1.f/(1.f+__expf(-x)); }
__device__ __forceinline__ float softplusf(float x){ return (x>20.f)? x : __logf(1.f+__expf(x)); }

// ---------------------------------------------------------------------------
// Generic tiled GEMM: out[m][n] = epi( sum_k A[m][k]*B[k][n] + bias[m] )
// Tiles: TM=64, TN=64, TK=32, 256 threads, 4x4 acc per thread.
// BMODE 0: B f32 channel-major (K rows of length 4096); rev => n -> 4095-n,
//          shuf => channel-shuffle row remap.
// BMODE 1: B = f32 concat(feat, lat) channel-major (K=1024, split at 512).
// BMODE 2: B f32 NHWC: B[k][n] = Bf[n*ldb + k].
// BMODE 3: implicit im2col 3x3 pad1 from Bf (1024,4096); k = c*9+ky*3+kx.
// EPI 0 none | 1 gelu | 2 softplus | 4 +f32 res | 5 concat*sigmoid
// TRANSW: write out[n*64+m] (requires M==64, EPI 0, no bias) via LDS bounce.
// ---------------------------------------------------------------------------
template<int BMODE, int EPI, bool TRANSW>
__launch_bounds__(256)
__global__ void k_gemm(int M, int K, int lda, int ldb,
    const float* __restrict__ A, const float* __restrict__ bias,
    const float* __restrict__ Bf, const float* __restrict__ Bc0,
    const float* __restrict__ Bc1, int rev, int shuf,
    const float* __restrict__ resf, float* __restrict__ out)
{
  __shared__ float smem[4352];           // 2 x [32][68] (or 64x68 for TRANSW)
  float* As = smem;
  float* Bs = smem + 2176;
  const int t  = threadIdx.x;
  const int n0 = blockIdx.x*64, m0 = blockIdx.y*64;
  float acc[4][4] = {};

  for (int k0=0; k0<K; k0+=32){
    __syncthreads();
    { // stage A (f32 weights, row-major M x K)
      int m = t>>2, kk0 = (t&3)*8;
      float av[8] = {0,0,0,0,0,0,0,0};
      if (m0+m < M){
        const float* pa = A + (size_t)(m0+m)*lda + k0 + kk0;
        float4 a0 = *(const float4*)pa; float4 a1 = *(const float4*)(pa+4);
        av[0]=a0.x; av[1]=a0.y; av[2]=a0.z; av[3]=a0.w;
        av[4]=a1.x; av[5]=a1.y; av[6]=a1.z; av[7]=a1.w;
      }
      #pragma unroll
      for (int j=0;j<8;j++) As[(kk0+j)*68 + m] = av[j];
    }
    if (BMODE==2){
      int n = t>>2, kk0 = (t&3)*8;
      const float* p = Bf + (size_t)(n0+n)*ldb + k0 + kk0;
      float4 x0 = *(const float4*)p; float4 x1 = *(const float4*)(p+4);
      Bs[(kk0+0)*68+n]=x0.x; Bs[(kk0+1)*68+n]=x0.y; Bs[(kk0+2)*68+n]=x0.z; Bs[(kk0+3)*68+n]=x0.w;
      Bs[(kk0+4)*68+n]=x1.x; Bs[(kk0+5)*68+n]=x1.y; Bs[(kk0+6)*68+n]=x1.z; Bs[(kk0+7)*68+n]=x1.w;
    } else {
      int kk = t>>3, n8 = (t&7)*8;
      float bv[8];
      if (BMODE==0){
        int r = k0+kk; if (shuf) r = (r&7)*64 + (r>>3);
        const float* p = Bf + (size_t)r*NT;
        if (!rev){
          float4 x0 = *(const float4*)(p + n0+n8); float4 x1 = *(const float4*)(p + n0+n8+4);
          bv[0]=x0.x;bv[1]=x0.y;bv[2]=x0.z;bv[3]=x0.w;bv[4]=x1.x;bv[5]=x1.y;bv[6]=x1.z;bv[7]=x1.w;
        } else {
          const float* q = p + (4088 - n0 - n8);
          float4 x0 = *(const float4*)q; float4 x1 = *(const float4*)(q+4);
          bv[0]=x1.w;bv[1]=x1.z;bv[2]=x1.y;bv[3]=x1.x;bv[4]=x0.w;bv[5]=x0.z;bv[6]=x0.y;bv[7]=x0.x;
        }
      } else if (BMODE==1){
        int c = k0+kk;
        const float* p = (c<512) ? (Bc0 + (size_t)c*NT) : (Bc1 + (size_t)(c-512)*NT);
        float4 x0 = *(const float4*)(p + n0+n8); float4 x1 = *(const float4*)(p + n0+n8+4);
        bv[0]=x0.x;bv[1]=x0.y;bv[2]=x0.z;bv[3]=x0.w;bv[4]=x1.x;bv[5]=x1.y;bv[6]=x1.z;bv[7]=x1.w;
      } else { // BMODE==3
        int k = k0+kk; int c = k/9; int t9 = k - c*9; int qy = t9/3;
        int dy = qy-1, dx = t9 - qy*3 - 1;
        int y = (n0>>6) + dy;               // n-tile is one image row
        bool yok = (y>=0)&&(y<64);
        const float* p = Bf + (size_t)c*NT + y*64;
        #pragma unroll
        for (int j=0;j<8;j++){
          int x = n8 + j + dx;
          bv[j] = (yok && x>=0 && x<64) ? p[x] : 0.f;
        }
      }
      *(float4*)&Bs[kk*68 + n8]   = make_float4(bv[0],bv[1],bv[2],bv[3]);
      *(float4*)&Bs[kk*68 + n8+4] = make_float4(bv[4],bv[5],bv[6],bv[7]);
    }
    __syncthreads();
    int ti = t>>4, tj = t&15;
    #pragma unroll
    for (int kk=0; kk<32; kk++){
      float4 a4 = *(const float4*)&As[kk*68 + ti*4];
      float4 b4 = *(const float4*)&Bs[kk*68 + tj*4];
      float aa[4] = {a4.x,a4.y,a4.z,a4.w};
      float bb[4] = {b4.x,b4.y,b4.z,b4.w};
      #pragma unroll
      for (int i=0;i<4;i++)
        #pragma unroll
        for (int j=0;j<4;j++) acc[i][j] += aa[i]*bb[j];
    }
  }

  int ti = t>>4, tj = t&15;
  if (!TRANSW){
    #pragma unroll
    for (int i=0;i<4;i++){
      int m = m0 + ti*4 + i;
      if (m >= M) continue;
      float bi = bias ? bias[m] : 0.f;
      float o4[4];
      #pragma unroll
      for (int j=0;j<4;j++){
        int n = n0 + tj*4 + j;
        float v = acc[i][j] + bi;
        if (EPI==1) v = geluf(v);
        else if (EPI==2) v = softplusf(v);
        else if (EPI==4) v = v + resf[(size_t)m*NT + n];
        else if (EPI==5){
          float cv = (m<512)? Bc0[(size_t)m*NT+n] : Bc1[(size_t)(m-512)*NT+n];
          v = cv * sigmf(v);
        }
        o4[j] = v;
      }
      *(float4*)&out[(size_t)m*NT + n0 + tj*4] = make_float4(o4[0],o4[1],o4[2],o4[3]);
    }
  } else {
    __syncthreads();
    #pragma unroll
    for (int i=0;i<4;i++)
      #pragma unroll
      for (int j=0;j<4;j++)
        smem[(tj*4+j)*68 + (ti*4+i)] = acc[i][j];
    __syncthreads();
    int nl = t>>2, c0 = (t&3)*16;
    #pragma unroll
    for (int g4=0; g4<4; g4++){
      float4 v = *(const float4*)&smem[nl*68 + c0 + g4*4];
      *(float4*)&out[(size_t)(n0+nl)*64 + c0 + g4*4] = v;
    }
  }
}

// ---------------------------------------------------------------------------
// Depthwise 3x3 conv (dilated), optional SiLU. grid = C*16, block 256.
template<int DIL, int ACT>
__global__ void k_dwconv(const float* __restrict__ in, const float* __restrict__ w,
                         const float* __restrict__ b, float* __restrict__ out){
  int bid = blockIdx.x;
  int c = bid >> 4, yb = bid & 15;
  int t = threadIdx.x;
  int y = yb*4 + (t>>6), x = t&63;
  const float* pin = in + (size_t)c*NT;
  float acc = b[c];
  #pragma unroll
  for (int ky=0; ky<3; ky++){
    int yy = y + DIL*(ky-1);
    if (yy<0 || yy>=64) continue;
    #pragma unroll
    for (int kx=0; kx<3; kx++){
      int xx = x + DIL*(kx-1);
      if (xx<0 || xx>=64) continue;
      acc += w[c*9 + ky*3 + kx] * pin[yy*64+xx];
    }
  }
  if (ACT==1) acc = acc * sigmf(acc);
  out[(size_t)c*NT + y*64 + x] = acc;
}

// ---------------------------------------------------------------------------
// Global LayerNorm over 512*4096 elems: partial -> final -> apply(gelu)
__global__ void k_red_part(const float* __restrict__ h, float* __restrict__ part){
  __shared__ float ls[256], lq[256];
  int t = threadIdx.x; size_t base = (size_t)blockIdx.x*4096 + t;
  float s=0, q=0;
  #pragma unroll
  for (int i=0;i<16;i++){ float v = h[base + i*256]; s+=v; q+=v*v; }
  ls[t]=s; lq[t]=q; __syncthreads();
  for (int off=128; off; off>>=1){ if (t<off){ ls[t]+=ls[t+off]; lq[t]+=lq[t+off]; } __syncthreads(); }
  if (t==0){ part[blockIdx.x] = ls[0]; part[512 + blockIdx.x] = lq[0]; }
}
__global__ void k_red_fin(const float* __restrict__ part, float* __restrict__ stats){
  __shared__ float ls[256], lq[256];
  int t = threadIdx.x;
  ls[t] = part[t] + part[t+256];
  lq[t] = part[512+t] + part[768+t];
  __syncthreads();
  for (int off=128; off; off>>=1){ if (t<off){ ls[t]+=ls[t+off]; lq[t]+=lq[t+off]; } __syncthreads(); }
  if (t==0){
    float mu = ls[0] * (1.f/2097152.f);
    float var = lq[0]*(1.f/2097152.f) - mu*mu;
    stats[0]=mu; stats[1]=rsqrtf(var + 1e-5f);
  }
}
__global__ void k_ln_gelu(const float* __restrict__ h, const float* __restrict__ g,
                          const float* __restrict__ b, const float* __restrict__ stats,
                          float* __restrict__ out){
  size_t idx = ((size_t)blockIdx.x*256 + threadIdx.x)*4;
  float mu = stats[0], rs = stats[1];
  float4 hv = *(const float4*)(h + idx);
  float4 gv = *(const float4*)(g + idx);
  float4 bv = *(const float4*)(b + idx);
  float4 o;
  o.x = geluf((hv.x-mu)*rs*gv.x+bv.x);
  o.y = geluf((hv.y-mu)*rs*gv.y+bv.y);
  o.z = geluf((hv.z-mu)*rs*gv.z+bv.z);
  o.w = geluf((hv.w-mu)*rs*gv.w+bv.w);
  *(float4*)(out + idx) = o;
}

// ---------------------------------------------------------------------------
// Per-pixel LN over C=512 (stats), then apply+transpose to NHWC xn(4096,512)
__global__ void k_ln1_stats(const float* __restrict__ fused, float* __restrict__ mu1,
                            float* __restrict__ rs1){
  __shared__ float ss[256], sq[256];
  int t = threadIdx.x; int ci = t>>6; int pj = t&63;
  int pos = blockIdx.x*64 + pj;
  float s=0,q=0;
  for (int c=ci; c<512; c+=4){ float v = fused[(size_t)c*NT + pos]; s+=v; q+=v*v; }
  ss[t]=s; sq[t]=q; __syncthreads();
  if (ci==0){
    float S = ss[pj]+ss[64+pj]+ss[128+pj]+ss[192+pj];
    float Q = sq[pj]+sq[64+pj]+sq[128+pj]+sq[192+pj];
    float mu = S*(1.f/512.f);
    mu1[pos]=mu; rs1[pos]=rsqrtf(Q*(1.f/512.f) - mu*mu + 1e-5f);
  }
}
__global__ void k_ln1_apply(const float* __restrict__ fused, const float* __restrict__ g,
                            const float* __restrict__ b, const float* __restrict__ mu1,
                            const float* __restrict__ rs1, float* __restrict__ xn){
  __shared__ float tile[64*65];
  int t = threadIdx.x;
  int p0 = blockIdx.x*64, c0 = blockIdx.y*64;
  for (int it=0; it<16; it++){
    int idx = t + it*256; int yy = idx>>6, xx = idx&63;  // yy=c-local, xx=p-local
    tile[yy*65+xx] = fused[(size_t)(c0+yy)*NT + p0+xx];
  }
  __syncthreads();
  for (int it=0; it<16; it++){
    int idx = t + it*256; int r = idx>>6, s = idx&63;    // r=p-local, s=c-local
    float v = tile[s*65+r];
    int pos = p0+r, c = c0+s;
    xn[(size_t)pos*512 + c] = (v - mu1[pos])*rs1[pos]*g[c] + b[c];
  }
}

// ---------------------------------------------------------------------------
// Per-channel 64x64 transpose: out[d][w*64+h] = in[d][h*64+w]. grid=1024.
__global__ void k_transpose64(const float* __restrict__ in, float* __restrict__ out){
  __shared__ float tile[64*65];
  int d = blockIdx.x; int t = threadIdx.x;
  const float* p = in + (size_t)d*NT; float* q = out + (size_t)d*NT;
  for (int it=0; it<16; it++){
    int idx = t+it*256; int yy = idx>>6, xx = idx&63;
    tile[yy*65+xx] = p[idx];
  }
  __syncthreads();
  for (int it=0; it<16; it++){
    int idx = t+it*256; int w = idx>>6, hh = idx&63;
    q[idx] = tile[hh*65+w];
  }
}

// ---------------------------------------------------------------------------
__global__ void k_zero(float* __restrict__ p){
  size_t i = ((size_t)blockIdx.x*256 + threadIdx.x)*4;
  *(float4*)(p+i) = make_float4(0,0,0,0);
}

// ---------------------------------------------------------------------------
// Chunked selective scan, phase A: per (scanset, chunk) compute
//   P = prod(dA) and S = chunk-local state (h0=0) for each state.
// grid = 256 scansets * NCH chunks, block = 64 (16 d x 4 ngrp x 4 states).
__launch_bounds__(64)
__global__ void k_scan_part(const float* __restrict__ delta, const float* __restrict__ xc,
                            const float* __restrict__ xcT, const float* __restrict__ xdblT,
                            const float* __restrict__ A_logs,
                            float* __restrict__ Pbuf, float* __restrict__ Sbuf){
  int bid = blockIdx.x;
  int ss = bid >> 4;              // scanset 0..255
  int c  = bid & (NCH-1);         // chunk
  int k = ss >> 6;
  int dbase = (ss & 63)*16;
  int lane = threadIdx.x;
  int dsub = lane & 15, ngrp = lane >> 4;
  int d = dbase + dsub;
  const float* up = ((k&1)? xcT : xc) + (size_t)d*NT;
  const float* dp = delta + ((size_t)(k*1024 + d))*NT;
  const float* bc = xdblT + (size_t)k*NT*64;
  float A[4], S[4]={0,0,0,0}, P[4]={1.f,1.f,1.f,1.f};
  #pragma unroll
  for (int j=0;j<4;j++) A[j] = -__expf(A_logs[(size_t)(k*1024+d)*16 + ngrp*4 + j]);
  const bool rv = (k>=2);
  int base = c*CHL;
  for (int l0=base; l0<base+CHL; l0+=4){
    float4 dv4 = *(const float4*)(dp + l0);
    float4 uraw = rv ? *(const float4*)(up + (4092-l0)) : *(const float4*)(up + l0);
    float dts[4] = {dv4.x,dv4.y,dv4.z,dv4.w};
    float us[4];
    if (rv){ us[0]=uraw.w; us[1]=uraw.z; us[2]=uraw.y; us[3]=uraw.x; }
    else   { us[0]=uraw.x; us[1]=uraw.y; us[2]=uraw.z; us[3]=uraw.w; }
    #pragma unroll
    for (int s=0;s<4;s++){
      int l = l0+s;
      float dt = dts[s];
      float4 B4 = *(const float4*)(bc + (size_t)l*64 + 32 + ngrp*4);
      float xbu = dt*us[s];
      float Bv[4]={B4.x,B4.y,B4.z,B4.w};
      #pragma unroll
      for (int j=0;j<4;j++){
        float dA = __expf(dt*A[j]);
        S[j] = dA*S[j] + xbu*Bv[j];
        P[j] *= dA;
      }
    }
  }
  size_t o = ((size_t)(k*1024+d)*NCH + c)*16 + ngrp*4;
  *(float4*)&Pbuf[o] = make_float4(P[0],P[1],P[2],P[3]);
  *(float4*)&Sbuf[o] = make_float4(S[0],S[1],S[2],S[3]);
}

// ---------------------------------------------------------------------------
// Phase B: serial combine over chunks. thread = one (scan, state).
// Hbuf[scan][c][n] = h_in at chunk c. grid=256, block=256 (64K threads).
__global__ void k_scan_comb(const float* __restrict__ Pbuf, const float* __restrict__ Sbuf,
                            float* __restrict__ Hbuf){
  int tid = blockIdx.x*256 + threadIdx.x;
  int scan = tid >> 4, n = tid & 15;
  size_t base = (size_t)scan*(NCH*16) + n;
  float h = 0.f;
  #pragma unroll
  for (int c=0;c<NCH;c++){
    Hbuf[base + c*16] = h;
    h = Pbuf[base + c*16]*h + Sbuf[base + c*16];
  }
}

// ---------------------------------------------------------------------------
// Phase C: re-run chunk from h_in, compute y, atomicAdd into ycomb(l,d).
// grid = 256 scansets * NCH, block = 64.
__launch_bounds__(64)
__global__ void k_scan_fin(const float* __restrict__ delta, const float* __restrict__ xc,
                           const float* __restrict__ xcT, const float* __restrict__ xdblT,
                           const float* __restrict__ A_logs, const float* __restrict__ Ds,
                           const float* __restrict__ Hbuf, float* __restrict__ ycomb){
  int bid = blockIdx.x;
  int ss = bid >> 4;
  int c  = bid & (NCH-1);
  int k = ss >> 6;
  int dbase = (ss & 63)*16;
  int lane = threadIdx.x;
  int dsub = lane & 15, ngrp = lane >> 4;
  int d = dbase + dsub;
  const float* up = ((k&1)? xcT : xc) + (size_t)d*NT;
  const float* dp = delta + ((size_t)(k*1024 + d))*NT;
  const float* bc = xdblT + (size_t)k*NT*64;
  float A[4], h[4];
  #pragma unroll
  for (int j=0;j<4;j++) A[j] = -__expf(A_logs[(size_t)(k*1024+d)*16 + ngrp*4 + j]);
  {
    size_t o = ((size_t)(k*1024+d)*NCH + c)*16 + ngrp*4;
    float4 h4 = *(const float4*)&Hbuf[o];
    h[0]=h4.x; h[1]=h4.y; h[2]=h4.z; h[3]=h4.w;
  }
  float Dv = Ds[k*1024+d];
  const bool rv = (k>=2);
  int base = c*CHL;
  for (int l0=base; l0<base+CHL; l0+=4){
    float4 dv4 = *(const float4*)(dp + l0);
    float4 uraw = rv ? *(const float4*)(up + (4092-l0)) : *(const float4*)(up + l0);
    float dts[4] = {dv4.x,dv4.y,dv4.z,dv4.w};
    float us[4];
    if (rv){ us[0]=uraw.w; us[1]=uraw.z; us[2]=uraw.y; us[3]=uraw.x; }
    else   { us[0]=uraw.x; us[1]=uraw.y; us[2]=uraw.z; us[3]=uraw.w; }
    #pragma unroll
    for (int s=0;s<4;s++){
      int l = l0+s;
      float dt = dts[s], u = us[s];
      float4 B4 = *(const float4*)(bc + (size_t)l*64 + 32 + ngrp*4);
      float4 C4 = *(const float4*)(bc + (size_t)l*64 + 48 + ngrp*4);
      float xbu = dt*u;
      float Bv[4]={B4.x,B4.y,B4.z,B4.w}, Cv[4]={C4.x,C4.y,C4.z,C4.w};
      float ys = 0.f;
      #pragma unroll
      for (int j=0;j<4;j++){
        float dA = __expf(dt*A[j]);
        h[j] = dA*h[j] + xbu*Bv[j];
        ys += h[j]*Cv[j];
      }
      ys += __shfl_xor(ys, 16);
      ys += __shfl_xor(ys, 32);
      if (ngrp==0){
        int pos;
        if (k==0) pos = l;
        else if (k==1) pos = ((l&63)<<6) | (l>>6);
        else if (k==2) pos = 4095-l;
        else { int tt = 4095-l; pos = ((tt&63)<<6) | (tt>>6); }
        atomicAdd(&ycomb[(size_t)pos*1024 + d], ys + Dv*u);
      }
    }
  }
}

// ---------------------------------------------------------------------------
// Combine: per-pixel LN over 1024 dirs-summed y, gate with silu(z) -> yact(l,d)
__global__ void k_combine(const float* __restrict__ ycomb, const float* __restrict__ xz,
                          const float* __restrict__ g, const float* __restrict__ b,
                          float* __restrict__ yact){
  int pos = blockIdx.x, t = threadIdx.x;
  float v[4]; float s=0,q=0;
  #pragma unroll
  for (int i=0;i<4;i++){ v[i] = ycomb[(size_t)pos*1024 + t + i*256]; s+=v[i]; q+=v[i]*v[i]; }
  #pragma unroll
  for (int off=32; off>=1; off>>=1){ s += __shfl_xor(s,off); q += __shfl_xor(q,off); }
  __shared__ float red[8];
  int wid = t>>6;
  if ((t&63)==0){ red[wid*2]=s; red[wid*2+1]=q; }
  __syncthreads();
  float S = red[0]+red[2]+red[4]+red[6];
  float Q = red[1]+red[3]+red[5]+red[7];
  float mu = S*(1.f/1024.f), rs = rsqrtf(Q*(1.f/1024.f) - mu*mu + 1e-5f);
  #pragma unroll
  for (int i=0;i<4;i++){
    int dd = t + i*256;
    float z = xz[(size_t)(1024+dd)*NT + pos];
    float yv = (v[i]-mu)*rs*g[dd] + b[dd];
    yact[(size_t)pos*1024 + dd] = yv * (z * sigmf(z));
  }
}

// ---------------------------------------------------------------------------
// Final: out = avgblur3x3(attn) + fused, f32. grid=512*16.
__global__ void k_blur(const float* __restrict__ attn, const float* __restrict__ fused,
                       float* __restrict__ outp){
  int bid = blockIdx.x; int c = bid>>4, yb = bid&15; int t = threadIdx.x;
  int y = yb*4 + (t>>6), x = t&63;
  const float* p = attn + (size_t)c*NT;
  float s = 0;
  #pragma unroll
  for (int dy=-1; dy<=1; dy++){
    int yy = y+dy; if (yy<0||yy>=64) continue;
    #pragma unroll
    for (int dx=-1; dx<=1; dx++){
      int xx = x+dx; if (xx<0||xx>=64) continue;
      s += p[yy*64+xx];
    }
  }
  float val = s*(1.f/9.f) + fused[(size_t)c*NT + y*64 + x];
  outp[(size_t)c*NT + y*64 + x] = val;
}

// ---------------------------------------------------------------------------
extern "C" void kernel_launch(void* const* d_in, const int* in_sizes, int n_in,
                              void* d_out, int out_size, void* d_ws, size_t ws_size,
                              hipStream_t stream){
  const float* feat = (const float*)d_in[0];
  const float* lat  = (const float*)d_in[1];
  const float* fg_w1= (const float*)d_in[2];
  const float* fg_b1= (const float*)d_in[3];
  const float* fg_w2= (const float*)d_in[4];
  const float* fg_b2= (const float*)d_in[5];
  const float* fb_w1= (const float*)d_in[6];
  const float* ln_g = (const float*)d_in[7];
  const float* ln_b = (const float*)d_in[8];
  const float* dw_w = (const float*)d_in[9];
  const float* dw_b = (const float*)d_in[10];
  const float* pw1_w= (const float*)d_in[11];
  const float* pw1_b= (const float*)d_in[12];
  const float* pw2_w= (const float*)d_in[13];
  const float* pw2_b= (const float*)d_in[14];
  const float* ln1_g= (const float*)d_in[15];
  const float* ln1_b= (const float*)d_in[16];
  const float* inpw = (const float*)d_in[17];
  const float* dc_w = (const float*)d_in[18];
  const float* dc_b = (const float*)d_in[19];
  const float* xpw  = (const float*)d_in[20];
  const float* dtw  = (const float*)d_in[21];
  const float* dtb  = (const float*)d_in[22];
  const float* Alog = (const float*)d_in[23];
  const float* Dsp  = (const float*)d_in[24];
  const float* ong  = (const float*)d_in[25];
  const float* onb  = (const float*)d_in[26];
  const float* opw  = (const float*)d_in[27];
  float* outp = (float*)d_out;
  (void)in_sizes; (void)n_in; (void)out_size; (void)ws_size;

  // ---- workspace regions with reuse (sizes in floats) ------------------
  float* Wp = (float*)d_ws;
  size_t off = 0;
  auto alloc = [&](size_t n){ float* p = Wp + off; off += n; return p; };
  float* S0    = alloc((size_t)1024*NT);   // wf -> xn -> (P/S/H scan bufs) -> yact
  float* S1    = alloc((size_t)512*NT);    // h -> h3 -> attn
  float* P0    = alloc((size_t)512*NT);    // fused (persistent)
  float* P1    = alloc((size_t)2048*NT);   // h2 (front) -> xz
  float* P2    = alloc((size_t)1024*NT);   // h4 (front) -> xc
  float* P3    = alloc((size_t)1024*NT);   // xcT
  float* P4    = alloc((size_t)4*NT*64);   // xdblT
  float* P5    = alloc((size_t)4*1024*NT); // delta
  float* P6    = alloc((size_t)1024*NT);   // g1 (front) -> ycomb
  float* part  = alloc(1024);
  float* stats = alloc(4);
  float* mu1   = alloc(4096);
  float* rs1   = alloc(4096);
  // total ~47.2M floats = 189 MB

  float* wf    = S0;
  float* h     = S1;
  float* h2    = P1;
  float* h3    = S1;
  float* h4    = P2;
  float* fused = P0;
  float* xn    = S0;
  float* xz    = P1;
  float* xc    = P2;
  float* xcT   = P3;
  float* xdblT = P4;
  float* delta = P5;
  float* g1    = P6;
  float* ycomb = P6;
  float* yact  = S0;
  float* attn  = S1;
  // scan chunk buffers live in S0 (xn is dead after step 9, yact written at 16)
  float* Pbuf  = S0;                       // 4096*NCH*16 = 1M floats
  float* Sbuf  = S0 + (size_t)1048576;
  float* Hbuf  = S0 + (size_t)2*1048576;

  // 1) g1 = gelu(fg1(concat))            M=32, K=1024
  hipLaunchKernelGGL((k_gemm<1,1,false>), dim3(64,1), dim3(256), 0, stream,
      32, 1024, 1024, 0, fg_w1, fg_b1, nullptr, feat, lat, 0,0, nullptr, g1);
  // 2) wf = concat * sigmoid(fg2(g1))    M=1024, K=32
  hipLaunchKernelGGL((k_gemm<0,5,false>), dim3(64,16), dim3(256), 0, stream,
      1024, 32, 32, 0, fg_w2, fg_b2, g1, feat, lat, 0,0, nullptr, wf);
  // 3) h = conv3x3(wf, fb_w1)            M=512, K=9216 (implicit im2col)
  hipLaunchKernelGGL((k_gemm<3,0,false>), dim3(64,8), dim3(256), 0, stream,
      512, 9216, 9216, 0, fb_w1, nullptr, wf, nullptr,nullptr, 0,0, nullptr, h);
  // 4) h2 = gelu(LN_global(h))
  hipLaunchKernelGGL(k_red_part, dim3(512), dim3(256), 0, stream, h, part);
  hipLaunchKernelGGL(k_red_fin,  dim3(1),   dim3(256), 0, stream, part, stats);
  hipLaunchKernelGGL(k_ln_gelu,  dim3(2048),dim3(256), 0, stream, h, ln_g, ln_b, stats, h2);
  // 5) h3 = dwconv3x3 dil2(h2)
  hipLaunchKernelGGL((k_dwconv<2,0>), dim3(512*16), dim3(256), 0, stream, h2, dw_w, dw_b, h3);
  // 6) h4 = gelu(pw1(h3))
  hipLaunchKernelGGL((k_gemm<0,1,false>), dim3(64,8), dim3(256), 0, stream,
      512, 512, 512, 0, pw1_w, pw1_b, h3, nullptr,nullptr, 0,0, nullptr, h4);
  // 7) fused = pw2(shuffle(h4)) + feature
  hipLaunchKernelGGL((k_gemm<0,4,false>), dim3(64,8), dim3(256), 0, stream,
      512, 512, 512, 0, pw2_w, pw2_b, h4, nullptr,nullptr, 0,1, feat, fused);
  // 8) xn = LN_c(fused^T) (NHWC)
  hipLaunchKernelGGL(k_ln1_stats, dim3(64), dim3(256), 0, stream, fused, mu1, rs1);
  hipLaunchKernelGGL(k_ln1_apply, dim3(64,8), dim3(256), 0, stream, fused, ln1_g, ln1_b, mu1, rs1, xn);
  // 9) xz = xn @ in_proj^T               M=2048, K=512, B NHWC
  hipLaunchKernelGGL((k_gemm<2,0,false>), dim3(64,32), dim3(256), 0, stream,
      2048, 512, 512, 512, inpw, nullptr, xn, nullptr,nullptr, 0,0, nullptr, xz);
  // 10) xc = silu(dwconv3x3(xp))
  hipLaunchKernelGGL((k_dwconv<1,1>), dim3(1024*16), dim3(256), 0, stream, xz, dc_w, dc_b, xc);
  // 11) xcT
  hipLaunchKernelGGL(k_transpose64, dim3(1024), dim3(256), 0, stream, xc, xcT);
  // 12) xdblT[k] = (x_proj_w[k] @ xs[k])^T   M=64, K=1024, transposed write
  for (int k=0;k<4;k++){
    hipLaunchKernelGGL((k_gemm<0,0,true>), dim3(64,1), dim3(256), 0, stream,
        64, 1024, 1024, 0, xpw + (size_t)k*64*1024, nullptr, (k&1)? xcT : xc,
        nullptr,nullptr, (k>=2)?1:0, 0, nullptr, xdblT + (size_t)k*NT*64);
  }
  // 13) delta[k] = softplus(dt_w[k] @ dts[k] + dt_b[k])   M=1024, K=32, B NHWC(ld 64)
  for (int k=0;k<4;k++){
    hipLaunchKernelGGL((k_gemm<2,2,false>), dim3(64,16), dim3(256), 0, stream,
        1024, 32, 32, 64, dtw + (size_t)k*1024*32, dtb + (size_t)k*1024,
        xdblT + (size_t)k*NT*64, nullptr,nullptr, 0,0, nullptr,
        delta + (size_t)k*1024*NT);
  }
  // 14) ycomb = 0
  hipLaunchKernelGGL(k_zero, dim3(4096), dim3(256), 0, stream, ycomb);
  // 15) chunked selective scan: partial -> combine -> final
  hipLaunchKernelGGL(k_scan_part, dim3(256*NCH), dim3(64), 0, stream,
      delta, xc, xcT, xdblT, Alog, Pbuf, Sbuf);
  hipLaunchKernelGGL(k_scan_comb, dim3(256), dim3(256), 0, stream, Pbuf, Sbuf, Hbuf);
  hipLaunchKernelGGL(k_scan_fin, dim3(256*NCH), dim3(64), 0, stream,
      delta, xc, xcT, xdblT, Alog, Dsp, Hbuf, ycomb);
  // 16) yact = out_norm(ycomb) * silu(z)
  hipLaunchKernelGGL(k_combine, dim3(4096), dim3(256), 0, stream, ycomb, xz, ong, onb, yact);
  // 17) attn = fused + yact @ out_proj^T   M=512, K=1024, B NHWC
  hipLaunchKernelGGL((k_gemm<2,4,false>), dim3(64,8), dim3(256), 0, stream,
      512, 1024, 1024, 1024, opw, nullptr, yact, nullptr,nullptr, 0,0, fused, attn);
  // 18) out = blur3x3(attn) + fused  -> f32
  hipLaunchKernelGGL(k_blur, dim3(512*16), dim3(256), 0, stream, attn, fused, outp);
}

// Round 8
// 1870.170 us; speedup vs baseline: 1.9831x; 1.0645x over previous
//
#include <hip/hip_runtime.h>

// ---------------------------------------------------------------------------
// FeatureMapApproximator: VMamba-style block. B=1, C=512, H=W=64, L=4096,
// d_inner=1024, K=4 dirs, N=16 states, dt_rank=32.
// All f32. Scan chunked (16x256). conv3x3 GEMM split-K x4 for occupancy.
// ---------------------------------------------------------------------------

#define NT 4096   // pixels (and GEMM N)
#define NCH 16    // scan chunks
#define CHL 256   // chunk length

__device__ __forceinline__ float geluf(float x){ return 0.5f*x*(1.f+erff(x*0.70710678118654752f)); }
__device__ __forceinline__ float sigmf(float x){ return 1.f/(1.f+__expf(-x)); }
__device__ __forceinline__ float softplusf(float x){ return (x>20.f)? x : __logf(1.f+__expf(x)); }

// ---------------------------------------------------------------------------
// Generic tiled GEMM: out[m][n] = epi( sum_k A[m][k]*B[k][n] + bias[m] )
// Tiles: TM=64, TN=64, TK=32, 256 threads, 4x4 acc per thread.
// BMODE 0: B f32 channel-major; rev/shuf remaps. BMODE 1: concat(feat,lat).
// BMODE 2: B f32 NHWC (ldb). BMODE 3: implicit im2col 3x3 pad1 (1024,4096).
// EPI 0 none | 1 gelu | 2 softplus | 4 +f32 res | 5 concat*sigmoid
// TRANSW: write out[n*64+m] via LDS bounce (M==64, EPI 0 only).
// SPLITK: blockIdx.z = K-slice; K = slice len; out += z*M*NT (BMODE3 only).
// ---------------------------------------------------------------------------
template<int BMODE, int EPI, bool TRANSW, bool SPLITK=false>
__launch_bounds__(256)
__global__ void k_gemm(int M, int K, int lda, int ldb,
    const float* __restrict__ A, const float* __restrict__ bias,
    const float* __restrict__ Bf, const float* __restrict__ Bc0,
    const float* __restrict__ Bc1, int rev, int shuf,
    const float* __restrict__ resf, float* __restrict__ out)
{
  __shared__ float smem[4352];           // 2 x [32][68] (or 64x68 for TRANSW)
  float* As = smem;
  float* Bs = smem + 2176;
  const int t  = threadIdx.x;
  const int n0 = blockIdx.x*64, m0 = blockIdx.y*64;
  const int kz = SPLITK ? blockIdx.z : 0;
  const int kab = kz*K;                  // absolute k offset of this slice
  float acc[4][4] = {};

  for (int k0=0; k0<K; k0+=32){
    __syncthreads();
    { // stage A (f32 weights, row-major M x K_total)
      int m = t>>2, kk0 = (t&3)*8;
      float av[8] = {0,0,0,0,0,0,0,0};
      if (m0+m < M){
        const float* pa = A + (size_t)(m0+m)*lda + kab + k0 + kk0;
        float4 a0 = *(const float4*)pa; float4 a1 = *(const float4*)(pa+4);
        av[0]=a0.x; av[1]=a0.y; av[2]=a0.z; av[3]=a0.w;
        av[4]=a1.x; av[5]=a1.y; av[6]=a1.z; av[7]=a1.w;
      }
      #pragma unroll
      for (int j=0;j<8;j++) As[(kk0+j)*68 + m] = av[j];
    }
    if (BMODE==2){
      int n = t>>2, kk0 = (t&3)*8;
      const float* p = Bf + (size_t)(n0+n)*ldb + k0 + kk0;
      float4 x0 = *(const float4*)p; float4 x1 = *(const float4*)(p+4);
      Bs[(kk0+0)*68+n]=x0.x; Bs[(kk0+1)*68+n]=x0.y; Bs[(kk0+2)*68+n]=x0.z; Bs[(kk0+3)*68+n]=x0.w;
      Bs[(kk0+4)*68+n]=x1.x; Bs[(kk0+5)*68+n]=x1.y; Bs[(kk0+6)*68+n]=x1.z; Bs[(kk0+7)*68+n]=x1.w;
    } else {
      int kk = t>>3, n8 = (t&7)*8;
      float bv[8];
      if (BMODE==0){
        int r = k0+kk; if (shuf) r = (r&7)*64 + (r>>3);
        const float* p = Bf + (size_t)r*NT;
        if (!rev){
          float4 x0 = *(const float4*)(p + n0+n8); float4 x1 = *(const float4*)(p + n0+n8+4);
          bv[0]=x0.x;bv[1]=x0.y;bv[2]=x0.z;bv[3]=x0.w;bv[4]=x1.x;bv[5]=x1.y;bv[6]=x1.z;bv[7]=x1.w;
        } else {
          const float* q = p + (4088 - n0 - n8);
          float4 x0 = *(const float4*)q; float4 x1 = *(const float4*)(q+4);
          bv[0]=x1.w;bv[1]=x1.z;bv[2]=x1.y;bv[3]=x1.x;bv[4]=x0.w;bv[5]=x0.z;bv[6]=x0.y;bv[7]=x0.x;
        }
      } else if (BMODE==1){
        int c = k0+kk;
        const float* p = (c<512) ? (Bc0 + (size_t)c*NT) : (Bc1 + (size_t)(c-512)*NT);
        float4 x0 = *(const float4*)(p + n0+n8); float4 x1 = *(const float4*)(p + n0+n8+4);
        bv[0]=x0.x;bv[1]=x0.y;bv[2]=x0.z;bv[3]=x0.w;bv[4]=x1.x;bv[5]=x1.y;bv[6]=x1.z;bv[7]=x1.w;
      } else { // BMODE==3
        int k = kab + k0 + kk; int c = k/9; int t9 = k - c*9; int qy = t9/3;
        int dy = qy-1, dx = t9 - qy*3 - 1;
        int y = (n0>>6) + dy;               // n-tile is one image row
        bool yok = (y>=0)&&(y<64);
        const float* p = Bf + (size_t)c*NT + y*64;
        #pragma unroll
        for (int j=0;j<8;j++){
          int x = n8 + j + dx;
          bv[j] = (yok && x>=0 && x<64) ? p[x] : 0.f;
        }
      }
      *(float4*)&Bs[kk*68 + n8]   = make_float4(bv[0],bv[1],bv[2],bv[3]);
      *(float4*)&Bs[kk*68 + n8+4] = make_float4(bv[4],bv[5],bv[6],bv[7]);
    }
    __syncthreads();
    int ti = t>>4, tj = t&15;
    #pragma unroll
    for (int kk=0; kk<32; kk++){
      float4 a4 = *(const float4*)&As[kk*68 + ti*4];
      float4 b4 = *(const float4*)&Bs[kk*68 + tj*4];
      float aa[4] = {a4.x,a4.y,a4.z,a4.w};
      float bb[4] = {b4.x,b4.y,b4.z,b4.w};
      #pragma unroll
      for (int i=0;i<4;i++)
        #pragma unroll
        for (int j=0;j<4;j++) acc[i][j] += aa[i]*bb[j];
    }
  }

  int ti = t>>4, tj = t&15;
  if (!TRANSW){
    float* op = out + (SPLITK ? (size_t)kz*M*NT : 0);
    #pragma unroll
    for (int i=0;i<4;i++){
      int m = m0 + ti*4 + i;
      if (m >= M) continue;
      float bi = bias ? bias[m] : 0.f;
      float o4[4];
      #pragma unroll
      for (int j=0;j<4;j++){
        int n = n0 + tj*4 + j;
        float v = acc[i][j] + bi;
        if (EPI==1) v = geluf(v);
        else if (EPI==2) v = softplusf(v);
        else if (EPI==4) v = v + resf[(size_t)m*NT + n];
        else if (EPI==5){
          float cv = (m<512)? Bc0[(size_t)m*NT+n] : Bc1[(size_t)(m-512)*NT+n];
          v = cv * sigmf(v);
        }
        o4[j] = v;
      }
      *(float4*)&op[(size_t)m*NT + n0 + tj*4] = make_float4(o4[0],o4[1],o4[2],o4[3]);
    }
  } else {
    __syncthreads();
    #pragma unroll
    for (int i=0;i<4;i++)
      #pragma unroll
      for (int j=0;j<4;j++)
        smem[(tj*4+j)*68 + (ti*4+i)] = acc[i][j];
    __syncthreads();
    int nl = t>>2, c0 = (t&3)*16;
    #pragma unroll
    for (int g4=0; g4<4; g4++){
      float4 v = *(const float4*)&smem[nl*68 + c0 + g4*4];
      *(float4*)&out[(size_t)(n0+nl)*64 + c0 + g4*4] = v;
    }
  }
}

// ---------------------------------------------------------------------------
// Depthwise 3x3 conv (dilated), optional SiLU. grid = C*16, block 256.
template<int DIL, int ACT>
__global__ void k_dwconv(const float* __restrict__ in, const float* __restrict__ w,
                         const float* __restrict__ b, float* __restrict__ out){
  int bid = blockIdx.x;
  int c = bid >> 4, yb = bid & 15;
  int t = threadIdx.x;
  int y = yb*4 + (t>>6), x = t&63;
  const float* pin = in + (size_t)c*NT;
  float acc = b[c];
  #pragma unroll
  for (int ky=0; ky<3; ky++){
    int yy = y + DIL*(ky-1);
    if (yy<0 || yy>=64) continue;
    #pragma unroll
    for (int kx=0; kx<3; kx++){
      int xx = x + DIL*(kx-1);
      if (xx<0 || xx>=64) continue;
      acc += w[c*9 + ky*3 + kx] * pin[yy*64+xx];
    }
  }
  if (ACT==1) acc = acc * sigmf(acc);
  out[(size_t)c*NT + y*64 + x] = acc;
}

// ---------------------------------------------------------------------------
// Global LN: sum 4 split-K partials -> h, partial stats -> final -> apply(gelu)
__global__ void k_red_part4(const float* __restrict__ hp, float* __restrict__ h,
                            float* __restrict__ part){
  __shared__ float ls[256], lq[256];
  int t = threadIdx.x; size_t base = (size_t)blockIdx.x*4096 + t;
  const size_t SL = (size_t)512*4096;
  float s=0, q=0;
  #pragma unroll
  for (int i=0;i<16;i++){
    size_t idx = base + i*256;
    float v = hp[idx] + hp[idx+SL] + hp[idx+2*SL] + hp[idx+3*SL];
    h[idx] = v; s+=v; q+=v*v;
  }
  ls[t]=s; lq[t]=q; __syncthreads();
  for (int off=128; off; off>>=1){ if (t<off){ ls[t]+=ls[t+off]; lq[t]+=lq[t+off]; } __syncthreads(); }
  if (t==0){ part[blockIdx.x] = ls[0]; part[512 + blockIdx.x] = lq[0]; }
}
__global__ void k_red_fin(const float* __restrict__ part, float* __restrict__ stats){
  __shared__ float ls[256], lq[256];
  int t = threadIdx.x;
  ls[t] = part[t] + part[t+256];
  lq[t] = part[512+t] + part[768+t];
  __syncthreads();
  for (int off=128; off; off>>=1){ if (t<off){ ls[t]+=ls[t+off]; lq[t]+=lq[t+off]; } __syncthreads(); }
  if (t==0){
    float mu = ls[0] * (1.f/2097152.f);
    float var = lq[0]*(1.f/2097152.f) - mu*mu;
    stats[0]=mu; stats[1]=rsqrtf(var + 1e-5f);
  }
}
__global__ void k_ln_gelu(const float* __restrict__ h, const float* __restrict__ g,
                          const float* __restrict__ b, const float* __restrict__ stats,
                          float* __restrict__ out){
  size_t idx = ((size_t)blockIdx.x*256 + threadIdx.x)*4;
  float mu = stats[0], rs = stats[1];
  float4 hv = *(const float4*)(h + idx);
  float4 gv = *(const float4*)(g + idx);
  float4 bv = *(const float4*)(b + idx);
  float4 o;
  o.x = geluf((hv.x-mu)*rs*gv.x+bv.x);
  o.y = geluf((hv.y-mu)*rs*gv.y+bv.y);
  o.z = geluf((hv.z-mu)*rs*gv.z+bv.z);
  o.w = geluf((hv.w-mu)*rs*gv.w+bv.w);
  *(float4*)(out + idx) = o;
}

// ---------------------------------------------------------------------------
// Per-pixel LN over C=512 (stats), then apply+transpose to NHWC xn(4096,512)
__global__ void k_ln1_stats(const float* __restrict__ fused, float* __restrict__ mu1,
                            float* __restrict__ rs1){
  __shared__ float ss[256], sq[256];
  int t = threadIdx.x; int ci = t>>6; int pj = t&63;
  int pos = blockIdx.x*64 + pj;
  float s=0,q=0;
  for (int c=ci; c<512; c+=4){ float v = fused[(size_t)c*NT + pos]; s+=v; q+=v*v; }
  ss[t]=s; sq[t]=q; __syncthreads();
  if (ci==0){
    float S = ss[pj]+ss[64+pj]+ss[128+pj]+ss[192+pj];
    float Q = sq[pj]+sq[64+pj]+sq[128+pj]+sq[192+pj];
    float mu = S*(1.f/512.f);
    mu1[pos]=mu; rs1[pos]=rsqrtf(Q*(1.f/512.f) - mu*mu + 1e-5f);
  }
}
__global__ void k_ln1_apply(const float* __restrict__ fused, const float* __restrict__ g,
                            const float* __restrict__ b, const float* __restrict__ mu1,
                            const float* __restrict__ rs1, float* __restrict__ xn){
  __shared__ float tile[64*65];
  int t = threadIdx.x;
  int p0 = blockIdx.x*64, c0 = blockIdx.y*64;
  for (int it=0; it<16; it++){
    int idx = t + it*256; int yy = idx>>6, xx = idx&63;  // yy=c-local, xx=p-local
    tile[yy*65+xx] = fused[(size_t)(c0+yy)*NT + p0+xx];
  }
  __syncthreads();
  for (int it=0; it<16; it++){
    int idx = t + it*256; int r = idx>>6, s = idx&63;    // r=p-local, s=c-local
    float v = tile[s*65+r];
    int pos = p0+r, c = c0+s;
    xn[(size_t)pos*512 + c] = (v - mu1[pos])*rs1[pos]*g[c] + b[c];
  }
}

// ---------------------------------------------------------------------------
// Per-channel 64x64 transpose: out[d][w*64+h] = in[d][h*64+w]. grid=1024.
__global__ void k_transpose64(const float* __restrict__ in, float* __restrict__ out){
  __shared__ float tile[64*65];
  int d = blockIdx.x; int t = threadIdx.x;
  const float* p = in + (size_t)d*NT; float* q = out + (size_t)d*NT;
  for (int it=0; it<16; it++){
    int idx = t+it*256; int yy = idx>>6, xx = idx&63;
    tile[yy*65+xx] = p[idx];
  }
  __syncthreads();
  for (int it=0; it<16; it++){
    int idx = t+it*256; int w = idx>>6, hh = idx&63;
    q[idx] = tile[hh*65+w];
  }
}

// ---------------------------------------------------------------------------
__global__ void k_zero(float* __restrict__ p){
  size_t i = ((size_t)blockIdx.x*256 + threadIdx.x)*4;
  *(float4*)(p+i) = make_float4(0,0,0,0);
}

// ---------------------------------------------------------------------------
// Chunked selective scan, phase A: per (scanset, chunk) compute
//   P = prod(dA) and S = chunk-local state (h0=0) for each state.
// grid = 256 scansets * NCH chunks, block = 64 (16 d x 4 ngrp x 4 states).
__launch_bounds__(64)
__global__ void k_scan_part(const float* __restrict__ delta, const float* __restrict__ xc,
                            const float* __restrict__ xcT, const float* __restrict__ xdblT,
                            const float* __restrict__ A_logs,
                            float* __restrict__ Pbuf, float* __restrict__ Sbuf){
  int bid = blockIdx.x;
  int ss = bid >> 4;              // scanset 0..255
  int c  = bid & (NCH-1);         // chunk
  int k = ss >> 6;
  int dbase = (ss & 63)*16;
  int lane = threadIdx.x;
  int dsub = lane & 15, ngrp = lane >> 4;
  int d = dbase + dsub;
  const float* up = ((k&1)? xcT : xc) + (size_t)d*NT;
  const float* dp = delta + ((size_t)(k*1024 + d))*NT;
  const float* bc = xdblT + (size_t)k*NT*64;
  float A[4], S[4]={0,0,0,0}, P[4]={1.f,1.f,1.f,1.f};
  #pragma unroll
  for (int j=0;j<4;j++) A[j] = -__expf(A_logs[(size_t)(k*1024+d)*16 + ngrp*4 + j]);
  const bool rv = (k>=2);
  int base = c*CHL;
  for (int l0=base; l0<base+CHL; l0+=4){
    float4 dv4 = *(const float4*)(dp + l0);
    float4 uraw = rv ? *(const float4*)(up + (4092-l0)) : *(const float4*)(up + l0);
    float dts[4] = {dv4.x,dv4.y,dv4.z,dv4.w};
    float us[4];
    if (rv){ us[0]=uraw.w; us[1]=uraw.z; us[2]=uraw.y; us[3]=uraw.x; }
    else   { us[0]=uraw.x; us[1]=uraw.y; us[2]=uraw.z; us[3]=uraw.w; }
    #pragma unroll
    for (int s=0;s<4;s++){
      int l = l0+s;
      float dt = dts[s];
      float4 B4 = *(const float4*)(bc + (size_t)l*64 + 32 + ngrp*4);
      float xbu = dt*us[s];
      float Bv[4]={B4.x,B4.y,B4.z,B4.w};
      #pragma unroll
      for (int j=0;j<4;j++){
        float dA = __expf(dt*A[j]);
        S[j] = dA*S[j] + xbu*Bv[j];
        P[j] *= dA;
      }
    }
  }
  size_t o = ((size_t)(k*1024+d)*NCH + c)*16 + ngrp*4;
  *(float4*)&Pbuf[o] = make_float4(P[0],P[1],P[2],P[3]);
  *(float4*)&Sbuf[o] = make_float4(S[0],S[1],S[2],S[3]);
}

// ---------------------------------------------------------------------------
// Phase B: serial combine over chunks. thread = one (scan, state).
// Hbuf[scan][c][n] = h_in at chunk c. grid=256, block=256 (64K threads).
__global__ void k_scan_comb(const float* __restrict__ Pbuf, const float* __restrict__ Sbuf,
                            float* __restrict__ Hbuf){
  int tid = blockIdx.x*256 + threadIdx.x;
  int scan = tid >> 4, n = tid & 15;
  size_t base = (size_t)scan*(NCH*16) + n;
  float h = 0.f;
  #pragma unroll
  for (int c=0;c<NCH;c++){
    Hbuf[base + c*16] = h;
    h = Pbuf[base + c*16]*h + Sbuf[base + c*16];
  }
}

// ---------------------------------------------------------------------------
// Phase C: re-run chunk from h_in, compute y, atomicAdd into ycomb(l,d).
// grid = 256 scansets * NCH, block = 64.
__launch_bounds__(64)
__global__ void k_scan_fin(const float* __restrict__ delta, const float* __restrict__ xc,
                           const float* __restrict__ xcT, const float* __restrict__ xdblT,
                           const float* __restrict__ A_logs, const float* __restrict__ Ds,
                           const float* __restrict__ Hbuf, float* __restrict__ ycomb){
  int bid = blockIdx.x;
  int ss = bid >> 4;
  int c  = bid & (NCH-1);
  int k = ss >> 6;
  int dbase = (ss & 63)*16;
  int lane = threadIdx.x;
  int dsub = lane & 15, ngrp = lane >> 4;
  int d = dbase + dsub;
  const float* up = ((k&1)? xcT : xc) + (size_t)d*NT;
  const float* dp = delta + ((size_t)(k*1024 + d))*NT;
  const float* bc = xdblT + (size_t)k*NT*64;
  float A[4], h[4];
  #pragma unroll
  for (int j=0;j<4;j++) A[j] = -__expf(A_logs[(size_t)(k*1024+d)*16 + ngrp*4 + j]);
  {
    size_t o = ((size_t)(k*1024+d)*NCH + c)*16 + ngrp*4;
    float4 h4 = *(const float4*)&Hbuf[o];
    h[0]=h4.x; h[1]=h4.y; h[2]=h4.z; h[3]=h4.w;
  }
  float Dv = Ds[k*1024+d];
  const bool rv = (k>=2);
  int base = c*CHL;
  for (int l0=base; l0<base+CHL; l0+=4){
    float4 dv4 = *(const float4*)(dp + l0);
    float4 uraw = rv ? *(const float4*)(up + (4092-l0)) : *(const float4*)(up + l0);
    float dts[4] = {dv4.x,dv4.y,dv4.z,dv4.w};
    float us[4];
    if (rv){ us[0]=uraw.w; us[1]=uraw.z; us[2]=uraw.y; us[3]=uraw.x; }
    else   { us[0]=uraw.x; us[1]=uraw.y; us[2]=uraw.z; us[3]=uraw.w; }
    #pragma unroll
    for (int s=0;s<4;s++){
      int l = l0+s;
      float dt = dts[s], u = us[s];
      float4 B4 = *(const float4*)(bc + (size_t)l*64 + 32 + ngrp*4);
      float4 C4 = *(const float4*)(bc + (size_t)l*64 + 48 + ngrp*4);
      float xbu = dt*u;
      float Bv[4]={B4.x,B4.y,B4.z,B4.w}, Cv[4]={C4.x,C4.y,C4.z,C4.w};
      float ys = 0.f;
      #pragma unroll
      for (int j=0;j<4;j++){
        float dA = __expf(dt*A[j]);
        h[j] = dA*h[j] + xbu*Bv[j];
        ys += h[j]*Cv[j];
      }
      ys += __shfl_xor(ys, 16);
      ys += __shfl_xor(ys, 32);
      if (ngrp==0){
        int pos;
        if (k==0) pos = l;
        else if (k==1) pos = ((l&63)<<6) | (l>>6);
        else if (k==2) pos = 4095-l;
        else { int tt = 4095-l; pos = ((tt&63)<<6) | (tt>>6); }
        atomicAdd(&ycomb[(size_t)pos*1024 + d], ys + Dv*u);
      }
    }
  }
}

// ---------------------------------------------------------------------------
// Combine: per-pixel LN over 1024 dirs-summed y, gate with silu(z) -> yact(l,d)
__global__ void k_combine(const float* __restrict__ ycomb, const float* __restrict__ xz,
                          const float* __restrict__ g, const float* __restrict__ b,
                          float* __restrict__ yact){
  int pos = blockIdx.x, t = threadIdx.x;
  float v[4]; float s=0,q=0;
  #pragma unroll
  for (int i=0;i<4;i++){ v[i] = ycomb[(size_t)pos*1024 + t + i*256]; s+=v[i]; q+=v[i]*v[i]; }
  #pragma unroll
  for (int off=32; off>=1; off>>=1){ s += __shfl_xor(s,off); q += __shfl_xor(q,off); }
  __shared__ float red[8];
  int wid = t>>6;
  if ((t&63)==0){ red[wid*2]=s; red[wid*2+1]=q; }
  __syncthreads();
  float S = red[0]+red[2]+red[4]+red[6];
  float Q = red[1]+red[3]+red[5]+red[7];
  float mu = S*(1.f/1024.f), rs = rsqrtf(Q*(1.f/1024.f) - mu*mu + 1e-5f);
  #pragma unroll
  for (int i=0;i<4;i++){
    int dd = t + i*256;
    float z = xz[(size_t)(1024+dd)*NT + pos];
    float yv = (v[i]-mu)*rs*g[dd] + b[dd];
    yact[(size_t)pos*1024 + dd] = yv * (z * sigmf(z));
  }
}

// ---------------------------------------------------------------------------
// Final: out = avgblur3x3(attn) + fused, f32. grid=512*16.
__global__ void k_blur(const float* __restrict__ attn, const float* __restrict__ fused,
                       float* __restrict__ outp){
  int bid = blockIdx.x; int c = bid>>4, yb = bid&15; int t = threadIdx.x;
  int y = yb*4 + (t>>6), x = t&63;
  const float* p = attn + (size_t)c*NT;
  float s = 0;
  #pragma unroll
  for (int dy=-1; dy<=1; dy++){
    int yy = y+dy; if (yy<0||yy>=64) continue;
    #pragma unroll
    for (int dx=-1; dx<=1; dx++){
      int xx = x+dx; if (xx<0||xx>=64) continue;
      s += p[yy*64+xx];
    }
  }
  float val = s*(1.f/9.f) + fused[(size_t)c*NT + y*64 + x];
  outp[(size_t)c*NT + y*64 + x] = val;
}

// ---------------------------------------------------------------------------
extern "C" void kernel_launch(void* const* d_in, const int* in_sizes, int n_in,
                              void* d_out, int out_size, void* d_ws, size_t ws_size,
                              hipStream_t stream){
  const float* feat = (const float*)d_in[0];
  const float* lat  = (const float*)d_in[1];
  const float* fg_w1= (const float*)d_in[2];
  const float* fg_b1= (const float*)d_in[3];
  const float* fg_w2= (const float*)d_in[4];
  const float* fg_b2= (const float*)d_in[5];
  const float* fb_w1= (const float*)d_in[6];
  const float* ln_g = (const float*)d_in[7];
  const float* ln_b = (const float*)d_in[8];
  const float* dw_w = (const float*)d_in[9];
  const float* dw_b = (const float*)d_in[10];
  const float* pw1_w= (const float*)d_in[11];
  const float* pw1_b= (const float*)d_in[12];
  const float* pw2_w= (const float*)d_in[13];
  const float* pw2_b= (const float*)d_in[14];
  const float* ln1_g= (const float*)d_in[15];
  const float* ln1_b= (const float*)d_in[16];
  const float* inpw = (const float*)d_in[17];
  const float* dc_w = (const float*)d_in[18];
  const float* dc_b = (const float*)d_in[19];
  const float* xpw  = (const float*)d_in[20];
  const float* dtw  = (const float*)d_in[21];
  const float* dtb  = (const float*)d_in[22];
  const float* Alog = (const float*)d_in[23];
  const float* Dsp  = (const float*)d_in[24];
  const float* ong  = (const float*)d_in[25];
  const float* onb  = (const float*)d_in[26];
  const float* opw  = (const float*)d_in[27];
  float* outp = (float*)d_out;
  (void)in_sizes; (void)n_in; (void)out_size; (void)ws_size;

  // ---- workspace regions with reuse (sizes in floats) ------------------
  float* Wp = (float*)d_ws;
  size_t off = 0;
  auto alloc = [&](size_t n){ float* p = Wp + off; off += n; return p; };
  float* S0    = alloc((size_t)1024*NT);   // wf -> xn -> (P/S/H scan bufs) -> yact
  float* S1    = alloc((size_t)512*NT);    // h -> h3 -> attn
  float* P0    = alloc((size_t)512*NT);    // fused (persistent)
  float* P1    = alloc((size_t)2048*NT);   // h2 (front) -> xz
  float* P2    = alloc((size_t)1024*NT);   // h4 (front) -> xc
  float* P3    = alloc((size_t)1024*NT);   // xcT
  float* P4    = alloc((size_t)4*NT*64);   // xdblT
  float* P5    = alloc((size_t)4*1024*NT); // hpart (conv split-K) -> delta
  float* P6    = alloc((size_t)1024*NT);   // g1 (front) -> ycomb
  float* part  = alloc(1024);
  float* stats = alloc(4);
  float* mu1   = alloc(4096);
  float* rs1   = alloc(4096);
  // total ~47.2M floats = 189 MB

  float* wf    = S0;
  float* h     = S1;
  float* h2    = P1;
  float* h3    = S1;
  float* h4    = P2;
  float* fused = P0;
  float* xn    = S0;
  float* xz    = P1;
  float* xc    = P2;
  float* xcT   = P3;
  float* xdblT = P4;
  float* hpart = P5;                       // 4 x 512 x 4096 split-K partials
  float* delta = P5;
  float* g1    = P6;
  float* ycomb = P6;
  float* yact  = S0;
  float* attn  = S1;
  // scan chunk buffers live in S0 (xn is dead after step 9, yact written at 16)
  float* Pbuf  = S0;                       // 4096*NCH*16 = 1M floats
  float* Sbuf  = S0 + (size_t)1048576;
  float* Hbuf  = S0 + (size_t)2*1048576;

  // 1) g1 = gelu(fg1(concat))            M=32, K=1024
  hipLaunchKernelGGL((k_gemm<1,1,false>), dim3(64,1), dim3(256), 0, stream,
      32, 1024, 1024, 0, fg_w1, fg_b1, nullptr, feat, lat, 0,0, nullptr, g1);
  // 2) wf = concat * sigmoid(fg2(g1))    M=1024, K=32
  hipLaunchKernelGGL((k_gemm<0,5,false>), dim3(64,16), dim3(256), 0, stream,
      1024, 32, 32, 0, fg_w2, fg_b2, g1, feat, lat, 0,0, nullptr, wf);
  // 3) hpart[z] = conv3x3 partial (split-K x4: 2304 each)  M=512
  hipLaunchKernelGGL((k_gemm<3,0,false,true>), dim3(64,8,4), dim3(256), 0, stream,
      512, 2304, 9216, 0, fb_w1, nullptr, wf, nullptr,nullptr, 0,0, nullptr, hpart);
  // 4) h = sum(hpart) ; h2 = gelu(LN_global(h))
  hipLaunchKernelGGL(k_red_part4, dim3(512), dim3(256), 0, stream, hpart, h, part);
  hipLaunchKernelGGL(k_red_fin,  dim3(1),   dim3(256), 0, stream, part, stats);
  hipLaunchKernelGGL(k_ln_gelu,  dim3(2048),dim3(256), 0, stream, h, ln_g, ln_b, stats, h2);
  // 5) h3 = dwconv3x3 dil2(h2)
  hipLaunchKernelGGL((k_dwconv<2,0>), dim3(512*16), dim3(256), 0, stream, h2, dw_w, dw_b, h3);
  // 6) h4 = gelu(pw1(h3))
  hipLaunchKernelGGL((k_gemm<0,1,false>), dim3(64,8), dim3(256), 0, stream,
      512, 512, 512, 0, pw1_w, pw1_b, h3, nullptr,nullptr, 0,0, nullptr, h4);
  // 7) fused = pw2(shuffle(h4)) + feature
  hipLaunchKernelGGL((k_gemm<0,4,false>), dim3(64,8), dim3(256), 0, stream,
      512, 512, 512, 0, pw2_w, pw2_b, h4, nullptr,nullptr, 0,1, feat, fused);
  // 8) xn = LN_c(fused^T) (NHWC)
  hipLaunchKernelGGL(k_ln1_stats, dim3(64), dim3(256), 0, stream, fused, mu1, rs1);
  hipLaunchKernelGGL(k_ln1_apply, dim3(64,8), dim3(256), 0, stream, fused, ln1_g, ln1_b, mu1, rs1, xn);
  // 9) xz = xn @ in_proj^T               M=2048, K=512, B NHWC
  hipLaunchKernelGGL((k_gemm<2,0,false>), dim3(64,32), dim3(256), 0, stream,
      2048, 512, 512, 512, inpw, nullptr, xn, nullptr,nullptr, 0,0, nullptr, xz);
  // 10) xc = silu(dwconv3x3(xp))
  hipLaunchKernelGGL((k_dwconv<1,1>), dim3(1024*16), dim3(256), 0, stream, xz, dc_w, dc_b, xc);
  // 11) xcT
  hipLaunchKernelGGL(k_transpose64, dim3(1024), dim3(256), 0, stream, xc, xcT);
  // 12) xdblT[k] = (x_proj_w[k] @ xs[k])^T   M=64, K=1024, transposed write
  for (int k=0;k<4;k++){
    hipLaunchKernelGGL((k_gemm<0,0,true>), dim3(64,1), dim3(256), 0, stream,
        64, 1024, 1024, 0, xpw + (size_t)k*64*1024, nullptr, (k&1)? xcT : xc,
        nullptr,nullptr, (k>=2)?1:0, 0, nullptr, xdblT + (size_t)k*NT*64);
  }
  // 13) delta[k] = softplus(dt_w[k] @ dts[k] + dt_b[k])   M=1024, K=32, B NHWC(ld 64)
  for (int k=0;k<4;k++){
    hipLaunchKernelGGL((k_gemm<2,2,false>), dim3(64,16), dim3(256), 0, stream,
        1024, 32, 32, 64, dtw + (size_t)k*1024*32, dtb + (size_t)k*1024,
        xdblT + (size_t)k*NT*64, nullptr,nullptr, 0,0, nullptr,
        delta + (size_t)k*1024*NT);
  }
  // 14) ycomb = 0
  hipLaunchKernelGGL(k_zero, dim3(4096), dim3(256), 0, stream, ycomb);
  // 15) chunked selective scan: partial -> combine -> final
  hipLaunchKernelGGL(k_scan_part, dim3(256*NCH), dim3(64), 0, stream,
      delta, xc, xcT, xdblT, Alog, Pbuf, Sbuf);
  hipLaunchKernelGGL(k_scan_comb, dim3(256), dim3(256), 0, stream, Pbuf, Sbuf, Hbuf);
  hipLaunchKernelGGL(k_scan_fin, dim3(256*NCH), dim3(64), 0, stream,
      delta, xc, xcT, xdblT, Alog, Dsp, Hbuf, ycomb);
  // 16) yact = out_norm(ycomb) * silu(z)
  hipLaunchKernelGGL(k_combine, dim3(4096), dim3(256), 0, stream, ycomb, xz, ong, onb, yact);
  // 17) attn = fused + yact @ out_proj^T   M=512, K=1024, B NHWC
  hipLaunchKernelGGL((k_gemm<2,4,false>), dim3(64,8), dim3(256), 0, stream,
      512, 1024, 1024, 1024, opw, nullptr, yact, nullptr,nullptr, 0,0, fused, attn);
  // 18) out = blur3x3(attn) + fused  -> f32
  hipLaunchKernelGGL(k_blur, dim3(512*16), dim3(256), 0, stream, attn, fused, outp);
}

// Round 9
// 1448.676 us; speedup vs baseline: 2.5600x; 1.2910x over previous
//
#include <hip/hip_runtime.h>

// ---------------------------------------------------------------------------
// FeatureMapApproximator: VMamba-style block. B=1, C=512, H=W=64, L=4096,
// d_inner=1024, K=4 dirs, N=16 states, dt_rank=32.
// f32 pipeline; conv3x3 runs on bf16 MFMA (16x16x32), split-K x8, f32 partials.
// ---------------------------------------------------------------------------

#define NT 4096   // pixels (and GEMM N)
#define NCH 16    // scan chunks
#define CHL 256   // chunk length

__device__ __forceinline__ float geluf(float x){ return 0.5f*x*(1.f+erff(x*0.70710678118654752f)); }
__device__ __forceinline__ float sigmf(float x){ return 1.f/(1.f+__expf(-x)); }
__device__ __forceinline__ float softplusf(float x){ return (x>20.f)? x : __logf(1.f+__expf(x)); }
__device__ __forceinline__ unsigned short f2b(float f){
  unsigned u = __float_as_uint(f);
  u += 0x7FFFu + ((u>>16)&1u);          // RNE
  return (unsigned short)(u>>16);
}

// ---------------------------------------------------------------------------
// Generic tiled GEMM (f32): out[m][n] = epi( sum_k A[m][k]*B[k][n] + bias[m] )
// TM=64, TN=64, TK=32, 256 threads, 4x4 acc. BMODEs/EPIs as before.
// ---------------------------------------------------------------------------
template<int BMODE, int EPI, bool TRANSW>
__launch_bounds__(256)
__global__ void k_gemm(int M, int K, int lda, int ldb,
    const float* __restrict__ A, const float* __restrict__ bias,
    const float* __restrict__ Bf, const float* __restrict__ Bc0,
    const float* __restrict__ Bc1, int rev, int shuf,
    const float* __restrict__ resf, float* __restrict__ out)
{
  __shared__ float smem[4352];           // 2 x [32][68] (or 64x68 for TRANSW)
  float* As = smem;
  float* Bs = smem + 2176;
  const int t  = threadIdx.x;
  const int n0 = blockIdx.x*64, m0 = blockIdx.y*64;
  float acc[4][4] = {};

  for (int k0=0; k0<K; k0+=32){
    __syncthreads();
    { // stage A (f32 weights, row-major M x K)
      int m = t>>2, kk0 = (t&3)*8;
      float av[8] = {0,0,0,0,0,0,0,0};
      if (m0+m < M){
        const float* pa = A + (size_t)(m0+m)*lda + k0 + kk0;
        float4 a0 = *(const float4*)pa; float4 a1 = *(const float4*)(pa+4);
        av[0]=a0.x; av[1]=a0.y; av[2]=a0.z; av[3]=a0.w;
        av[4]=a1.x; av[5]=a1.y; av[6]=a1.z; av[7]=a1.w;
      }
      #pragma unroll
      for (int j=0;j<8;j++) As[(kk0+j)*68 + m] = av[j];
    }
    if (BMODE==2){
      int n = t>>2, kk0 = (t&3)*8;
      const float* p = Bf + (size_t)(n0+n)*ldb + k0 + kk0;
      float4 x0 = *(const float4*)p; float4 x1 = *(const float4*)(p+4);
      Bs[(kk0+0)*68+n]=x0.x; Bs[(kk0+1)*68+n]=x0.y; Bs[(kk0+2)*68+n]=x0.z; Bs[(kk0+3)*68+n]=x0.w;
      Bs[(kk0+4)*68+n]=x1.x; Bs[(kk0+5)*68+n]=x1.y; Bs[(kk0+6)*68+n]=x1.z; Bs[(kk0+7)*68+n]=x1.w;
    } else {
      int kk = t>>3, n8 = (t&7)*8;
      float bv[8];
      if (BMODE==0){
        int r = k0+kk; if (shuf) r = (r&7)*64 + (r>>3);
        const float* p = Bf + (size_t)r*NT;
        if (!rev){
          float4 x0 = *(const float4*)(p + n0+n8); float4 x1 = *(const float4*)(p + n0+n8+4);
          bv[0]=x0.x;bv[1]=x0.y;bv[2]=x0.z;bv[3]=x0.w;bv[4]=x1.x;bv[5]=x1.y;bv[6]=x1.z;bv[7]=x1.w;
        } else {
          const float* q = p + (4088 - n0 - n8);
          float4 x0 = *(const float4*)q; float4 x1 = *(const float4*)(q+4);
          bv[0]=x1.w;bv[1]=x1.z;bv[2]=x1.y;bv[3]=x1.x;bv[4]=x0.w;bv[5]=x0.z;bv[6]=x0.y;bv[7]=x0.x;
        }
      } else if (BMODE==1){
        int c = k0+kk;
        const float* p = (c<512) ? (Bc0 + (size_t)c*NT) : (Bc1 + (size_t)(c-512)*NT);
        float4 x0 = *(const float4*)(p + n0+n8); float4 x1 = *(const float4*)(p + n0+n8+4);
        bv[0]=x0.x;bv[1]=x0.y;bv[2]=x0.z;bv[3]=x0.w;bv[4]=x1.x;bv[5]=x1.y;bv[6]=x1.z;bv[7]=x1.w;
      } else { // BMODE==3 (unused now)
        #pragma unroll
        for (int j=0;j<8;j++) bv[j] = 0.f;
      }
      *(float4*)&Bs[kk*68 + n8]   = make_float4(bv[0],bv[1],bv[2],bv[3]);
      *(float4*)&Bs[kk*68 + n8+4] = make_float4(bv[4],bv[5],bv[6],bv[7]);
    }
    __syncthreads();
    int ti = t>>4, tj = t&15;
    #pragma unroll
    for (int kk=0; kk<32; kk++){
      float4 a4 = *(const float4*)&As[kk*68 + ti*4];
      float4 b4 = *(const float4*)&Bs[kk*68 + tj*4];
      float aa[4] = {a4.x,a4.y,a4.z,a4.w};
      float bb[4] = {b4.x,b4.y,b4.z,b4.w};
      #pragma unroll
      for (int i=0;i<4;i++)
        #pragma unroll
        for (int j=0;j<4;j++) acc[i][j] += aa[i]*bb[j];
    }
  }

  int ti = t>>4, tj = t&15;
  if (!TRANSW){
    #pragma unroll
    for (int i=0;i<4;i++){
      int m = m0 + ti*4 + i;
      if (m >= M) continue;
      float bi = bias ? bias[m] : 0.f;
      float o4[4];
      #pragma unroll
      for (int j=0;j<4;j++){
        int n = n0 + tj*4 + j;
        float v = acc[i][j] + bi;
        if (EPI==1) v = geluf(v);
        else if (EPI==2) v = softplusf(v);
        else if (EPI==4) v = v + resf[(size_t)m*NT + n];
        else if (EPI==5){
          float cv = (m<512)? Bc0[(size_t)m*NT+n] : Bc1[(size_t)(m-512)*NT+n];
          v = cv * sigmf(v);
        }
        o4[j] = v;
      }
      *(float4*)&out[(size_t)m*NT + n0 + tj*4] = make_float4(o4[0],o4[1],o4[2],o4[3]);
    }
  } else {
    __syncthreads();
    #pragma unroll
    for (int i=0;i<4;i++)
      #pragma unroll
      for (int j=0;j<4;j++)
        smem[(tj*4+j)*68 + (ti*4+i)] = acc[i][j];
    __syncthreads();
    int nl = t>>2, c0 = (t&3)*16;
    #pragma unroll
    for (int g4=0; g4<4; g4++){
      float4 v = *(const float4*)&smem[nl*68 + c0 + g4*4];
      *(float4*)&out[(size_t)(n0+nl)*64 + c0 + g4*4] = v;
    }
  }
}

// ---------------------------------------------------------------------------
// f32 -> bf16 (RNE) flat convert: n elems, 8 per thread.
__global__ void k_cvt_bf16(const float* __restrict__ in, unsigned short* __restrict__ outp){
  size_t i = ((size_t)blockIdx.x*256 + threadIdx.x)*8;
  float4 a = *(const float4*)(in+i), b = *(const float4*)(in+i+4);
  unsigned short o[8] = { f2b(a.x),f2b(a.y),f2b(a.z),f2b(a.w),
                          f2b(b.x),f2b(b.y),f2b(b.z),f2b(b.w) };
  *(int4*)(outp+i) = *(int4*)o;
}

// ---------------------------------------------------------------------------
// fb_w1 (512x9216 f32) -> MFMA-fragment-linear bf16:
// layout idx = ((MT*288 + KS)*512 + lane*8 + j); A[m= MT*16+(lane&15)]
// [k= KS*32+(lane>>4)*8+j]. thread = one (MT,KS,lane): 8 outs.
__global__ void k_cvt_wfrag(const float* __restrict__ w, unsigned short* __restrict__ outp){
  int tid = blockIdx.x*256 + threadIdx.x;       // 0 .. 589823
  int lane = tid & 63;
  int tmp = tid >> 6;
  int KS = tmp % 288, MT = tmp / 288;
  int m = MT*16 + (lane&15);
  int k = KS*32 + (lane>>4)*8;
  const float* p = w + (size_t)m*9216 + k;
  float4 a = *(const float4*)p, b = *(const float4*)(p+4);
  unsigned short o[8] = { f2b(a.x),f2b(a.y),f2b(a.z),f2b(a.w),
                          f2b(b.x),f2b(b.y),f2b(b.z),f2b(b.w) };
  *(int4*)(outp + (size_t)tid*8) = *(int4*)o;
}

// ---------------------------------------------------------------------------
// conv3x3 via bf16 MFMA 16x16x32. grid (32 Ntiles, 4 Mtiles, 8 Kslices),
// block 256 = 4 waves (2x2 of 64x64). A from fragment-linear global Wf;
// B staged in LDS as [n=128][k=32 pad 40] bf16 via on-the-fly im2col.
// Writes f32 partial plane per K-slice: outp + z*512*4096.
typedef __attribute__((ext_vector_type(8))) short bf16x8;
typedef __attribute__((ext_vector_type(4))) float f32x4;
__launch_bounds__(256)
__global__ void k_conv_mfma(const unsigned short* __restrict__ Wf,
                            const unsigned short* __restrict__ Bb,
                            float* __restrict__ outp){
  __shared__ unsigned short Bs[128*40];
  int t = threadIdx.x;
  int n0 = blockIdx.x*128, m0y = blockIdx.y;    // m0 = m0y*128
  int kz = blockIdx.z;                          // K slice: 1152, 36 steps
  int w = t>>6, lane = t&63;
  int wm = (w>>1)*64, wn = (w&1)*64;
  int ln15 = lane&15, lhi = lane>>4;
  f32x4 acc[4][4] = {};                         // [fm][fn]
  int sn = t & 127, kh = t>>7;                  // B stager: n, k-half
  int p = n0 + sn, py = p>>6, px = p&63;

  for (int ks=0; ks<36; ks++){
    // gather 16 im2col bf16 values (global, L2-resident)
    unsigned short tmp[16];
    int kbase = kz*1152 + ks*32 + kh*16;
    #pragma unroll
    for (int j=0;j<16;j++){
      int ka = kbase + j;
      int c = ka/9; int t9 = ka - c*9; int qy = t9/3;
      int dy = qy-1, dx = t9 - qy*3 - 1;
      int yy = py+dy, xx = px+dx;
      tmp[j] = (yy>=0 && yy<64 && xx>=0 && xx<64) ? Bb[(size_t)c*4096 + yy*64 + xx]
                                                  : (unsigned short)0;
    }
    __syncthreads();                            // prev iter's reads done
    *(int4*)&Bs[sn*40 + kh*16]     = *(int4*)&tmp[0];
    *(int4*)&Bs[sn*40 + kh*16 + 8] = *(int4*)&tmp[8];
    __syncthreads();                            // writes visible
    // load frags
    bf16x8 af[4], bf[4];
    int KSab = kz*36 + ks;
    #pragma unroll
    for (int fm=0; fm<4; fm++){
      int MT = m0y*8 + (w>>1)*4 + fm;
      af[fm] = *(const bf16x8*)&Wf[((size_t)MT*288 + KSab)*512 + lane*8];
    }
    #pragma unroll
    for (int fn=0; fn<4; fn++)
      bf[fn] = *(const bf16x8*)&Bs[(wn + fn*16 + ln15)*40 + lhi*8];
    #pragma unroll
    for (int fm=0; fm<4; fm++)
      #pragma unroll
      for (int fn=0; fn<4; fn++)
        acc[fm][fn] = __builtin_amdgcn_mfma_f32_16x16x32_bf16(af[fm], bf[fn], acc[fm][fn], 0,0,0);
  }
  // epilogue: D col=lane&15, row=(lane>>4)*4+r  [m89/m91 verified]
  float* op = outp + (size_t)kz*512*4096;
  #pragma unroll
  for (int fm=0; fm<4; fm++){
    #pragma unroll
    for (int fn=0; fn<4; fn++){
      int col = n0 + wn + fn*16 + ln15;
      int rowb = m0y*128 + wm + fm*16 + lhi*4;
      #pragma unroll
      for (int r=0; r<4; r++)
        op[(size_t)(rowb+r)*4096 + col] = acc[fm][fn][r];
    }
  }
}

// ---------------------------------------------------------------------------
// Depthwise 3x3 conv (dilated), optional SiLU. grid = C*16, block 256.
template<int DIL, int ACT>
__global__ void k_dwconv(const float* __restrict__ in, const float* __restrict__ w,
                         const float* __restrict__ b, float* __restrict__ out){
  int bid = blockIdx.x;
  int c = bid >> 4, yb = bid & 15;
  int t = threadIdx.x;
  int y = yb*4 + (t>>6), x = t&63;
  const float* pin = in + (size_t)c*NT;
  float acc = b[c];
  #pragma unroll
  for (int ky=0; ky<3; ky++){
    int yy = y + DIL*(ky-1);
    if (yy<0 || yy>=64) continue;
    #pragma unroll
    for (int kx=0; kx<3; kx++){
      int xx = x + DIL*(kx-1);
      if (xx<0 || xx>=64) continue;
      acc += w[c*9 + ky*3 + kx] * pin[yy*64+xx];
    }
  }
  if (ACT==1) acc = acc * sigmf(acc);
  out[(size_t)c*NT + y*64 + x] = acc;
}

// ---------------------------------------------------------------------------
// Global LN: sum 8 split-K partials -> h, partial stats -> final -> apply(gelu)
__global__ void k_red_part8(const float* __restrict__ hp, float* __restrict__ h,
                            float* __restrict__ part){
  __shared__ float ls[256], lq[256];
  int t = threadIdx.x; size_t base = (size_t)blockIdx.x*4096 + t;
  const size_t SL = (size_t)512*4096;
  float s=0, q=0;
  #pragma unroll
  for (int i=0;i<16;i++){
    size_t idx = base + i*256;
    float v = 0.f;
    #pragma unroll
    for (int z=0; z<8; z++) v += hp[idx + z*SL];
    h[idx] = v; s+=v; q+=v*v;
  }
  ls[t]=s; lq[t]=q; __syncthreads();
  for (int off=128; off; off>>=1){ if (t<off){ ls[t]+=ls[t+off]; lq[t]+=lq[t+off]; } __syncthreads(); }
  if (t==0){ part[blockIdx.x] = ls[0]; part[512 + blockIdx.x] = lq[0]; }
}
__global__ void k_red_fin(const float* __restrict__ part, float* __restrict__ stats){
  __shared__ float ls[256], lq[256];
  int t = threadIdx.x;
  ls[t] = part[t] + part[t+256];
  lq[t] = part[512+t] + part[768+t];
  __syncthreads();
  for (int off=128; off; off>>=1){ if (t<off){ ls[t]+=ls[t+off]; lq[t]+=lq[t+off]; } __syncthreads(); }
  if (t==0){
    float mu = ls[0] * (1.f/2097152.f);
    float var = lq[0]*(1.f/2097152.f) - mu*mu;
    stats[0]=mu; stats[1]=rsqrtf(var + 1e-5f);
  }
}
__global__ void k_ln_gelu(const float* __restrict__ h, const float* __restrict__ g,
                          const float* __restrict__ b, const float* __restrict__ stats,
                          float* __restrict__ out){
  size_t idx = ((size_t)blockIdx.x*256 + threadIdx.x)*4;
  float mu = stats[0], rs = stats[1];
  float4 hv = *(const float4*)(h + idx);
  float4 gv = *(const float4*)(g + idx);
  float4 bv = *(const float4*)(b + idx);
  float4 o;
  o.x = geluf((hv.x-mu)*rs*gv.x+bv.x);
  o.y = geluf((hv.y-mu)*rs*gv.y+bv.y);
  o.z = geluf((hv.z-mu)*rs*gv.z+bv.z);
  o.w = geluf((hv.w-mu)*rs*gv.w+bv.w);
  *(float4*)(out + idx) = o;
}

// ---------------------------------------------------------------------------
// Per-pixel LN over C=512 (stats), then apply+transpose to NHWC xn(4096,512)
__global__ void k_ln1_stats(const float* __restrict__ fused, float* __restrict__ mu1,
                            float* __restrict__ rs1){
  __shared__ float ss[256], sq[256];
  int t = threadIdx.x; int ci = t>>6; int pj = t&63;
  int pos = blockIdx.x*64 + pj;
  float s=0,q=0;
  for (int c=ci; c<512; c+=4){ float v = fused[(size_t)c*NT + pos]; s+=v; q+=v*v; }
  ss[t]=s; sq[t]=q; __syncthreads();
  if (ci==0){
    float S = ss[pj]+ss[64+pj]+ss[128+pj]+ss[192+pj];
    float Q = sq[pj]+sq[64+pj]+sq[128+pj]+sq[192+pj];
    float mu = S*(1.f/512.f);
    mu1[pos]=mu; rs1[pos]=rsqrtf(Q*(1.f/512.f) - mu*mu + 1e-5f);
  }
}
__global__ void k_ln1_apply(const float* __restrict__ fused, const float* __restrict__ g,
                            const float* __restrict__ b, const float* __restrict__ mu1,
                            const float* __restrict__ rs1, float* __restrict__ xn){
  __shared__ float tile[64*65];
  int t = threadIdx.x;
  int p0 = blockIdx.x*64, c0 = blockIdx.y*64;
  for (int it=0; it<16; it++){
    int idx = t + it*256; int yy = idx>>6, xx = idx&63;  // yy=c-local, xx=p-local
    tile[yy*65+xx] = fused[(size_t)(c0+yy)*NT + p0+xx];
  }
  __syncthreads();
  for (int it=0; it<16; it++){
    int idx = t + it*256; int r = idx>>6, s = idx&63;    // r=p-local, s=c-local
    float v = tile[s*65+r];
    int pos = p0+r, c = c0+s;
    xn[(size_t)pos*512 + c] = (v - mu1[pos])*rs1[pos]*g[c] + b[c];
  }
}

// ---------------------------------------------------------------------------
// Per-channel 64x64 transpose: out[d][w*64+h] = in[d][h*64+w]. grid=1024.
__global__ void k_transpose64(const float* __restrict__ in, float* __restrict__ out){
  __shared__ float tile[64*65];
  int d = blockIdx.x; int t = threadIdx.x;
  const float* p = in + (size_t)d*NT; float* q = out + (size_t)d*NT;
  for (int it=0; it<16; it++){
    int idx = t+it*256; int yy = idx>>6, xx = idx&63;
    tile[yy*65+xx] = p[idx];
  }
  __syncthreads();
  for (int it=0; it<16; it++){
    int idx = t+it*256; int w = idx>>6, hh = idx&63;
    q[idx] = tile[hh*65+w];
  }
}

// ---------------------------------------------------------------------------
__global__ void k_zero(float* __restrict__ p){
  size_t i = ((size_t)blockIdx.x*256 + threadIdx.x)*4;
  *(float4*)(p+i) = make_float4(0,0,0,0);
}

// ---------------------------------------------------------------------------
// Chunked selective scan, phase A: per (scanset, chunk) compute
//   P = prod(dA) and S = chunk-local state (h0=0) for each state.
__launch_bounds__(64)
__global__ void k_scan_part(const float* __restrict__ delta, const float* __restrict__ xc,
                            const float* __restrict__ xcT, const float* __restrict__ xdblT,
                            const float* __restrict__ A_logs,
                            float* __restrict__ Pbuf, float* __restrict__ Sbuf){
  int bid = blockIdx.x;
  int ss = bid >> 4;              // scanset 0..255
  int c  = bid & (NCH-1);         // chunk
  int k = ss >> 6;
  int dbase = (ss & 63)*16;
  int lane = threadIdx.x;
  int dsub = lane & 15, ngrp = lane >> 4;
  int d = dbase + dsub;
  const float* up = ((k&1)? xcT : xc) + (size_t)d*NT;
  const float* dp = delta + ((size_t)(k*1024 + d))*NT;
  const float* bc = xdblT + (size_t)k*NT*64;
  float A[4], S[4]={0,0,0,0}, P[4]={1.f,1.f,1.f,1.f};
  #pragma unroll
  for (int j=0;j<4;j++) A[j] = -__expf(A_logs[(size_t)(k*1024+d)*16 + ngrp*4 + j]);
  const bool rv = (k>=2);
  int base = c*CHL;
  for (int l0=base; l0<base+CHL; l0+=4){
    float4 dv4 = *(const float4*)(dp + l0);
    float4 uraw = rv ? *(const float4*)(up + (4092-l0)) : *(const float4*)(up + l0);
    float dts[4] = {dv4.x,dv4.y,dv4.z,dv4.w};
    float us[4];
    if (rv){ us[0]=uraw.w; us[1]=uraw.z; us[2]=uraw.y; us[3]=uraw.x; }
    else   { us[0]=uraw.x; us[1]=uraw.y; us[2]=uraw.z; us[3]=uraw.w; }
    #pragma unroll
    for (int s=0;s<4;s++){
      int l = l0+s;
      float dt = dts[s];
      float4 B4 = *(const float4*)(bc + (size_t)l*64 + 32 + ngrp*4);
      float xbu = dt*us[s];
      float Bv[4]={B4.x,B4.y,B4.z,B4.w};
      #pragma unroll
      for (int j=0;j<4;j++){
        float dA = __expf(dt*A[j]);
        S[j] = dA*S[j] + xbu*Bv[j];
        P[j] *= dA;
      }
    }
  }
  size_t o = ((size_t)(k*1024+d)*NCH + c)*16 + ngrp*4;
  *(float4*)&Pbuf[o] = make_float4(P[0],P[1],P[2],P[3]);
  *(float4*)&Sbuf[o] = make_float4(S[0],S[1],S[2],S[3]);
}

// ---------------------------------------------------------------------------
// Phase B: serial combine over chunks.
__global__ void k_scan_comb(const float* __restrict__ Pbuf, const float* __restrict__ Sbuf,
                            float* __restrict__ Hbuf){
  int tid = blockIdx.x*256 + threadIdx.x;
  int scan = tid >> 4, n = tid & 15;
  size_t base = (size_t)scan*(NCH*16) + n;
  float h = 0.f;
  #pragma unroll
  for (int c=0;c<NCH;c++){
    Hbuf[base + c*16] = h;
    h = Pbuf[base + c*16]*h + Sbuf[base + c*16];
  }
}

// ---------------------------------------------------------------------------
// Phase C: re-run chunk from h_in, compute y, atomicAdd into ycomb(l,d).
__launch_bounds__(64)
__global__ void k_scan_fin(const float* __restrict__ delta, const float* __restrict__ xc,
                           const float* __restrict__ xcT, const float* __restrict__ xdblT,
                           const float* __restrict__ A_logs, const float* __restrict__ Ds,
                           const float* __restrict__ Hbuf, float* __restrict__ ycomb){
  int bid = blockIdx.x;
  int ss = bid >> 4;
  int c  = bid & (NCH-1);
  int k = ss >> 6;
  int dbase = (ss & 63)*16;
  int lane = threadIdx.x;
  int dsub = lane & 15, ngrp = lane >> 4;
  int d = dbase + dsub;
  const float* up = ((k&1)? xcT : xc) + (size_t)d*NT;
  const float* dp = delta + ((size_t)(k*1024 + d))*NT;
  const float* bc = xdblT + (size_t)k*NT*64;
  float A[4], h[4];
  #pragma unroll
  for (int j=0;j<4;j++) A[j] = -__expf(A_logs[(size_t)(k*1024+d)*16 + ngrp*4 + j]);
  {
    size_t o = ((size_t)(k*1024+d)*NCH + c)*16 + ngrp*4;
    float4 h4 = *(const float4*)&Hbuf[o];
    h[0]=h4.x; h[1]=h4.y; h[2]=h4.z; h[3]=h4.w;
  }
  float Dv = Ds[k*1024+d];
  const bool rv = (k>=2);
  int base = c*CHL;
  for (int l0=base; l0<base+CHL; l0+=4){
    float4 dv4 = *(const float4*)(dp + l0);
    float4 uraw = rv ? *(const float4*)(up + (4092-l0)) : *(const float4*)(up + l0);
    float dts[4] = {dv4.x,dv4.y,dv4.z,dv4.w};
    float us[4];
    if (rv){ us[0]=uraw.w; us[1]=uraw.z; us[2]=uraw.y; us[3]=uraw.x; }
    else   { us[0]=uraw.x; us[1]=uraw.y; us[2]=uraw.z; us[3]=uraw.w; }
    #pragma unroll
    for (int s=0;s<4;s++){
      int l = l0+s;
      float dt = dts[s], u = us[s];
      float4 B4 = *(const float4*)(bc + (size_t)l*64 + 32 + ngrp*4);
      float4 C4 = *(const float4*)(bc + (size_t)l*64 + 48 + ngrp*4);
      float xbu = dt*u;
      float Bv[4]={B4.x,B4.y,B4.z,B4.w}, Cv[4]={C4.x,C4.y,C4.z,C4.w};
      float ys = 0.f;
      #pragma unroll
      for (int j=0;j<4;j++){
        float dA = __expf(dt*A[j]);
        h[j] = dA*h[j] + xbu*Bv[j];
        ys += h[j]*Cv[j];
      }
      ys += __shfl_xor(ys, 16);
      ys += __shfl_xor(ys, 32);
      if (ngrp==0){
        int pos;
        if (k==0) pos = l;
        else if (k==1) pos = ((l&63)<<6) | (l>>6);
        else if (k==2) pos = 4095-l;
        else { int tt = 4095-l; pos = ((tt&63)<<6) | (tt>>6); }
        atomicAdd(&ycomb[(size_t)pos*1024 + d], ys + Dv*u);
      }
    }
  }
}

// ---------------------------------------------------------------------------
// Combine: per-pixel LN over 1024 dirs-summed y, gate with silu(z) -> yact(l,d)
__global__ void k_combine(const float* __restrict__ ycomb, const float* __restrict__ xz,
                          const float* __restrict__ g, const float* __restrict__ b,
                          float* __restrict__ yact){
  int pos = blockIdx.x, t = threadIdx.x;
  float v[4]; float s=0,q=0;
  #pragma unroll
  for (int i=0;i<4;i++){ v[i] = ycomb[(size_t)pos*1024 + t + i*256]; s+=v[i]; q+=v[i]*v[i]; }
  #pragma unroll
  for (int off=32; off>=1; off>>=1){ s += __shfl_xor(s,off); q += __shfl_xor(q,off); }
  __shared__ float red[8];
  int wid = t>>6;
  if ((t&63)==0){ red[wid*2]=s; red[wid*2+1]=q; }
  __syncthreads();
  float S = red[0]+red[2]+red[4]+red[6];
  float Q = red[1]+red[3]+red[5]+red[7];
  float mu = S*(1.f/1024.f), rs = rsqrtf(Q*(1.f/1024.f) - mu*mu + 1e-5f);
  #pragma unroll
  for (int i=0;i<4;i++){
    int dd = t + i*256;
    float z = xz[(size_t)(1024+dd)*NT + pos];
    float yv = (v[i]-mu)*rs*g[dd] + b[dd];
    yact[(size_t)pos*1024 + dd] = yv * (z * sigmf(z));
  }
}

// ---------------------------------------------------------------------------
// Final: out = avgblur3x3(attn) + fused, f32. grid=512*16.
__global__ void k_blur(const float* __restrict__ attn, const float* __restrict__ fused,
                       float* __restrict__ outp){
  int bid = blockIdx.x; int c = bid>>4, yb = bid&15; int t = threadIdx.x;
  int y = yb*4 + (t>>6), x = t&63;
  const float* p = attn + (size_t)c*NT;
  float s = 0;
  #pragma unroll
  for (int dy=-1; dy<=1; dy++){
    int yy = y+dy; if (yy<0||yy>=64) continue;
    #pragma unroll
    for (int dx=-1; dx<=1; dx++){
      int xx = x+dx; if (xx<0||xx>=64) continue;
      s += p[yy*64+xx];
    }
  }
  float val = s*(1.f/9.f) + fused[(size_t)c*NT + y*64 + x];
  outp[(size_t)c*NT + y*64 + x] = val;
}

// ---------------------------------------------------------------------------
extern "C" void kernel_launch(void* const* d_in, const int* in_sizes, int n_in,
                              void* d_out, int out_size, void* d_ws, size_t ws_size,
                              hipStream_t stream){
  const float* feat = (const float*)d_in[0];
  const float* lat  = (const float*)d_in[1];
  const float* fg_w1= (const float*)d_in[2];
  const float* fg_b1= (const float*)d_in[3];
  const float* fg_w2= (const float*)d_in[4];
  const float* fg_b2= (const float*)d_in[5];
  const float* fb_w1= (const float*)d_in[6];
  const float* ln_g = (const float*)d_in[7];
  const float* ln_b = (const float*)d_in[8];
  const float* dw_w = (const float*)d_in[9];
  const float* dw_b = (const float*)d_in[10];
  const float* pw1_w= (const float*)d_in[11];
  const float* pw1_b= (const float*)d_in[12];
  const float* pw2_w= (const float*)d_in[13];
  const float* pw2_b= (const float*)d_in[14];
  const float* ln1_g= (const float*)d_in[15];
  const float* ln1_b= (const float*)d_in[16];
  const float* inpw = (const float*)d_in[17];
  const float* dc_w = (const float*)d_in[18];
  const float* dc_b = (const float*)d_in[19];
  const float* xpw  = (const float*)d_in[20];
  const float* dtw  = (const float*)d_in[21];
  const float* dtb  = (const float*)d_in[22];
  const float* Alog = (const float*)d_in[23];
  const float* Dsp  = (const float*)d_in[24];
  const float* ong  = (const float*)d_in[25];
  const float* onb  = (const float*)d_in[26];
  const float* opw  = (const float*)d_in[27];
  float* outp = (float*)d_out;
  (void)in_sizes; (void)n_in; (void)out_size; (void)ws_size;

  // ---- workspace regions with reuse (sizes in floats) ------------------
  float* Wp = (float*)d_ws;
  size_t off = 0;
  auto alloc = [&](size_t n){ float* p = Wp + off; off += n; return p; };
  float* S0    = alloc((size_t)1024*NT);   // wf -> xn -> (P/S/H scan bufs) -> yact
  float* S1    = alloc((size_t)512*NT);    // h -> h3 -> attn
  float* P0    = alloc((size_t)512*NT);    // fused (persistent)
  float* P1    = alloc((size_t)2048*NT);   // h2 | wf_bf | w_frag -> xz
  float* P2    = alloc((size_t)1024*NT);   // h4 (front) -> xc
  float* P3    = alloc((size_t)1024*NT);   // xcT
  float* P4    = alloc((size_t)4*NT*64);   // xdblT
  float* P5    = alloc((size_t)4*1024*NT); // hpart (8 x 512 x 4096 f32) -> delta
  float* P6    = alloc((size_t)1024*NT);   // g1 (front) -> ycomb
  float* part  = alloc(1024);
  float* stats = alloc(4);
  float* mu1   = alloc(4096);
  float* rs1   = alloc(4096);
  // total ~47.2M floats = 189 MB

  float* wf    = S0;
  float* h     = S1;
  float* h2    = P1;                       // front 512*NT
  float* h3    = S1;
  float* h4    = P2;
  float* fused = P0;
  float* xn    = S0;
  float* xz    = P1;
  float* xc    = P2;
  float* xcT   = P3;
  float* xdblT = P4;
  float* hpart = P5;                       // 8 planes x 512x4096 f32 = 16.8M floats
  float* delta = P5;
  float* g1    = P6;
  float* ycomb = P6;
  float* yact  = S0;
  float* attn  = S1;
  // bf16 staging in P1 beyond h2 (dead until xz at step 9)
  unsigned short* wf_bf  = (unsigned short*)(P1 + (size_t)512*NT);  // 4.2M bf16 = 8.4MB
  unsigned short* w_frag = (unsigned short*)(P1 + (size_t)1024*NT); // 4.7M bf16
  // scan chunk buffers live in S0 (xn dead after step 9, yact written at 16)
  float* Pbuf  = S0;                       // 4096*NCH*16 = 1M floats
  float* Sbuf  = S0 + (size_t)1048576;
  float* Hbuf  = S0 + (size_t)2*1048576;

  // 1) g1 = gelu(fg1(concat))            M=32, K=1024
  hipLaunchKernelGGL((k_gemm<1,1,false>), dim3(64,1), dim3(256), 0, stream,
      32, 1024, 1024, 0, fg_w1, fg_b1, nullptr, feat, lat, 0,0, nullptr, g1);
  // 2) wf = concat * sigmoid(fg2(g1))    M=1024, K=32
  hipLaunchKernelGGL((k_gemm<0,5,false>), dim3(64,16), dim3(256), 0, stream,
      1024, 32, 32, 0, fg_w2, fg_b2, g1, feat, lat, 0,0, nullptr, wf);
  // 3) conv3x3 via bf16 MFMA, split-K x8
  hipLaunchKernelGGL(k_cvt_bf16, dim3(2048), dim3(256), 0, stream, wf, wf_bf);
  hipLaunchKernelGGL(k_cvt_wfrag, dim3(2304), dim3(256), 0, stream, fb_w1, w_frag);
  hipLaunchKernelGGL(k_conv_mfma, dim3(32,4,8), dim3(256), 0, stream, w_frag, wf_bf, hpart);
  // 4) h = sum(hpart) ; h2 = gelu(LN_global(h))
  hipLaunchKernelGGL(k_red_part8, dim3(512), dim3(256), 0, stream, hpart, h, part);
  hipLaunchKernelGGL(k_red_fin,  dim3(1),   dim3(256), 0, stream, part, stats);
  hipLaunchKernelGGL(k_ln_gelu,  dim3(2048),dim3(256), 0, stream, h, ln_g, ln_b, stats, h2);
  // 5) h3 = dwconv3x3 dil2(h2)
  hipLaunchKernelGGL((k_dwconv<2,0>), dim3(512*16), dim3(256), 0, stream, h2, dw_w, dw_b, h3);
  // 6) h4 = gelu(pw1(h3))
  hipLaunchKernelGGL((k_gemm<0,1,false>), dim3(64,8), dim3(256), 0, stream,
      512, 512, 512, 0, pw1_w, pw1_b, h3, nullptr,nullptr, 0,0, nullptr, h4);
  // 7) fused = pw2(shuffle(h4)) + feature
  hipLaunchKernelGGL((k_gemm<0,4,false>), dim3(64,8), dim3(256), 0, stream,
      512, 512, 512, 0, pw2_w, pw2_b, h4, nullptr,nullptr, 0,1, feat, fused);
  // 8) xn = LN_c(fused^T) (NHWC)
  hipLaunchKernelGGL(k_ln1_stats, dim3(64), dim3(256), 0, stream, fused, mu1, rs1);
  hipLaunchKernelGGL(k_ln1_apply, dim3(64,8), dim3(256), 0, stream, fused, ln1_g, ln1_b, mu1, rs1, xn);
  // 9) xz = xn @ in_proj^T               M=2048, K=512, B NHWC
  hipLaunchKernelGGL((k_gemm<2,0,false>), dim3(64,32), dim3(256), 0, stream,
      2048, 512, 512, 512, inpw, nullptr, xn, nullptr,nullptr, 0,0, nullptr, xz);
  // 10) xc = silu(dwconv3x3(xp))
  hipLaunchKernelGGL((k_dwconv<1,1>), dim3(1024*16), dim3(256), 0, stream, xz, dc_w, dc_b, xc);
  // 11) xcT
  hipLaunchKernelGGL(k_transpose64, dim3(1024), dim3(256), 0, stream, xc, xcT);
  // 12) xdblT[k] = (x_proj_w[k] @ xs[k])^T   M=64, K=1024, transposed write
  for (int k=0;k<4;k++){
    hipLaunchKernelGGL((k_gemm<0,0,true>), dim3(64,1), dim3(256), 0, stream,
        64, 1024, 1024, 0, xpw + (size_t)k*64*1024, nullptr, (k&1)? xcT : xc,
        nullptr,nullptr, (k>=2)?1:0, 0, nullptr, xdblT + (size_t)k*NT*64);
  }
  // 13) delta[k] = softplus(dt_w[k] @ dts[k] + dt_b[k])   M=1024, K=32, B NHWC(ld 64)
  for (int k=0;k<4;k++){
    hipLaunchKernelGGL((k_gemm<2,2,false>), dim3(64,16), dim3(256), 0, stream,
        1024, 32, 32, 64, dtw + (size_t)k*1024*32, dtb + (size_t)k*1024,
        xdblT + (size_t)k*NT*64, nullptr,nullptr, 0,0, nullptr,
        delta + (size_t)k*1024*NT);
  }
  // 14) ycomb = 0
  hipLaunchKernelGGL(k_zero, dim3(4096), dim3(256), 0, stream, ycomb);
  // 15) chunked selective scan: partial -> combine -> final
  hipLaunchKernelGGL(k_scan_part, dim3(256*NCH), dim3(64), 0, stream,
      delta, xc, xcT, xdblT, Alog, Pbuf, Sbuf);
  hipLaunchKernelGGL(k_scan_comb, dim3(256), dim3(256), 0, stream, Pbuf, Sbuf, Hbuf);
  hipLaunchKernelGGL(k_scan_fin, dim3(256*NCH), dim3(64), 0, stream,
      delta, xc, xcT, xdblT, Alog, Dsp, Hbuf, ycomb);
  // 16) yact = out_norm(ycomb) * silu(z)
  hipLaunchKernelGGL(k_combine, dim3(4096), dim3(256), 0, stream, ycomb, xz, ong, onb, yact);
  // 17) attn = fused + yact @ out_proj^T   M=512, K=1024, B NHWC
  hipLaunchKernelGGL((k_gemm<2,4,false>), dim3(64,8), dim3(256), 0, stream,
      512, 1024, 1024, 1024, opw, nullptr, yact, nullptr,nullptr, 0,0, fused, attn);
  // 18) out = blur3x3(attn) + fused  -> f32
  hipLaunchKernelGGL(k_blur, dim3(512*16), dim3(256), 0, stream, attn, fused, outp);
}

// Round 11
// 1080.044 us; speedup vs baseline: 3.4338x; 1.3413x over previous
//
#include <hip/hip_runtime.h>

// ---------------------------------------------------------------------------
// FeatureMapApproximator: VMamba-style block. B=1, C=512, H=W=64, L=4096,
// d_inner=1024, K=4 dirs, N=16 states, dt_rank=32.
// f32 pipeline; conv3x3 + xz on bf16 MFMA; scan chunked 32x128.
// ---------------------------------------------------------------------------

#define NT 4096   // pixels (and GEMM N)
#define NCH 32    // scan chunks
#define CHL 128   // chunk length

__device__ __forceinline__ float geluf(float x){ return 0.5f*x*(1.f+erff(x*0.70710678118654752f)); }
__device__ __forceinline__ float sigmf(float x){ return 1.f/(1.f+__expf(-x)); }
__device__ __forceinline__ float softplusf(float x){ return (x>20.f)? x : __logf(1.f+__expf(x)); }
__device__ __forceinline__ unsigned short f2b(float f){
  unsigned u = __float_as_uint(f);
  u += 0x7FFFu + ((u>>16)&1u);          // RNE
  return (unsigned short)(u>>16);
}

// ---------------------------------------------------------------------------
// Generic tiled GEMM (f32). TM=64, TN=64, TK=32, 256 threads, 4x4 acc.
// BMODE 0: B channel-major (rev/shuf). 1: concat(feat,lat). 2: B NHWC (ldb).
// EPI 0 none | 1 gelu | 2 softplus | 4 +f32 res | 5 concat*sigmoid
// TRANSW: write out[n*64+m] via LDS bounce (M==64, EPI 0 only).
// ZB 0: none. 1: xdbl batch (z: A+=z*64K, B=xc/xcT by z&1, rev=z>=2,
//   out+=z*NT*64). 2: delta batch (z: A+=z*32K, bias+=z*1024, Bf+=z*NT*64,
//   out+=z*1024*NT).
// ---------------------------------------------------------------------------
template<int BMODE, int EPI, bool TRANSW, int ZB=0>
__launch_bounds__(256)
__global__ void k_gemm(int M, int K, int lda, int ldb,
    const float* __restrict__ A, const float* __restrict__ bias,
    const float* __restrict__ Bf, const float* __restrict__ Bc0,
    const float* __restrict__ Bc1, int rev, int shuf,
    const float* __restrict__ resf, float* __restrict__ out)
{
  __shared__ float smem[4352];           // 2 x [32][68] (or 64x68 for TRANSW)
  float* As = smem;
  float* Bs = smem + 2176;
  const int t  = threadIdx.x;
  const int n0 = blockIdx.x*64, m0 = blockIdx.y*64;
  if (ZB==1){
    int z = blockIdx.z;
    A   += (size_t)z*64*1024;
    if (z&1) Bf = Bc0;                   // xcT
    rev  = (z>=2);
    out += (size_t)z*NT*64;
  } else if (ZB==2){
    int z = blockIdx.z;
    A    += (size_t)z*1024*32;
    bias += (size_t)z*1024;
    Bf   += (size_t)z*NT*64;
    out  += (size_t)z*1024*NT;
  }
  float acc[4][4] = {};

  for (int k0=0; k0<K; k0+=32){
    __syncthreads();
    { // stage A (f32 weights, row-major M x K)
      int m = t>>2, kk0 = (t&3)*8;
      float av[8] = {0,0,0,0,0,0,0,0};
      if (m0+m < M){
        const float* pa = A + (size_t)(m0+m)*lda + k0 + kk0;
        float4 a0 = *(const float4*)pa; float4 a1 = *(const float4*)(pa+4);
        av[0]=a0.x; av[1]=a0.y; av[2]=a0.z; av[3]=a0.w;
        av[4]=a1.x; av[5]=a1.y; av[6]=a1.z; av[7]=a1.w;
      }
      #pragma unroll
      for (int j=0;j<8;j++) As[(kk0+j)*68 + m] = av[j];
    }
    if (BMODE==2){
      int n = t>>2, kk0 = (t&3)*8;
      const float* p = Bf + (size_t)(n0+n)*ldb + k0 + kk0;
      float4 x0 = *(const float4*)p; float4 x1 = *(const float4*)(p+4);
      Bs[(kk0+0)*68+n]=x0.x; Bs[(kk0+1)*68+n]=x0.y; Bs[(kk0+2)*68+n]=x0.z; Bs[(kk0+3)*68+n]=x0.w;
      Bs[(kk0+4)*68+n]=x1.x; Bs[(kk0+5)*68+n]=x1.y; Bs[(kk0+6)*68+n]=x1.z; Bs[(kk0+7)*68+n]=x1.w;
    } else {
      int kk = t>>3, n8 = (t&7)*8;
      float bv[8];
      if (BMODE==0){
        int r = k0+kk; if (shuf) r = (r&7)*64 + (r>>3);
        const float* p = Bf + (size_t)r*NT;
        if (!rev){
          float4 x0 = *(const float4*)(p + n0+n8); float4 x1 = *(const float4*)(p + n0+n8+4);
          bv[0]=x0.x;bv[1]=x0.y;bv[2]=x0.z;bv[3]=x0.w;bv[4]=x1.x;bv[5]=x1.y;bv[6]=x1.z;bv[7]=x1.w;
        } else {
          const float* q = p + (4088 - n0 - n8);
          float4 x0 = *(const float4*)q; float4 x1 = *(const float4*)(q+4);
          bv[0]=x1.w;bv[1]=x1.z;bv[2]=x1.y;bv[3]=x1.x;bv[4]=x0.w;bv[5]=x0.z;bv[6]=x0.y;bv[7]=x0.x;
        }
      } else if (BMODE==1){
        int c = k0+kk;
        const float* p = (c<512) ? (Bc0 + (size_t)c*NT) : (Bc1 + (size_t)(c-512)*NT);
        float4 x0 = *(const float4*)(p + n0+n8); float4 x1 = *(const float4*)(p + n0+n8+4);
        bv[0]=x0.x;bv[1]=x0.y;bv[2]=x0.z;bv[3]=x0.w;bv[4]=x1.x;bv[5]=x1.y;bv[6]=x1.z;bv[7]=x1.w;
      } else {
        #pragma unroll
        for (int j=0;j<8;j++) bv[j] = 0.f;
      }
      *(float4*)&Bs[kk*68 + n8]   = make_float4(bv[0],bv[1],bv[2],bv[3]);
      *(float4*)&Bs[kk*68 + n8+4] = make_float4(bv[4],bv[5],bv[6],bv[7]);
    }
    __syncthreads();
    int ti = t>>4, tj = t&15;
    #pragma unroll
    for (int kk=0; kk<32; kk++){
      float4 a4 = *(const float4*)&As[kk*68 + ti*4];
      float4 b4 = *(const float4*)&Bs[kk*68 + tj*4];
      float aa[4] = {a4.x,a4.y,a4.z,a4.w};
      float bb[4] = {b4.x,b4.y,b4.z,b4.w};
      #pragma unroll
      for (int i=0;i<4;i++)
        #pragma unroll
        for (int j=0;j<4;j++) acc[i][j] += aa[i]*bb[j];
    }
  }

  int ti = t>>4, tj = t&15;
  if (!TRANSW){
    #pragma unroll
    for (int i=0;i<4;i++){
      int m = m0 + ti*4 + i;
      if (m >= M) continue;
      float bi = bias ? bias[m] : 0.f;
      float o4[4];
      #pragma unroll
      for (int j=0;j<4;j++){
        int n = n0 + tj*4 + j;
        float v = acc[i][j] + bi;
        if (EPI==1) v = geluf(v);
        else if (EPI==2) v = softplusf(v);
        else if (EPI==4) v = v + resf[(size_t)m*NT + n];
        else if (EPI==5){
          float cv = (m<512)? Bc0[(size_t)m*NT+n] : Bc1[(size_t)(m-512)*NT+n];
          v = cv * sigmf(v);
        }
        o4[j] = v;
      }
      *(float4*)&out[(size_t)m*NT + n0 + tj*4] = make_float4(o4[0],o4[1],o4[2],o4[3]);
    }
  } else {
    __syncthreads();
    #pragma unroll
    for (int i=0;i<4;i++)
      #pragma unroll
      for (int j=0;j<4;j++)
        smem[(tj*4+j)*68 + (ti*4+i)] = acc[i][j];
    __syncthreads();
    int nl = t>>2, c0 = (t&3)*16;
    #pragma unroll
    for (int g4=0; g4<4; g4++){
      float4 v = *(const float4*)&smem[nl*68 + c0 + g4*4];
      *(float4*)&out[(size_t)(n0+nl)*64 + c0 + g4*4] = v;
    }
  }
}

// ---------------------------------------------------------------------------
// f32 -> bf16 (RNE) flat convert: 8 per thread.
__global__ void k_cvt_bf16(const float* __restrict__ in, unsigned short* __restrict__ outp){
  size_t i = ((size_t)blockIdx.x*256 + threadIdx.x)*8;
  float4 a = *(const float4*)(in+i), b = *(const float4*)(in+i+4);
  unsigned short o[8] = { f2b(a.x),f2b(a.y),f2b(a.z),f2b(a.w),
                          f2b(b.x),f2b(b.y),f2b(b.z),f2b(b.w) };
  *(int4*)(outp+i) = *(int4*)o;
}

// ---------------------------------------------------------------------------
// Row-major (M x lda f32) -> MFMA-fragment-linear bf16:
// idx = ((MT*KSn + KS)*64 + lane)*8 + j ; A[m=MT*16+(lane&15)][k=KS*32+(lane>>4)*8+j]
__global__ void k_cvt_wfrag(const float* __restrict__ w, int lda, int KSn,
                            unsigned short* __restrict__ outp){
  int tid = blockIdx.x*256 + threadIdx.x;
  int lane = tid & 63;
  int tmp = tid >> 6;
  int KS = tmp % KSn, MT = tmp / KSn;
  int m = MT*16 + (lane&15);
  int k = KS*32 + (lane>>4)*8;
  const float* p = w + (size_t)m*lda + k;
  float4 a = *(const float4*)p, b = *(const float4*)(p+4);
  unsigned short o[8] = { f2b(a.x),f2b(a.y),f2b(a.z),f2b(a.w),
                          f2b(b.x),f2b(b.y),f2b(b.z),f2b(b.w) };
  *(int4*)(outp + (size_t)tid*8) = *(int4*)o;
}

// ---------------------------------------------------------------------------
typedef __attribute__((ext_vector_type(8))) short bf16x8;
typedef __attribute__((ext_vector_type(4))) float f32x4;

// conv3x3 via bf16 MFMA 16x16x32. grid (32,4,8), block 256 = 4 waves (2x2).
__launch_bounds__(256)
__global__ void k_conv_mfma(const unsigned short* __restrict__ Wf,
                            const unsigned short* __restrict__ Bb,
                            float* __restrict__ outp){
  __shared__ unsigned short Bs[128*40];
  int t = threadIdx.x;
  int n0 = blockIdx.x*128, m0y = blockIdx.y;
  int kz = blockIdx.z;                          // K slice: 1152, 36 steps
  int w = t>>6, lane = t&63;
  int wm = (w>>1)*64, wn = (w&1)*64;
  int ln15 = lane&15, lhi = lane>>4;
  f32x4 acc[4][4] = {};
  int sn = t & 127, kh = t>>7;
  int p = n0 + sn, py = p>>6, px = p&63;

  for (int ks=0; ks<36; ks++){
    unsigned short tmp[16];
    int kbase = kz*1152 + ks*32 + kh*16;
    #pragma unroll
    for (int j=0;j<16;j++){
      int ka = kbase + j;
      int c = ka/9; int t9 = ka - c*9; int qy = t9/3;
      int dy = qy-1, dx = t9 - qy*3 - 1;
      int yy = py+dy, xx = px+dx;
      tmp[j] = (yy>=0 && yy<64 && xx>=0 && xx<64) ? Bb[(size_t)c*4096 + yy*64 + xx]
                                                  : (unsigned short)0;
    }
    __syncthreads();
    *(int4*)&Bs[sn*40 + kh*16]     = *(int4*)&tmp[0];
    *(int4*)&Bs[sn*40 + kh*16 + 8] = *(int4*)&tmp[8];
    __syncthreads();
    bf16x8 af[4], bf[4];
    int KSab = kz*36 + ks;
    #pragma unroll
    for (int fm=0; fm<4; fm++){
      int MT = m0y*8 + (w>>1)*4 + fm;
      af[fm] = *(const bf16x8*)&Wf[((size_t)MT*288 + KSab)*512 + lane*8];
    }
    #pragma unroll
    for (int fn=0; fn<4; fn++)
      bf[fn] = *(const bf16x8*)&Bs[(wn + fn*16 + ln15)*40 + lhi*8];
    #pragma unroll
    for (int fm=0; fm<4; fm++)
      #pragma unroll
      for (int fn=0; fn<4; fn++)
        acc[fm][fn] = __builtin_amdgcn_mfma_f32_16x16x32_bf16(af[fm], bf[fn], acc[fm][fn], 0,0,0);
  }
  float* op = outp + (size_t)kz*512*4096;
  #pragma unroll
  for (int fm=0; fm<4; fm++){
    #pragma unroll
    for (int fn=0; fn<4; fn++){
      int col = n0 + wn + fn*16 + ln15;
      int rowb = m0y*128 + wm + fm*16 + lhi*4;
      #pragma unroll
      for (int r=0; r<4; r++)
        op[(size_t)(rowb+r)*4096 + col] = acc[fm][fn][r];
    }
  }
}

// ---------------------------------------------------------------------------
// xz = in_proj @ xn^T via bf16 MFMA. M=2048 (grid.y 16), N=4096 (grid.x 32),
// K=512 (16 steps). B = xn bf16 NHWC (4096 x 512). Direct f32 out, no epi.
__launch_bounds__(256)
__global__ void k_xz_mfma(const unsigned short* __restrict__ Wf,
                          const unsigned short* __restrict__ xnb,
                          float* __restrict__ outp){
  __shared__ unsigned short Bs[128*40];
  int t = threadIdx.x;
  int n0 = blockIdx.x*128, m0y = blockIdx.y;
  int w = t>>6, lane = t&63;
  int wm = (w>>1)*64, wn = (w&1)*64;
  int ln15 = lane&15, lhi = lane>>4;
  f32x4 acc[4][4] = {};
  int sn = t & 127, kh = t>>7;

  for (int ks=0; ks<16; ks++){
    const unsigned short* src = xnb + (size_t)(n0+sn)*512 + ks*32 + kh*16;
    int4 v0 = *(const int4*)src;
    int4 v1 = *(const int4*)(src+8);
    __syncthreads();
    *(int4*)&Bs[sn*40 + kh*16]     = v0;
    *(int4*)&Bs[sn*40 + kh*16 + 8] = v1;
    __syncthreads();
    bf16x8 af[4], bf[4];
    #pragma unroll
    for (int fm=0; fm<4; fm++){
      int MT = m0y*8 + (w>>1)*4 + fm;
      af[fm] = *(const bf16x8*)&Wf[((size_t)MT*16 + ks)*512 + lane*8];
    }
    #pragma unroll
    for (int fn=0; fn<4; fn++)
      bf[fn] = *(const bf16x8*)&Bs[(wn + fn*16 + ln15)*40 + lhi*8];
    #pragma unroll
    for (int fm=0; fm<4; fm++)
      #pragma unroll
      for (int fn=0; fn<4; fn++)
        acc[fm][fn] = __builtin_amdgcn_mfma_f32_16x16x32_bf16(af[fm], bf[fn], acc[fm][fn], 0,0,0);
  }
  #pragma unroll
  for (int fm=0; fm<4; fm++){
    #pragma unroll
    for (int fn=0; fn<4; fn++){
      int col = n0 + wn + fn*16 + ln15;
      int rowb = m0y*128 + wm + fm*16 + lhi*4;
      #pragma unroll
      for (int r=0; r<4; r++)
        outp[(size_t)(rowb+r)*4096 + col] = acc[fm][fn][r];
    }
  }
}

// ---------------------------------------------------------------------------
// Depthwise 3x3 conv (dilated), optional SiLU. grid = C*16, block 256.
template<int DIL, int ACT>
__global__ void k_dwconv(const float* __restrict__ in, const float* __restrict__ w,
                         const float* __restrict__ b, float* __restrict__ out){
  int bid = blockIdx.x;
  int c = bid >> 4, yb = bid & 15;
  int t = threadIdx.x;
  int y = yb*4 + (t>>6), x = t&63;
  const float* pin = in + (size_t)c*NT;
  float acc = b[c];
  #pragma unroll
  for (int ky=0; ky<3; ky++){
    int yy = y + DIL*(ky-1);
    if (yy<0 || yy>=64) continue;
    #pragma unroll
    for (int kx=0; kx<3; kx++){
      int xx = x + DIL*(kx-1);
      if (xx<0 || xx>=64) continue;
      acc += w[c*9 + ky*3 + kx] * pin[yy*64+xx];
    }
  }
  if (ACT==1) acc = acc * sigmf(acc);
  out[(size_t)c*NT + y*64 + x] = acc;
}

// ---------------------------------------------------------------------------
// Global LN: sum 8 split-K partials -> h, partial stats -> final -> apply(gelu)
__global__ void k_red_part8(const float* __restrict__ hp, float* __restrict__ h,
                            float* __restrict__ part){
  __shared__ float ls[256], lq[256];
  int t = threadIdx.x; size_t base = (size_t)blockIdx.x*4096 + t;
  const size_t SL = (size_t)512*4096;
  float s=0, q=0;
  #pragma unroll
  for (int i=0;i<16;i++){
    size_t idx = base + i*256;
    float v = 0.f;
    #pragma unroll
    for (int z=0; z<8; z++) v += hp[idx + z*SL];
    h[idx] = v; s+=v; q+=v*v;
  }
  ls[t]=s; lq[t]=q; __syncthreads();
  for (int off=128; off; off>>=1){ if (t<off){ ls[t]+=ls[t+off]; lq[t]+=lq[t+off]; } __syncthreads(); }
  if (t==0){ part[blockIdx.x] = ls[0]; part[512 + blockIdx.x] = lq[0]; }
}
__global__ void k_red_fin(const float* __restrict__ part, float* __restrict__ stats){
  __shared__ float ls[256], lq[256];
  int t = threadIdx.x;
  ls[t] = part[t] + part[t+256];
  lq[t] = part[512+t] + part[768+t];
  __syncthreads();
  for (int off=128; off; off>>=1){ if (t<off){ ls[t]+=ls[t+off]; lq[t]+=lq[t+off]; } __syncthreads(); }
  if (t==0){
    float mu = ls[0] * (1.f/2097152.f);
    float var = lq[0]*(1.f/2097152.f) - mu*mu;
    stats[0]=mu; stats[1]=rsqrtf(var + 1e-5f);
  }
}
__global__ void k_ln_gelu(const float* __restrict__ h, const float* __restrict__ g,
                          const float* __restrict__ b, const float* __restrict__ stats,
                          float* __restrict__ out){
  size_t idx = ((size_t)blockIdx.x*256 + threadIdx.x)*4;
  float mu = stats[0], rs = stats[1];
  float4 hv = *(const float4*)(h + idx);
  float4 gv = *(const float4*)(g + idx);
  float4 bv = *(const float4*)(b + idx);
  float4 o;
  o.x = geluf((hv.x-mu)*rs*gv.x+bv.x);
  o.y = geluf((hv.y-mu)*rs*gv.y+bv.y);
  o.z = geluf((hv.z-mu)*rs*gv.z+bv.z);
  o.w = geluf((hv.w-mu)*rs*gv.w+bv.w);
  *(float4*)(out + idx) = o;
}

// ---------------------------------------------------------------------------
// Per-pixel LN over C=512 (stats), then apply+transpose to NHWC bf16 xnb(4096,512)
__global__ void k_ln1_stats(const float* __restrict__ fused, float* __restrict__ mu1,
                            float* __restrict__ rs1){
  __shared__ float ss[256], sq[256];
  int t = threadIdx.x; int ci = t>>6; int pj = t&63;
  int pos = blockIdx.x*64 + pj;
  float s=0,q=0;
  for (int c=ci; c<512; c+=4){ float v = fused[(size_t)c*NT + pos]; s+=v; q+=v*v; }
  ss[t]=s; sq[t]=q; __syncthreads();
  if (ci==0){
    float S = ss[pj]+ss[64+pj]+ss[128+pj]+ss[192+pj];
    float Q = sq[pj]+sq[64+pj]+sq[128+pj]+sq[192+pj];
    float mu = S*(1.f/512.f);
    mu1[pos]=mu; rs1[pos]=rsqrtf(Q*(1.f/512.f) - mu*mu + 1e-5f);
  }
}
__global__ void k_ln1_apply(const float* __restrict__ fused, const float* __restrict__ g,
                            const float* __restrict__ b, const float* __restrict__ mu1,
                            const float* __restrict__ rs1, unsigned short* __restrict__ xnb){
  __shared__ float tile[64*65];
  int t = threadIdx.x;
  int p0 = blockIdx.x*64, c0 = blockIdx.y*64;
  for (int it=0; it<16; it++){
    int idx = t + it*256; int yy = idx>>6, xx = idx&63;
    tile[yy*65+xx] = fused[(size_t)(c0+yy)*NT + p0+xx];
  }
  __syncthreads();
  for (int it=0; it<16; it++){
    int idx = t + it*256; int r = idx>>6, s = idx&63;
    float v = tile[s*65+r];
    int pos = p0+r, c = c0+s;
    xnb[(size_t)pos*512 + c] = f2b((v - mu1[pos])*rs1[pos]*g[c] + b[c]);
  }
}

// ---------------------------------------------------------------------------
// Per-channel 64x64 transpose: out[d][w*64+h] = in[d][h*64+w]. grid=1024.
__global__ void k_transpose64(const float* __restrict__ in, float* __restrict__ out){
  __shared__ float tile[64*65];
  int d = blockIdx.x; int t = threadIdx.x;
  const float* p = in + (size_t)d*NT; float* q = out + (size_t)d*NT;
  for (int it=0; it<16; it++){
    int idx = t+it*256; int yy = idx>>6, xx = idx&63;
    tile[yy*65+xx] = p[idx];
  }
  __syncthreads();
  for (int it=0; it<16; it++){
    int idx = t+it*256; int w = idx>>6, hh = idx&63;
    q[idx] = tile[hh*65+w];
  }
}

// ---------------------------------------------------------------------------
__global__ void k_zero(float* __restrict__ p){
  size_t i = ((size_t)blockIdx.x*256 + threadIdx.x)*4;
  *(float4*)(p+i) = make_float4(0,0,0,0);
}

// ---------------------------------------------------------------------------
// Chunked selective scan, phase A. grid = 256 scansets * NCH, block 64.
__launch_bounds__(64)
__global__ void k_scan_part(const float* __restrict__ delta, const float* __restrict__ xc,
                            const float* __restrict__ xcT, const float* __restrict__ xdblT,
                            const float* __restrict__ A_logs,
                            float* __restrict__ Pbuf, float* __restrict__ Sbuf){
  int bid = blockIdx.x;
  int ss = bid / NCH;
  int c  = bid % NCH;
  int k = ss >> 6;
  int dbase = (ss & 63)*16;
  int lane = threadIdx.x;
  int dsub = lane & 15, ngrp = lane >> 4;
  int d = dbase + dsub;
  const float* up = ((k&1)? xcT : xc) + (size_t)d*NT;
  const float* dp = delta + ((size_t)(k*1024 + d))*NT;
  const float* bc = xdblT + (size_t)k*NT*64;
  float A[4], S[4]={0,0,0,0}, P[4]={1.f,1.f,1.f,1.f};
  #pragma unroll
  for (int j=0;j<4;j++) A[j] = -__expf(A_logs[(size_t)(k*1024+d)*16 + ngrp*4 + j]);
  const bool rv = (k>=2);
  int base = c*CHL;
  for (int l0=base; l0<base+CHL; l0+=4){
    float4 dv4 = *(const float4*)(dp + l0);
    float4 uraw = rv ? *(const float4*)(up + (4092-l0)) : *(const float4*)(up + l0);
    float dts[4] = {dv4.x,dv4.y,dv4.z,dv4.w};
    float us[4];
    if (rv){ us[0]=uraw.w; us[1]=uraw.z; us[2]=uraw.y; us[3]=uraw.x; }
    else   { us[0]=uraw.x; us[1]=uraw.y; us[2]=uraw.z; us[3]=uraw.w; }
    #pragma unroll
    for (int s=0;s<4;s++){
      int l = l0+s;
      float dt = dts[s];
      float4 B4 = *(const float4*)(bc + (size_t)l*64 + 32 + ngrp*4);
      float xbu = dt*us[s];
      float Bv[4]={B4.x,B4.y,B4.z,B4.w};
      #pragma unroll
      for (int j=0;j<4;j++){
        float dA = __expf(dt*A[j]);
        S[j] = dA*S[j] + xbu*Bv[j];
        P[j] *= dA;
      }
    }
  }
  size_t o = ((size_t)(k*1024+d)*NCH + c)*16 + ngrp*4;
  *(float4*)&Pbuf[o] = make_float4(P[0],P[1],P[2],P[3]);
  *(float4*)&Sbuf[o] = make_float4(S[0],S[1],S[2],S[3]);
}

// ---------------------------------------------------------------------------
// Phase B: serial combine over chunks. grid=256, block=256.
__global__ void k_scan_comb(const float* __restrict__ Pbuf, const float* __restrict__ Sbuf,
                            float* __restrict__ Hbuf){
  int tid = blockIdx.x*256 + threadIdx.x;
  int scan = tid >> 4, n = tid & 15;
  size_t base = (size_t)scan*(NCH*16) + n;
  float h = 0.f;
  #pragma unroll
  for (int c=0;c<NCH;c++){
    Hbuf[base + c*16] = h;
    h = Pbuf[base + c*16]*h + Sbuf[base + c*16];
  }
}

// ---------------------------------------------------------------------------
// Phase C: re-run chunk from h_in, compute y, atomicAdd into ycomb(l,d).
__launch_bounds__(64)
__global__ void k_scan_fin(const float* __restrict__ delta, const float* __restrict__ xc,
                           const float* __restrict__ xcT, const float* __restrict__ xdblT,
                           const float* __restrict__ A_logs, const float* __restrict__ Ds,
                           const float* __restrict__ Hbuf, float* __restrict__ ycomb){
  int bid = blockIdx.x;
  int ss = bid / NCH;
  int c  = bid % NCH;
  int k = ss >> 6;
  int dbase = (ss & 63)*16;
  int lane = threadIdx.x;
  int dsub = lane & 15, ngrp = lane >> 4;
  int d = dbase + dsub;
  const float* up = ((k&1)? xcT : xc) + (size_t)d*NT;
  const float* dp = delta + ((size_t)(k*1024 + d))*NT;
  const float* bc = xdblT + (size_t)k*NT*64;
  float A[4], h[4];
  #pragma unroll
  for (int j=0;j<4;j++) A[j] = -__expf(A_logs[(size_t)(k*1024+d)*16 + ngrp*4 + j]);
  {
    size_t o = ((size_t)(k*1024+d)*NCH + c)*16 + ngrp*4;
    float4 h4 = *(const float4*)&Hbuf[o];
    h[0]=h4.x; h[1]=h4.y; h[2]=h4.z; h[3]=h4.w;
  }
  float Dv = Ds[k*1024+d];
  const bool rv = (k>=2);
  int base = c*CHL;
  for (int l0=base; l0<base+CHL; l0+=4){
    float4 dv4 = *(const float4*)(dp + l0);
    float4 uraw = rv ? *(const float4*)(up + (4092-l0)) : *(const float4*)(up + l0);
    float dts[4] = {dv4.x,dv4.y,dv4.z,dv4.w};
    float us[4];
    if (rv){ us[0]=uraw.w; us[1]=uraw.z; us[2]=uraw.y; us[3]=uraw.x; }
    else   { us[0]=uraw.x; us[1]=uraw.y; us[2]=uraw.z; us[3]=uraw.w; }
    #pragma unroll
    for (int s=0;s<4;s++){
      int l = l0+s;
      float dt = dts[s], u = us[s];
      float4 B4 = *(const float4*)(bc + (size_t)l*64 + 32 + ngrp*4);
      float4 C4 = *(const float4*)(bc + (size_t)l*64 + 48 + ngrp*4);
      float xbu = dt*u;
      float Bv[4]={B4.x,B4.y,B4.z,B4.w}, Cv[4]={C4.x,C4.y,C4.z,C4.w};
      float ys = 0.f;
      #pragma unroll
      for (int j=0;j<4;j++){
        float dA = __expf(dt*A[j]);
        h[j] = dA*h[j] + xbu*Bv[j];
        ys += h[j]*Cv[j];
      }
      ys += __shfl_xor(ys, 16);
      ys += __shfl_xor(ys, 32);
      if (ngrp==0){
        int pos;
        if (k==0) pos = l;
        else if (k==1) pos = ((l&63)<<6) | (l>>6);
        else if (k==2) pos = 4095-l;
        else { int tt = 4095-l; pos = ((tt&63)<<6) | (tt>>6); }
        atomicAdd(&ycomb[(size_t)pos*1024 + d], ys + Dv*u);
      }
    }
  }
}

// ---------------------------------------------------------------------------
// Combine: per-pixel LN over 1024 dirs-summed y, gate with silu(z) -> yact(l,d)
__global__ void k_combine(const float* __restrict__ ycomb, const float* __restrict__ xz,
                          const float* __restrict__ g, const float* __restrict__ b,
                          float* __restrict__ yact){
  int pos = blockIdx.x, t = threadIdx.x;
  float v[4]; float s=0,q=0;
  #pragma unroll
  for (int i=0;i<4;i++){ v[i] = ycomb[(size_t)pos*1024 + t + i*256]; s+=v[i]; q+=v[i]*v[i]; }
  #pragma unroll
  for (int off=32; off>=1; off>>=1){ s += __shfl_xor(s,off); q += __shfl_xor(q,off); }
  __shared__ float red[8];
  int wid = t>>6;
  if ((t&63)==0){ red[wid*2]=s; red[wid*2+1]=q; }
  __syncthreads();
  float S = red[0]+red[2]+red[4]+red[6];
  float Q = red[1]+red[3]+red[5]+red[7];
  float mu = S*(1.f/1024.f), rs = rsqrtf(Q*(1.f/1024.f) - mu*mu + 1e-5f);
  #pragma unroll
  for (int i=0;i<4;i++){
    int dd = t + i*256;
    float z = xz[(size_t)(1024+dd)*NT + pos];
    float yv = (v[i]-mu)*rs*g[dd] + b[dd];
    yact[(size_t)pos*1024 + dd] = yv * (z * sigmf(z));
  }
}

// ---------------------------------------------------------------------------
// Final: out = avgblur3x3(attn) + fused, f32. grid=512*16.
__global__ void k_blur(const float* __restrict__ attn, const float* __restrict__ fused,
                       float* __restrict__ outp){
  int bid = blockIdx.x; int c = bid>>4, yb = bid&15; int t = threadIdx.x;
  int y = yb*4 + (t>>6), x = t&63;
  const float* p = attn + (size_t)c*NT;
  float s = 0;
  #pragma unroll
  for (int dy=-1; dy<=1; dy++){
    int yy = y+dy; if (yy<0||yy>=64) continue;
    #pragma unroll
    for (int dx=-1; dx<=1; dx++){
      int xx = x+dx; if (xx<0||xx>=64) continue;
      s += p[yy*64+xx];
    }
  }
  float val = s*(1.f/9.f) + fused[(size_t)c*NT + y*64 + x];
  outp[(size_t)c*NT + y*64 + x] = val;
}

// ---------------------------------------------------------------------------
extern "C" void kernel_launch(void* const* d_in, const int* in_sizes, int n_in,
                              void* d_out, int out_size, void* d_ws, size_t ws_size,
                              hipStream_t stream){
  const float* feat = (const float*)d_in[0];
  const float* lat  = (const float*)d_in[1];
  const float* fg_w1= (const float*)d_in[2];
  const float* fg_b1= (const float*)d_in[3];
  const float* fg_w2= (const float*)d_in[4];
  const float* fg_b2= (const float*)d_in[5];
  const float* fb_w1= (const float*)d_in[6];
  const float* ln_g = (const float*)d_in[7];
  const float* ln_b = (const float*)d_in[8];
  const float* dw_w = (const float*)d_in[9];
  const float* dw_b = (const float*)d_in[10];
  const float* pw1_w= (const float*)d_in[11];
  const float* pw1_b= (const float*)d_in[12];
  const float* pw2_w= (const float*)d_in[13];
  const float* pw2_b= (const float*)d_in[14];
  const float* ln1_g= (const float*)d_in[15];
  const float* ln1_b= (const float*)d_in[16];
  const float* inpw = (const float*)d_in[17];
  const float* dc_w = (const float*)d_in[18];
  const float* dc_b = (const float*)d_in[19];
  const float* xpw  = (const float*)d_in[20];
  const float* dtw  = (const float*)d_in[21];
  const float* dtb  = (const float*)d_in[22];
  const float* Alog = (const float*)d_in[23];
  const float* Dsp  = (const float*)d_in[24];
  const float* ong  = (const float*)d_in[25];
  const float* onb  = (const float*)d_in[26];
  const float* opw  = (const float*)d_in[27];
  float* outp = (float*)d_out;
  (void)in_sizes; (void)n_in; (void)out_size; (void)ws_size;

  // ---- workspace regions with reuse (sizes in floats) ------------------
  float* Wp = (float*)d_ws;
  size_t off = 0;
  auto alloc = [&](size_t n){ float* p = Wp + off; off += n; return p; };
  float* S0    = alloc((size_t)1024*NT);   // wf -> xnb -> (Pbuf/Sbuf) -> yact
  float* S1    = alloc((size_t)512*NT);    // h -> h3 -> Hbuf -> attn
  float* P0    = alloc((size_t)512*NT);    // fused (persistent)
  float* P1    = alloc((size_t)2048*NT);   // h2 | wf_bf | w_frag -> xz
  float* P2    = alloc((size_t)1024*NT);   // h4 (front) -> xc
  float* P3    = alloc((size_t)1024*NT);   // xcT
  float* P4    = alloc((size_t)4*NT*64);   // xdblT
  float* P5    = alloc((size_t)4*1024*NT); // hpart -> w_frag2 -> delta
  float* P6    = alloc((size_t)1024*NT);   // g1 (front) -> ycomb
  float* part  = alloc(1024);
  float* stats = alloc(4);
  float* mu1   = alloc(4096);
  float* rs1   = alloc(4096);
  // total ~47.2M floats = 189 MB

  float* wf    = S0;
  float* h     = S1;
  float* h2    = P1;                       // front 512*NT
  float* h3    = S1;
  float* h4    = P2;
  float* fused = P0;
  float* xz    = P1;
  float* xc    = P2;
  float* xcT   = P3;
  float* xdblT = P4;
  float* hpart = P5;                       // 8 planes x 512x4096 f32
  float* delta = P5;
  float* g1    = P6;
  float* ycomb = P6;
  float* yact  = S0;
  float* attn  = S1;
  // bf16 staging
  unsigned short* wf_bf   = (unsigned short*)(P1 + (size_t)512*NT);   // conv B
  unsigned short* w_frag  = (unsigned short*)(P1 + (size_t)1024*NT);  // conv A frags
  unsigned short* xnb     = (unsigned short*)S0;                      // xn bf16 (4096x512)
  unsigned short* w_frag2 = (unsigned short*)P5;                      // in_proj A frags (1M bf16)
  // scan chunk buffers (after xnb dead at step 9):
  float* Pbuf  = S0;                       // 4096*NCH*16 = 2M floats
  float* Sbuf  = S0 + (size_t)2*1048576;   // 2M floats
  float* Hbuf  = S1;                       // 2M floats (h3 dead after step 6)

  // 1) g1 = gelu(fg1(concat))            M=32, K=1024
  hipLaunchKernelGGL((k_gemm<1,1,false>), dim3(64,1), dim3(256), 0, stream,
      32, 1024, 1024, 0, fg_w1, fg_b1, nullptr, feat, lat, 0,0, nullptr, g1);
  // 2) wf = concat * sigmoid(fg2(g1))    M=1024, K=32
  hipLaunchKernelGGL((k_gemm<0,5,false>), dim3(64,16), dim3(256), 0, stream,
      1024, 32, 32, 0, fg_w2, fg_b2, g1, feat, lat, 0,0, nullptr, wf);
  // 3) conv3x3 via bf16 MFMA, split-K x8
  hipLaunchKernelGGL(k_cvt_bf16, dim3(2048), dim3(256), 0, stream, wf, wf_bf);
  hipLaunchKernelGGL(k_cvt_wfrag, dim3(2304), dim3(256), 0, stream, fb_w1, 9216, 288, w_frag);
  hipLaunchKernelGGL(k_conv_mfma, dim3(32,4,8), dim3(256), 0, stream, w_frag, wf_bf, hpart);
  // 4) h = sum(hpart) ; h2 = gelu(LN_global(h))
  hipLaunchKernelGGL(k_red_part8, dim3(512), dim3(256), 0, stream, hpart, h, part);
  hipLaunchKernelGGL(k_red_fin,  dim3(1),   dim3(256), 0, stream, part, stats);
  hipLaunchKernelGGL(k_ln_gelu,  dim3(2048),dim3(256), 0, stream, h, ln_g, ln_b, stats, h2);
  // 5) h3 = dwconv3x3 dil2(h2)
  hipLaunchKernelGGL((k_dwconv<2,0>), dim3(512*16), dim3(256), 0, stream, h2, dw_w, dw_b, h3);
  // 6) h4 = gelu(pw1(h3))
  hipLaunchKernelGGL((k_gemm<0,1,false>), dim3(64,8), dim3(256), 0, stream,
      512, 512, 512, 0, pw1_w, pw1_b, h3, nullptr,nullptr, 0,0, nullptr, h4);
  // 7) fused = pw2(shuffle(h4)) + feature
  hipLaunchKernelGGL((k_gemm<0,4,false>), dim3(64,8), dim3(256), 0, stream,
      512, 512, 512, 0, pw2_w, pw2_b, h4, nullptr,nullptr, 0,1, feat, fused);
  // 8) xnb = LN_c(fused^T) bf16 (NHWC)
  hipLaunchKernelGGL(k_ln1_stats, dim3(64), dim3(256), 0, stream, fused, mu1, rs1);
  hipLaunchKernelGGL(k_ln1_apply, dim3(64,8), dim3(256), 0, stream, fused, ln1_g, ln1_b, mu1, rs1, xnb);
  // 9) xz = in_proj @ xn^T via bf16 MFMA  (w_frag2 staged in dead hpart region)
  hipLaunchKernelGGL(k_cvt_wfrag, dim3(512), dim3(256), 0, stream, inpw, 512, 16, w_frag2);
  hipLaunchKernelGGL(k_xz_mfma, dim3(32,16), dim3(256), 0, stream, w_frag2, xnb, xz);
  // 10) xc = silu(dwconv3x3(xp))
  hipLaunchKernelGGL((k_dwconv<1,1>), dim3(1024*16), dim3(256), 0, stream, xz, dc_w, dc_b, xc);
  // 11) xcT
  hipLaunchKernelGGL(k_transpose64, dim3(1024), dim3(256), 0, stream, xc, xcT);
  // 12) xdblT[k] batched: grid.z = direction
  hipLaunchKernelGGL((k_gemm<0,0,true,1>), dim3(64,1,4), dim3(256), 0, stream,
      64, 1024, 1024, 0, xpw, nullptr, xc, xcT, nullptr, 0,0, nullptr, xdblT);
  // 13) delta[k] batched: grid.z = direction
  hipLaunchKernelGGL((k_gemm<2,2,false,2>), dim3(64,16,4), dim3(256), 0, stream,
      1024, 32, 32, 64, dtw, dtb, xdblT, nullptr,nullptr, 0,0, nullptr, delta);
  // 14) ycomb = 0
  hipLaunchKernelGGL(k_zero, dim3(4096), dim3(256), 0, stream, ycomb);
  // 15) chunked selective scan: partial -> combine -> final
  hipLaunchKernelGGL(k_scan_part, dim3(256*NCH), dim3(64), 0, stream,
      delta, xc, xcT, xdblT, Alog, Pbuf, Sbuf);
  hipLaunchKernelGGL(k_scan_comb, dim3(256), dim3(256), 0, stream, Pbuf, Sbuf, Hbuf);
  hipLaunchKernelGGL(k_scan_fin, dim3(256*NCH), dim3(64), 0, stream,
      delta, xc, xcT, xdblT, Alog, Dsp, Hbuf, ycomb);
  // 16) yact = out_norm(ycomb) * silu(z)
  hipLaunchKernelGGL(k_combine, dim3(4096), dim3(256), 0, stream, ycomb, xz, ong, onb, yact);
  // 17) attn = fused + yact @ out_proj^T   M=512, K=1024, B NHWC
  hipLaunchKernelGGL((k_gemm<2,4,false>), dim3(64,8), dim3(256), 0, stream,
      512, 1024, 1024, 1024, opw, nullptr, yact, nullptr,nullptr, 0,0, fused, attn);
  // 18) out = blur3x3(attn) + fused  -> f32
  hipLaunchKernelGGL(k_blur, dim3(512*16), dim3(256), 0, stream, attn, fused, outp);
}

// Round 12
// 1051.835 us; speedup vs baseline: 3.5259x; 1.0268x over previous
//
#include <hip/hip_runtime.h>

// ---------------------------------------------------------------------------
// FeatureMapApproximator: VMamba-style block. B=1, C=512, H=W=64, L=4096,
// d_inner=1024, K=4 dirs, N=16 states, dt_rank=32.
// f32 pipeline; conv3x3 + xz + out_proj on bf16 MFMA; scan chunked 32x128,
// 4-wave blocks (64 d) to deduplicate B/C HBM traffic.
// ---------------------------------------------------------------------------

#define NT 4096   // pixels (and GEMM N)
#define NCH 32    // scan chunks
#define CHL 128   // chunk length

__device__ __forceinline__ float geluf(float x){ return 0.5f*x*(1.f+erff(x*0.70710678118654752f)); }
__device__ __forceinline__ float sigmf(float x){ return 1.f/(1.f+__expf(-x)); }
__device__ __forceinline__ float softplusf(float x){ return (x>20.f)? x : __logf(1.f+__expf(x)); }
__device__ __forceinline__ unsigned short f2b(float f){
  unsigned u = __float_as_uint(f);
  u += 0x7FFFu + ((u>>16)&1u);          // RNE
  return (unsigned short)(u>>16);
}

// ---------------------------------------------------------------------------
// Generic tiled GEMM (f32). TM=64, TN=64, TK=32, 256 threads, 4x4 acc.
// BMODE 0: B channel-major (rev/shuf). 1: concat(feat,lat). 2: B NHWC (ldb).
// EPI 0 none | 1 gelu | 2 softplus | 4 +f32 res | 5 concat*sigmoid
// TRANSW: write out[n*64+m] via LDS bounce (M==64, EPI 0 only).
// ZB 0: none. 1: xdbl batch. 2: delta batch.
// ---------------------------------------------------------------------------
template<int BMODE, int EPI, bool TRANSW, int ZB=0>
__launch_bounds__(256)
__global__ void k_gemm(int M, int K, int lda, int ldb,
    const float* __restrict__ A, const float* __restrict__ bias,
    const float* __restrict__ Bf, const float* __restrict__ Bc0,
    const float* __restrict__ Bc1, int rev, int shuf,
    const float* __restrict__ resf, float* __restrict__ out)
{
  __shared__ float smem[4352];           // 2 x [32][68] (or 64x68 for TRANSW)
  float* As = smem;
  float* Bs = smem + 2176;
  const int t  = threadIdx.x;
  const int n0 = blockIdx.x*64, m0 = blockIdx.y*64;
  if (ZB==1){
    int z = blockIdx.z;
    A   += (size_t)z*64*1024;
    if (z&1) Bf = Bc0;                   // xcT
    rev  = (z>=2);
    out += (size_t)z*NT*64;
  } else if (ZB==2){
    int z = blockIdx.z;
    A    += (size_t)z*1024*32;
    bias += (size_t)z*1024;
    Bf   += (size_t)z*NT*64;
    out  += (size_t)z*1024*NT;
  }
  float acc[4][4] = {};

  for (int k0=0; k0<K; k0+=32){
    __syncthreads();
    { // stage A (f32 weights, row-major M x K)
      int m = t>>2, kk0 = (t&3)*8;
      float av[8] = {0,0,0,0,0,0,0,0};
      if (m0+m < M){
        const float* pa = A + (size_t)(m0+m)*lda + k0 + kk0;
        float4 a0 = *(const float4*)pa; float4 a1 = *(const float4*)(pa+4);
        av[0]=a0.x; av[1]=a0.y; av[2]=a0.z; av[3]=a0.w;
        av[4]=a1.x; av[5]=a1.y; av[6]=a1.z; av[7]=a1.w;
      }
      #pragma unroll
      for (int j=0;j<8;j++) As[(kk0+j)*68 + m] = av[j];
    }
    if (BMODE==2){
      int n = t>>2, kk0 = (t&3)*8;
      const float* p = Bf + (size_t)(n0+n)*ldb + k0 + kk0;
      float4 x0 = *(const float4*)p; float4 x1 = *(const float4*)(p+4);
      Bs[(kk0+0)*68+n]=x0.x; Bs[(kk0+1)*68+n]=x0.y; Bs[(kk0+2)*68+n]=x0.z; Bs[(kk0+3)*68+n]=x0.w;
      Bs[(kk0+4)*68+n]=x1.x; Bs[(kk0+5)*68+n]=x1.y; Bs[(kk0+6)*68+n]=x1.z; Bs[(kk0+7)*68+n]=x1.w;
    } else {
      int kk = t>>3, n8 = (t&7)*8;
      float bv[8];
      if (BMODE==0){
        int r = k0+kk; if (shuf) r = (r&7)*64 + (r>>3);
        const float* p = Bf + (size_t)r*NT;
        if (!rev){
          float4 x0 = *(const float4*)(p + n0+n8); float4 x1 = *(const float4*)(p + n0+n8+4);
          bv[0]=x0.x;bv[1]=x0.y;bv[2]=x0.z;bv[3]=x0.w;bv[4]=x1.x;bv[5]=x1.y;bv[6]=x1.z;bv[7]=x1.w;
        } else {
          const float* q = p + (4088 - n0 - n8);
          float4 x0 = *(const float4*)q; float4 x1 = *(const float4*)(q+4);
          bv[0]=x1.w;bv[1]=x1.z;bv[2]=x1.y;bv[3]=x1.x;bv[4]=x0.w;bv[5]=x0.z;bv[6]=x0.y;bv[7]=x0.x;
        }
      } else if (BMODE==1){
        int c = k0+kk;
        const float* p = (c<512) ? (Bc0 + (size_t)c*NT) : (Bc1 + (size_t)(c-512)*NT);
        float4 x0 = *(const float4*)(p + n0+n8); float4 x1 = *(const float4*)(p + n0+n8+4);
        bv[0]=x0.x;bv[1]=x0.y;bv[2]=x0.z;bv[3]=x0.w;bv[4]=x1.x;bv[5]=x1.y;bv[6]=x1.z;bv[7]=x1.w;
      } else {
        #pragma unroll
        for (int j=0;j<8;j++) bv[j] = 0.f;
      }
      *(float4*)&Bs[kk*68 + n8]   = make_float4(bv[0],bv[1],bv[2],bv[3]);
      *(float4*)&Bs[kk*68 + n8+4] = make_float4(bv[4],bv[5],bv[6],bv[7]);
    }
    __syncthreads();
    int ti = t>>4, tj = t&15;
    #pragma unroll
    for (int kk=0; kk<32; kk++){
      float4 a4 = *(const float4*)&As[kk*68 + ti*4];
      float4 b4 = *(const float4*)&Bs[kk*68 + tj*4];
      float aa[4] = {a4.x,a4.y,a4.z,a4.w};
      float bb[4] = {b4.x,b4.y,b4.z,b4.w};
      #pragma unroll
      for (int i=0;i<4;i++)
        #pragma unroll
        for (int j=0;j<4;j++) acc[i][j] += aa[i]*bb[j];
    }
  }

  int ti = t>>4, tj = t&15;
  if (!TRANSW){
    #pragma unroll
    for (int i=0;i<4;i++){
      int m = m0 + ti*4 + i;
      if (m >= M) continue;
      float bi = bias ? bias[m] : 0.f;
      float o4[4];
      #pragma unroll
      for (int j=0;j<4;j++){
        int n = n0 + tj*4 + j;
        float v = acc[i][j] + bi;
        if (EPI==1) v = geluf(v);
        else if (EPI==2) v = softplusf(v);
        else if (EPI==4) v = v + resf[(size_t)m*NT + n];
        else if (EPI==5){
          float cv = (m<512)? Bc0[(size_t)m*NT+n] : Bc1[(size_t)(m-512)*NT+n];
          v = cv * sigmf(v);
        }
        o4[j] = v;
      }
      *(float4*)&out[(size_t)m*NT + n0 + tj*4] = make_float4(o4[0],o4[1],o4[2],o4[3]);
    }
  } else {
    __syncthreads();
    #pragma unroll
    for (int i=0;i<4;i++)
      #pragma unroll
      for (int j=0;j<4;j++)
        smem[(tj*4+j)*68 + (ti*4+i)] = acc[i][j];
    __syncthreads();
    int nl = t>>2, c0 = (t&3)*16;
    #pragma unroll
    for (int g4=0; g4<4; g4++){
      float4 v = *(const float4*)&smem[nl*68 + c0 + g4*4];
      *(float4*)&out[(size_t)(n0+nl)*64 + c0 + g4*4] = v;
    }
  }
}

// ---------------------------------------------------------------------------
// f32 -> bf16 (RNE) flat convert: 8 per thread.
__global__ void k_cvt_bf16(const float* __restrict__ in, unsigned short* __restrict__ outp){
  size_t i = ((size_t)blockIdx.x*256 + threadIdx.x)*8;
  float4 a = *(const float4*)(in+i), b = *(const float4*)(in+i+4);
  unsigned short o[8] = { f2b(a.x),f2b(a.y),f2b(a.z),f2b(a.w),
                          f2b(b.x),f2b(b.y),f2b(b.z),f2b(b.w) };
  *(int4*)(outp+i) = *(int4*)o;
}

// ---------------------------------------------------------------------------
// Row-major (M x lda f32) -> MFMA-fragment-linear bf16:
// idx = ((MT*KSn + KS)*64 + lane)*8 + j ; A[m=MT*16+(lane&15)][k=KS*32+(lane>>4)*8+j]
__global__ void k_cvt_wfrag(const float* __restrict__ w, int lda, int KSn,
                            unsigned short* __restrict__ outp){
  int tid = blockIdx.x*256 + threadIdx.x;
  int lane = tid & 63;
  int tmp = tid >> 6;
  int KS = tmp % KSn, MT = tmp / KSn;
  int m = MT*16 + (lane&15);
  int k = KS*32 + (lane>>4)*8;
  const float* p = w + (size_t)m*lda + k;
  float4 a = *(const float4*)p, b = *(const float4*)(p+4);
  unsigned short o[8] = { f2b(a.x),f2b(a.y),f2b(a.z),f2b(a.w),
                          f2b(b.x),f2b(b.y),f2b(b.z),f2b(b.w) };
  *(int4*)(outp + (size_t)tid*8) = *(int4*)o;
}

// ---------------------------------------------------------------------------
typedef __attribute__((ext_vector_type(8))) short bf16x8;
typedef __attribute__((ext_vector_type(4))) float f32x4;

// conv3x3 via bf16 MFMA 16x16x32. grid (32,4,8), block 256 = 4 waves (2x2).
__launch_bounds__(256)
__global__ void k_conv_mfma(const unsigned short* __restrict__ Wf,
                            const unsigned short* __restrict__ Bb,
                            float* __restrict__ outp){
  __shared__ unsigned short Bs[128*40];
  int t = threadIdx.x;
  int n0 = blockIdx.x*128, m0y = blockIdx.y;
  int kz = blockIdx.z;                          // K slice: 1152, 36 steps
  int w = t>>6, lane = t&63;
  int wm = (w>>1)*64, wn = (w&1)*64;
  int ln15 = lane&15, lhi = lane>>4;
  f32x4 acc[4][4] = {};
  int sn = t & 127, kh = t>>7;
  int p = n0 + sn, py = p>>6, px = p&63;

  for (int ks=0; ks<36; ks++){
    unsigned short tmp[16];
    int kbase = kz*1152 + ks*32 + kh*16;
    #pragma unroll
    for (int j=0;j<16;j++){
      int ka = kbase + j;
      int c = ka/9; int t9 = ka - c*9; int qy = t9/3;
      int dy = qy-1, dx = t9 - qy*3 - 1;
      int yy = py+dy, xx = px+dx;
      tmp[j] = (yy>=0 && yy<64 && xx>=0 && xx<64) ? Bb[(size_t)c*4096 + yy*64 + xx]
                                                  : (unsigned short)0;
    }
    __syncthreads();
    *(int4*)&Bs[sn*40 + kh*16]     = *(int4*)&tmp[0];
    *(int4*)&Bs[sn*40 + kh*16 + 8] = *(int4*)&tmp[8];
    __syncthreads();
    bf16x8 af[4], bf[4];
    int KSab = kz*36 + ks;
    #pragma unroll
    for (int fm=0; fm<4; fm++){
      int MT = m0y*8 + (w>>1)*4 + fm;
      af[fm] = *(const bf16x8*)&Wf[((size_t)MT*288 + KSab)*512 + lane*8];
    }
    #pragma unroll
    for (int fn=0; fn<4; fn++)
      bf[fn] = *(const bf16x8*)&Bs[(wn + fn*16 + ln15)*40 + lhi*8];
    #pragma unroll
    for (int fm=0; fm<4; fm++)
      #pragma unroll
      for (int fn=0; fn<4; fn++)
        acc[fm][fn] = __builtin_amdgcn_mfma_f32_16x16x32_bf16(af[fm], bf[fn], acc[fm][fn], 0,0,0);
  }
  float* op = outp + (size_t)kz*512*4096;
  #pragma unroll
  for (int fm=0; fm<4; fm++){
    #pragma unroll
    for (int fn=0; fn<4; fn++){
      int col = n0 + wn + fn*16 + ln15;
      int rowb = m0y*128 + wm + fm*16 + lhi*4;
      #pragma unroll
      for (int r=0; r<4; r++)
        op[(size_t)(rowb+r)*4096 + col] = acc[fm][fn][r];
    }
  }
}

// ---------------------------------------------------------------------------
// NHWC bf16 B GEMM via MFMA: out[m][n] = acc (+res). grid (32, M/128).
// KSTEPS = K/32. EPI 0: plain f32 out. EPI 4: + resf.
template<int KSTEPS, int EPI>
__launch_bounds__(256)
__global__ void k_nhwc_mfma(const unsigned short* __restrict__ Wf,
                            const unsigned short* __restrict__ Bb, int ldb,
                            const float* __restrict__ resf,
                            float* __restrict__ outp){
  __shared__ unsigned short Bs[128*40];
  int t = threadIdx.x;
  int n0 = blockIdx.x*128, m0y = blockIdx.y;
  int w = t>>6, lane = t&63;
  int wm = (w>>1)*64, wn = (w&1)*64;
  int ln15 = lane&15, lhi = lane>>4;
  f32x4 acc[4][4] = {};
  int sn = t & 127, kh = t>>7;

  for (int ks=0; ks<KSTEPS; ks++){
    const unsigned short* src = Bb + (size_t)(n0+sn)*ldb + ks*32 + kh*16;
    int4 v0 = *(const int4*)src;
    int4 v1 = *(const int4*)(src+8);
    __syncthreads();
    *(int4*)&Bs[sn*40 + kh*16]     = v0;
    *(int4*)&Bs[sn*40 + kh*16 + 8] = v1;
    __syncthreads();
    bf16x8 af[4], bf[4];
    #pragma unroll
    for (int fm=0; fm<4; fm++){
      int MT = m0y*8 + (w>>1)*4 + fm;
      af[fm] = *(const bf16x8*)&Wf[((size_t)MT*KSTEPS + ks)*512 + lane*8];
    }
    #pragma unroll
    for (int fn=0; fn<4; fn++)
      bf[fn] = *(const bf16x8*)&Bs[(wn + fn*16 + ln15)*40 + lhi*8];
    #pragma unroll
    for (int fm=0; fm<4; fm++)
      #pragma unroll
      for (int fn=0; fn<4; fn++)
        acc[fm][fn] = __builtin_amdgcn_mfma_f32_16x16x32_bf16(af[fm], bf[fn], acc[fm][fn], 0,0,0);
  }
  #pragma unroll
  for (int fm=0; fm<4; fm++){
    #pragma unroll
    for (int fn=0; fn<4; fn++){
      int col = n0 + wn + fn*16 + ln15;
      int rowb = m0y*128 + wm + fm*16 + lhi*4;
      #pragma unroll
      for (int r=0; r<4; r++){
        float v = acc[fm][fn][r];
        if (EPI==4) v += resf[(size_t)(rowb+r)*4096 + col];
        outp[(size_t)(rowb+r)*4096 + col] = v;
      }
    }
  }
}

// ---------------------------------------------------------------------------
// Depthwise 3x3 conv (dilated), optional SiLU. grid = C*16, block 256.
template<int DIL, int ACT>
__global__ void k_dwconv(const float* __restrict__ in, const float* __restrict__ w,
                         const float* __restrict__ b, float* __restrict__ out){
  int bid = blockIdx.x;
  int c = bid >> 4, yb = bid & 15;
  int t = threadIdx.x;
  int y = yb*4 + (t>>6), x = t&63;
  const float* pin = in + (size_t)c*NT;
  float acc = b[c];
  #pragma unroll
  for (int ky=0; ky<3; ky++){
    int yy = y + DIL*(ky-1);
    if (yy<0 || yy>=64) continue;
    #pragma unroll
    for (int kx=0; kx<3; kx++){
      int xx = x + DIL*(kx-1);
      if (xx<0 || xx>=64) continue;
      acc += w[c*9 + ky*3 + kx] * pin[yy*64+xx];
    }
  }
  if (ACT==1) acc = acc * sigmf(acc);
  out[(size_t)c*NT + y*64 + x] = acc;
}

// ---------------------------------------------------------------------------
// Global LN: sum 8 split-K partials -> h, partial stats -> final -> apply(gelu)
__global__ void k_red_part8(const float* __restrict__ hp, float* __restrict__ h,
                            float* __restrict__ part){
  __shared__ float ls[256], lq[256];
  int t = threadIdx.x; size_t base = (size_t)blockIdx.x*4096 + t;
  const size_t SL = (size_t)512*4096;
  float s=0, q=0;
  #pragma unroll
  for (int i=0;i<16;i++){
    size_t idx = base + i*256;
    float v = 0.f;
    #pragma unroll
    for (int z=0; z<8; z++) v += hp[idx + z*SL];
    h[idx] = v; s+=v; q+=v*v;
  }
  ls[t]=s; lq[t]=q; __syncthreads();
  for (int off=128; off; off>>=1){ if (t<off){ ls[t]+=ls[t+off]; lq[t]+=lq[t+off]; } __syncthreads(); }
  if (t==0){ part[blockIdx.x] = ls[0]; part[512 + blockIdx.x] = lq[0]; }
}
__global__ void k_red_fin(const float* __restrict__ part, float* __restrict__ stats){
  __shared__ float ls[256], lq[256];
  int t = threadIdx.x;
  ls[t] = part[t] + part[t+256];
  lq[t] = part[512+t] + part[768+t];
  __syncthreads();
  for (int off=128; off; off>>=1){ if (t<off){ ls[t]+=ls[t+off]; lq[t]+=lq[t+off]; } __syncthreads(); }
  if (t==0){
    float mu = ls[0] * (1.f/2097152.f);
    float var = lq[0]*(1.f/2097152.f) - mu*mu;
    stats[0]=mu; stats[1]=rsqrtf(var + 1e-5f);
  }
}
__global__ void k_ln_gelu(const float* __restrict__ h, const float* __restrict__ g,
                          const float* __restrict__ b, const float* __restrict__ stats,
                          float* __restrict__ out){
  size_t idx = ((size_t)blockIdx.x*256 + threadIdx.x)*4;
  float mu = stats[0], rs = stats[1];
  float4 hv = *(const float4*)(h + idx);
  float4 gv = *(const float4*)(g + idx);
  float4 bv = *(const float4*)(b + idx);
  float4 o;
  o.x = geluf((hv.x-mu)*rs*gv.x+bv.x);
  o.y = geluf((hv.y-mu)*rs*gv.y+bv.y);
  o.z = geluf((hv.z-mu)*rs*gv.z+bv.z);
  o.w = geluf((hv.w-mu)*rs*gv.w+bv.w);
  *(float4*)(out + idx) = o;
}

// ---------------------------------------------------------------------------
// Per-pixel LN over C=512 (stats), then apply+transpose to NHWC bf16 xnb(4096,512)
__global__ void k_ln1_stats(const float* __restrict__ fused, float* __restrict__ mu1,
                            float* __restrict__ rs1){
  __shared__ float ss[256], sq[256];
  int t = threadIdx.x; int ci = t>>6; int pj = t&63;
  int pos = blockIdx.x*64 + pj;
  float s=0,q=0;
  for (int c=ci; c<512; c+=4){ float v = fused[(size_t)c*NT + pos]; s+=v; q+=v*v; }
  ss[t]=s; sq[t]=q; __syncthreads();
  if (ci==0){
    float S = ss[pj]+ss[64+pj]+ss[128+pj]+ss[192+pj];
    float Q = sq[pj]+sq[64+pj]+sq[128+pj]+sq[192+pj];
    float mu = S*(1.f/512.f);
    mu1[pos]=mu; rs1[pos]=rsqrtf(Q*(1.f/512.f) - mu*mu + 1e-5f);
  }
}
__global__ void k_ln1_apply(const float* __restrict__ fused, const float* __restrict__ g,
                            const float* __restrict__ b, const float* __restrict__ mu1,
                            const float* __restrict__ rs1, unsigned short* __restrict__ xnb){
  __shared__ float tile[64*65];
  int t = threadIdx.x;
  int p0 = blockIdx.x*64, c0 = blockIdx.y*64;
  for (int it=0; it<16; it++){
    int idx = t + it*256; int yy = idx>>6, xx = idx&63;
    tile[yy*65+xx] = fused[(size_t)(c0+yy)*NT + p0+xx];
  }
  __syncthreads();
  for (int it=0; it<16; it++){
    int idx = t + it*256; int r = idx>>6, s = idx&63;
    float v = tile[s*65+r];
    int pos = p0+r, c = c0+s;
    xnb[(size_t)pos*512 + c] = f2b((v - mu1[pos])*rs1[pos]*g[c] + b[c]);
  }
}

// ---------------------------------------------------------------------------
// Per-channel 64x64 transpose: out[d][w*64+h] = in[d][h*64+w]. grid=1024.
__global__ void k_transpose64(const float* __restrict__ in, float* __restrict__ out){
  __shared__ float tile[64*65];
  int d = blockIdx.x; int t = threadIdx.x;
  const float* p = in + (size_t)d*NT; float* q = out + (size_t)d*NT;
  for (int it=0; it<16; it++){
    int idx = t+it*256; int yy = idx>>6, xx = idx&63;
    tile[yy*65+xx] = p[idx];
  }
  __syncthreads();
  for (int it=0; it<16; it++){
    int idx = t+it*256; int w = idx>>6, hh = idx&63;
    q[idx] = tile[hh*65+w];
  }
}

// ---------------------------------------------------------------------------
__global__ void k_zero(float* __restrict__ p){
  size_t i = ((size_t)blockIdx.x*256 + threadIdx.x)*4;
  *(float4*)(p+i) = make_float4(0,0,0,0);
}

// ---------------------------------------------------------------------------
// Chunked selective scan, phase A. grid = 64 (k,dblk) * NCH, block 256
// (4 waves; wave w covers d = dblk*64 + w*16 + dsub). B/C reads shared
// across the 4 waves via L1.
__launch_bounds__(256)
__global__ void k_scan_part(const float* __restrict__ delta, const float* __restrict__ xc,
                            const float* __restrict__ xcT, const float* __restrict__ xdblT,
                            const float* __restrict__ A_logs,
                            float* __restrict__ Pbuf, float* __restrict__ Sbuf){
  int bid = blockIdx.x;
  int c    = bid % NCH;
  int rest = bid / NCH;            // 0..63
  int k    = rest >> 4;
  int dblk = rest & 15;
  int w    = threadIdx.x >> 6;
  int lane = threadIdx.x & 63;
  int dsub = lane & 15, ngrp = lane >> 4;
  int d = dblk*64 + w*16 + dsub;
  const float* up = ((k&1)? xcT : xc) + (size_t)d*NT;
  const float* dp = delta + ((size_t)(k*1024 + d))*NT;
  const float* bc = xdblT + (size_t)k*NT*64;
  float A[4], S[4]={0,0,0,0}, P[4]={1.f,1.f,1.f,1.f};
  #pragma unroll
  for (int j=0;j<4;j++) A[j] = -__expf(A_logs[(size_t)(k*1024+d)*16 + ngrp*4 + j]);
  const bool rv = (k>=2);
  int base = c*CHL;
  for (int l0=base; l0<base+CHL; l0+=4){
    float4 dv4 = *(const float4*)(dp + l0);
    float4 uraw = rv ? *(const float4*)(up + (4092-l0)) : *(const float4*)(up + l0);
    float dts[4] = {dv4.x,dv4.y,dv4.z,dv4.w};
    float us[4];
    if (rv){ us[0]=uraw.w; us[1]=uraw.z; us[2]=uraw.y; us[3]=uraw.x; }
    else   { us[0]=uraw.x; us[1]=uraw.y; us[2]=uraw.z; us[3]=uraw.w; }
    #pragma unroll
    for (int s=0;s<4;s++){
      int l = l0+s;
      float dt = dts[s];
      float4 B4 = *(const float4*)(bc + (size_t)l*64 + 32 + ngrp*4);
      float xbu = dt*us[s];
      float Bv[4]={B4.x,B4.y,B4.z,B4.w};
      #pragma unroll
      for (int j=0;j<4;j++){
        float dA = __expf(dt*A[j]);
        S[j] = dA*S[j] + xbu*Bv[j];
        P[j] *= dA;
      }
    }
  }
  size_t o = ((size_t)(k*1024+d)*NCH + c)*16 + ngrp*4;
  *(float4*)&Pbuf[o] = make_float4(P[0],P[1],P[2],P[3]);
  *(float4*)&Sbuf[o] = make_float4(S[0],S[1],S[2],S[3]);
}

// ---------------------------------------------------------------------------
// Phase B: serial combine over chunks. grid=256, block=256.
__global__ void k_scan_comb(const float* __restrict__ Pbuf, const float* __restrict__ Sbuf,
                            float* __restrict__ Hbuf){
  int tid = blockIdx.x*256 + threadIdx.x;
  int scan = tid >> 4, n = tid & 15;
  size_t base = (size_t)scan*(NCH*16) + n;
  float h = 0.f;
  #pragma unroll
  for (int c=0;c<NCH;c++){
    Hbuf[base + c*16] = h;
    h = Pbuf[base + c*16]*h + Sbuf[base + c*16];
  }
}

// ---------------------------------------------------------------------------
// Phase C: re-run chunk from h_in, compute y, atomicAdd into ycomb(l,d).
// Same 4-wave structure as phase A.
__launch_bounds__(256)
__global__ void k_scan_fin(const float* __restrict__ delta, const float* __restrict__ xc,
                           const float* __restrict__ xcT, const float* __restrict__ xdblT,
                           const float* __restrict__ A_logs, const float* __restrict__ Ds,
                           const float* __restrict__ Hbuf, float* __restrict__ ycomb){
  int bid = blockIdx.x;
  int c    = bid % NCH;
  int rest = bid / NCH;
  int k    = rest >> 4;
  int dblk = rest & 15;
  int w    = threadIdx.x >> 6;
  int lane = threadIdx.x & 63;
  int dsub = lane & 15, ngrp = lane >> 4;
  int d = dblk*64 + w*16 + dsub;
  const float* up = ((k&1)? xcT : xc) + (size_t)d*NT;
  const float* dp = delta + ((size_t)(k*1024 + d))*NT;
  const float* bc = xdblT + (size_t)k*NT*64;
  float A[4], h[4];
  #pragma unroll
  for (int j=0;j<4;j++) A[j] = -__expf(A_logs[(size_t)(k*1024+d)*16 + ngrp*4 + j]);
  {
    size_t o = ((size_t)(k*1024+d)*NCH + c)*16 + ngrp*4;
    float4 h4 = *(const float4*)&Hbuf[o];
    h[0]=h4.x; h[1]=h4.y; h[2]=h4.z; h[3]=h4.w;
  }
  float Dv = Ds[k*1024+d];
  const bool rv = (k>=2);
  int base = c*CHL;
  for (int l0=base; l0<base+CHL; l0+=4){
    float4 dv4 = *(const float4*)(dp + l0);
    float4 uraw = rv ? *(const float4*)(up + (4092-l0)) : *(const float4*)(up + l0);
    float dts[4] = {dv4.x,dv4.y,dv4.z,dv4.w};
    float us[4];
    if (rv){ us[0]=uraw.w; us[1]=uraw.z; us[2]=uraw.y; us[3]=uraw.x; }
    else   { us[0]=uraw.x; us[1]=uraw.y; us[2]=uraw.z; us[3]=uraw.w; }
    #pragma unroll
    for (int s=0;s<4;s++){
      int l = l0+s;
      float dt = dts[s], u = us[s];
      float4 B4 = *(const float4*)(bc + (size_t)l*64 + 32 + ngrp*4);
      float4 C4 = *(const float4*)(bc + (size_t)l*64 + 48 + ngrp*4);
      float xbu = dt*u;
      float Bv[4]={B4.x,B4.y,B4.z,B4.w}, Cv[4]={C4.x,C4.y,C4.z,C4.w};
      float ys = 0.f;
      #pragma unroll
      for (int j=0;j<4;j++){
        float dA = __expf(dt*A[j]);
        h[j] = dA*h[j] + xbu*Bv[j];
        ys += h[j]*Cv[j];
      }
      ys += __shfl_xor(ys, 16);
      ys += __shfl_xor(ys, 32);
      if (ngrp==0){
        int pos;
        if (k==0) pos = l;
        else if (k==1) pos = ((l&63)<<6) | (l>>6);
        else if (k==2) pos = 4095-l;
        else { int tt = 4095-l; pos = ((tt&63)<<6) | (tt>>6); }
        atomicAdd(&ycomb[(size_t)pos*1024 + d], ys + Dv*u);
      }
    }
  }
}

// ---------------------------------------------------------------------------
// Combine: per-pixel LN over 1024 dirs-summed y, gate with silu(z),
// write yact as bf16 NHWC (feeds out_proj MFMA).
__global__ void k_combine(const float* __restrict__ ycomb, const float* __restrict__ xz,
                          const float* __restrict__ g, const float* __restrict__ b,
                          unsigned short* __restrict__ yactb){
  int pos = blockIdx.x, t = threadIdx.x;
  float v[4]; float s=0,q=0;
  #pragma unroll
  for (int i=0;i<4;i++){ v[i] = ycomb[(size_t)pos*1024 + t + i*256]; s+=v[i]; q+=v[i]*v[i]; }
  #pragma unroll
  for (int off=32; off>=1; off>>=1){ s += __shfl_xor(s,off); q += __shfl_xor(q,off); }
  __shared__ float red[8];
  int wid = t>>6;
  if ((t&63)==0){ red[wid*2]=s; red[wid*2+1]=q; }
  __syncthreads();
  float S = red[0]+red[2]+red[4]+red[6];
  float Q = red[1]+red[3]+red[5]+red[7];
  float mu = S*(1.f/1024.f), rs = rsqrtf(Q*(1.f/1024.f) - mu*mu + 1e-5f);
  #pragma unroll
  for (int i=0;i<4;i++){
    int dd = t + i*256;
    float z = xz[(size_t)(1024+dd)*NT + pos];
    float yv = (v[i]-mu)*rs*g[dd] + b[dd];
    yactb[(size_t)pos*1024 + dd] = f2b(yv * (z * sigmf(z)));
  }
}

// ---------------------------------------------------------------------------
// Final: out = avgblur3x3(attn) + fused, f32. grid=512*16.
__global__ void k_blur(const float* __restrict__ attn, const float* __restrict__ fused,
                       float* __restrict__ outp){
  int bid = blockIdx.x; int c = bid>>4, yb = bid&15; int t = threadIdx.x;
  int y = yb*4 + (t>>6), x = t&63;
  const float* p = attn + (size_t)c*NT;
  float s = 0;
  #pragma unroll
  for (int dy=-1; dy<=1; dy++){
    int yy = y+dy; if (yy<0||yy>=64) continue;
    #pragma unroll
    for (int dx=-1; dx<=1; dx++){
      int xx = x+dx; if (xx<0||xx>=64) continue;
      s += p[yy*64+xx];
    }
  }
  float val = s*(1.f/9.f) + fused[(size_t)c*NT + y*64 + x];
  outp[(size_t)c*NT + y*64 + x] = val;
}

// ---------------------------------------------------------------------------
extern "C" void kernel_launch(void* const* d_in, const int* in_sizes, int n_in,
                              void* d_out, int out_size, void* d_ws, size_t ws_size,
                              hipStream_t stream){
  const float* feat = (const float*)d_in[0];
  const float* lat  = (const float*)d_in[1];
  const float* fg_w1= (const float*)d_in[2];
  const float* fg_b1= (const float*)d_in[3];
  const float* fg_w2= (const float*)d_in[4];
  const float* fg_b2= (const float*)d_in[5];
  const float* fb_w1= (const float*)d_in[6];
  const float* ln_g = (const float*)d_in[7];
  const float* ln_b = (const float*)d_in[8];
  const float* dw_w = (const float*)d_in[9];
  const float* dw_b = (const float*)d_in[10];
  const float* pw1_w= (const float*)d_in[11];
  const float* pw1_b= (const float*)d_in[12];
  const float* pw2_w= (const float*)d_in[13];
  const float* pw2_b= (const float*)d_in[14];
  const float* ln1_g= (const float*)d_in[15];
  const float* ln1_b= (const float*)d_in[16];
  const float* inpw = (const float*)d_in[17];
  const float* dc_w = (const float*)d_in[18];
  const float* dc_b = (const float*)d_in[19];
  const float* xpw  = (const float*)d_in[20];
  const float* dtw  = (const float*)d_in[21];
  const float* dtb  = (const float*)d_in[22];
  const float* Alog = (const float*)d_in[23];
  const float* Dsp  = (const float*)d_in[24];
  const float* ong  = (const float*)d_in[25];
  const float* onb  = (const float*)d_in[26];
  const float* opw  = (const float*)d_in[27];
  float* outp = (float*)d_out;
  (void)in_sizes; (void)n_in; (void)out_size; (void)ws_size;

  // ---- workspace regions with reuse (sizes in floats) ------------------
  float* Wp = (float*)d_ws;
  size_t off = 0;
  auto alloc = [&](size_t n){ float* p = Wp + off; off += n; return p; };
  float* S0    = alloc((size_t)1024*NT);   // wf -> xnb -> (Pbuf/Sbuf) -> yactb
  float* S1    = alloc((size_t)512*NT);    // h -> h3 -> Hbuf -> attn
  float* P0    = alloc((size_t)512*NT);    // fused (persistent)
  float* P1    = alloc((size_t)2048*NT);   // h2 | wf_bf | w_frag -> xz
  float* P2    = alloc((size_t)1024*NT);   // h4 (front) -> xc
  float* P3    = alloc((size_t)1024*NT);   // xcT
  float* P4    = alloc((size_t)4*NT*64);   // xdblT
  float* P5    = alloc((size_t)4*1024*NT); // hpart -> w_frag2 -> delta -> w_frag3
  float* P6    = alloc((size_t)1024*NT);   // g1 (front) -> ycomb
  float* part  = alloc(1024);
  float* stats = alloc(4);
  float* mu1   = alloc(4096);
  float* rs1   = alloc(4096);
  // total ~47.2M floats = 189 MB

  float* wf    = S0;
  float* h     = S1;
  float* h2    = P1;                       // front 512*NT
  float* h3    = S1;
  float* h4    = P2;
  float* fused = P0;
  float* xz    = P1;
  float* xc    = P2;
  float* xcT   = P3;
  float* xdblT = P4;
  float* hpart = P5;                       // 8 planes x 512x4096 f32
  float* delta = P5;
  float* g1    = P6;
  float* ycomb = P6;
  float* attn  = S1;
  // bf16 staging
  unsigned short* wf_bf   = (unsigned short*)(P1 + (size_t)512*NT);   // conv B
  unsigned short* w_frag  = (unsigned short*)(P1 + (size_t)1024*NT);  // conv A frags
  unsigned short* xnb     = (unsigned short*)S0;                      // xn bf16 (4096x512)
  unsigned short* w_frag2 = (unsigned short*)P5;                      // in_proj A frags
  unsigned short* yactb   = (unsigned short*)S0;                      // yact bf16 (4096x1024)
  unsigned short* w_frag3 = (unsigned short*)P5;                      // out_proj A frags (dead delta)
  // scan chunk buffers (after xnb dead at step 9):
  float* Pbuf  = S0;                       // 4096*NCH*16 = 2M floats
  float* Sbuf  = S0 + (size_t)2*1048576;   // 2M floats
  float* Hbuf  = S1;                       // 2M floats (h3 dead after step 6)

  // 1) g1 = gelu(fg1(concat))            M=32, K=1024
  hipLaunchKernelGGL((k_gemm<1,1,false>), dim3(64,1), dim3(256), 0, stream,
      32, 1024, 1024, 0, fg_w1, fg_b1, nullptr, feat, lat, 0,0, nullptr, g1);
  // 2) wf = concat * sigmoid(fg2(g1))    M=1024, K=32
  hipLaunchKernelGGL((k_gemm<0,5,false>), dim3(64,16), dim3(256), 0, stream,
      1024, 32, 32, 0, fg_w2, fg_b2, g1, feat, lat, 0,0, nullptr, wf);
  // 3) conv3x3 via bf16 MFMA, split-K x8
  hipLaunchKernelGGL(k_cvt_bf16, dim3(2048), dim3(256), 0, stream, wf, wf_bf);
  hipLaunchKernelGGL(k_cvt_wfrag, dim3(2304), dim3(256), 0, stream, fb_w1, 9216, 288, w_frag);
  hipLaunchKernelGGL(k_conv_mfma, dim3(32,4,8), dim3(256), 0, stream, w_frag, wf_bf, hpart);
  // 4) h = sum(hpart) ; h2 = gelu(LN_global(h))
  hipLaunchKernelGGL(k_red_part8, dim3(512), dim3(256), 0, stream, hpart, h, part);
  hipLaunchKernelGGL(k_red_fin,  dim3(1),   dim3(256), 0, stream, part, stats);
  hipLaunchKernelGGL(k_ln_gelu,  dim3(2048),dim3(256), 0, stream, h, ln_g, ln_b, stats, h2);
  // 5) h3 = dwconv3x3 dil2(h2)
  hipLaunchKernelGGL((k_dwconv<2,0>), dim3(512*16), dim3(256), 0, stream, h2, dw_w, dw_b, h3);
  // 6) h4 = gelu(pw1(h3))
  hipLaunchKernelGGL((k_gemm<0,1,false>), dim3(64,8), dim3(256), 0, stream,
      512, 512, 512, 0, pw1_w, pw1_b, h3, nullptr,nullptr, 0,0, nullptr, h4);
  // 7) fused = pw2(shuffle(h4)) + feature
  hipLaunchKernelGGL((k_gemm<0,4,false>), dim3(64,8), dim3(256), 0, stream,
      512, 512, 512, 0, pw2_w, pw2_b, h4, nullptr,nullptr, 0,1, feat, fused);
  // 8) xnb = LN_c(fused^T) bf16 (NHWC)
  hipLaunchKernelGGL(k_ln1_stats, dim3(64), dim3(256), 0, stream, fused, mu1, rs1);
  hipLaunchKernelGGL(k_ln1_apply, dim3(64,8), dim3(256), 0, stream, fused, ln1_g, ln1_b, mu1, rs1, xnb);
  // 9) xz = in_proj @ xn^T via bf16 MFMA  (w_frag2 in dead hpart region)
  hipLaunchKernelGGL(k_cvt_wfrag, dim3(512), dim3(256), 0, stream, inpw, 512, 16, w_frag2);
  hipLaunchKernelGGL((k_nhwc_mfma<16,0>), dim3(32,16), dim3(256), 0, stream,
      w_frag2, xnb, 512, nullptr, xz);
  // 10) xc = silu(dwconv3x3(xp))
  hipLaunchKernelGGL((k_dwconv<1,1>), dim3(1024*16), dim3(256), 0, stream, xz, dc_w, dc_b, xc);
  // 11) xcT
  hipLaunchKernelGGL(k_transpose64, dim3(1024), dim3(256), 0, stream, xc, xcT);
  // 12) xdblT[k] batched: grid.z = direction
  hipLaunchKernelGGL((k_gemm<0,0,true,1>), dim3(64,1,4), dim3(256), 0, stream,
      64, 1024, 1024, 0, xpw, nullptr, xc, xcT, nullptr, 0,0, nullptr, xdblT);
  // 13) delta[k] batched: grid.z = direction
  hipLaunchKernelGGL((k_gemm<2,2,false,2>), dim3(64,16,4), dim3(256), 0, stream,
      1024, 32, 32, 64, dtw, dtb, xdblT, nullptr,nullptr, 0,0, nullptr, delta);
  // 14) ycomb = 0
  hipLaunchKernelGGL(k_zero, dim3(4096), dim3(256), 0, stream, ycomb);
  // 15) chunked selective scan: partial -> combine -> final (4-wave blocks)
  hipLaunchKernelGGL(k_scan_part, dim3(64*NCH), dim3(256), 0, stream,
      delta, xc, xcT, xdblT, Alog, Pbuf, Sbuf);
  hipLaunchKernelGGL(k_scan_comb, dim3(256), dim3(256), 0, stream, Pbuf, Sbuf, Hbuf);
  hipLaunchKernelGGL(k_scan_fin, dim3(64*NCH), dim3(256), 0, stream,
      delta, xc, xcT, xdblT, Alog, Dsp, Hbuf, ycomb);
  // 16) yactb = out_norm(ycomb) * silu(z)  (bf16 NHWC)
  hipLaunchKernelGGL(k_combine, dim3(4096), dim3(256), 0, stream, ycomb, xz, ong, onb, yactb);
  // 17) attn = fused + yact @ out_proj^T via bf16 MFMA (w_frag3 in dead delta)
  hipLaunchKernelGGL(k_cvt_wfrag, dim3(256), dim3(256), 0, stream, opw, 1024, 32, w_frag3);
  hipLaunchKernelGGL((k_nhwc_mfma<32,4>), dim3(32,4), dim3(256), 0, stream,
      w_frag3, yactb, 1024, fused, attn);
  // 18) out = blur3x3(attn) + fused  -> f32
  hipLaunchKernelGGL(k_blur, dim3(512*16), dim3(256), 0, stream, attn, fused, outp);
}

// Round 13
// 942.327 us; speedup vs baseline: 3.9356x; 1.1162x over previous
//
#include <hip/hip_runtime.h>

// ---------------------------------------------------------------------------
// FeatureMapApproximator: VMamba-style block. B=1, C=512, H=W=64, L=4096,
// d_inner=1024, K=4 dirs, N=16 states, dt_rank=32.
// f32 pipeline; conv3x3 + pw1 + pw2 + xz + out_proj on bf16 MFMA;
// scan chunked 32x128 with LDS-staged delta/u (coalesced HBM reads).
// ---------------------------------------------------------------------------

#define NT 4096   // pixels (and GEMM N)
#define NCH 32    // scan chunks
#define CHL 128   // chunk length

__device__ __forceinline__ float geluf(float x){ return 0.5f*x*(1.f+erff(x*0.70710678118654752f)); }
__device__ __forceinline__ float sigmf(float x){ return 1.f/(1.f+__expf(-x)); }
__device__ __forceinline__ float softplusf(float x){ return (x>20.f)? x : __logf(1.f+__expf(x)); }
__device__ __forceinline__ unsigned short f2b(float f){
  unsigned u = __float_as_uint(f);
  u += 0x7FFFu + ((u>>16)&1u);          // RNE
  return (unsigned short)(u>>16);
}

// ---------------------------------------------------------------------------
// Generic tiled GEMM (f32). TM=64, TN=64, TK=32, 256 threads, 4x4 acc.
// Used for: fg1 (BMODE1), fg2 (BMODE0+EPI5), xdbl batch (ZB1, TRANSW),
// delta batch (ZB2, BMODE2+EPI2).
template<int BMODE, int EPI, bool TRANSW, int ZB=0>
__launch_bounds__(256)
__global__ void k_gemm(int M, int K, int lda, int ldb,
    const float* __restrict__ A, const float* __restrict__ bias,
    const float* __restrict__ Bf, const float* __restrict__ Bc0,
    const float* __restrict__ Bc1, int rev, int shuf,
    const float* __restrict__ resf, float* __restrict__ out)
{
  __shared__ float smem[4352];
  float* As = smem;
  float* Bs = smem + 2176;
  const int t  = threadIdx.x;
  const int n0 = blockIdx.x*64, m0 = blockIdx.y*64;
  if (ZB==1){
    int z = blockIdx.z;
    A   += (size_t)z*64*1024;
    if (z&1) Bf = Bc0;                   // xcT
    rev  = (z>=2);
    out += (size_t)z*NT*64;
  } else if (ZB==2){
    int z = blockIdx.z;
    A    += (size_t)z*1024*32;
    bias += (size_t)z*1024;
    Bf   += (size_t)z*NT*64;
    out  += (size_t)z*1024*NT;
  }
  float acc[4][4] = {};

  for (int k0=0; k0<K; k0+=32){
    __syncthreads();
    { // stage A
      int m = t>>2, kk0 = (t&3)*8;
      float av[8] = {0,0,0,0,0,0,0,0};
      if (m0+m < M){
        const float* pa = A + (size_t)(m0+m)*lda + k0 + kk0;
        float4 a0 = *(const float4*)pa; float4 a1 = *(const float4*)(pa+4);
        av[0]=a0.x; av[1]=a0.y; av[2]=a0.z; av[3]=a0.w;
        av[4]=a1.x; av[5]=a1.y; av[6]=a1.z; av[7]=a1.w;
      }
      #pragma unroll
      for (int j=0;j<8;j++) As[(kk0+j)*68 + m] = av[j];
    }
    if (BMODE==2){
      int n = t>>2, kk0 = (t&3)*8;
      const float* p = Bf + (size_t)(n0+n)*ldb + k0 + kk0;
      float4 x0 = *(const float4*)p; float4 x1 = *(const float4*)(p+4);
      Bs[(kk0+0)*68+n]=x0.x; Bs[(kk0+1)*68+n]=x0.y; Bs[(kk0+2)*68+n]=x0.z; Bs[(kk0+3)*68+n]=x0.w;
      Bs[(kk0+4)*68+n]=x1.x; Bs[(kk0+5)*68+n]=x1.y; Bs[(kk0+6)*68+n]=x1.z; Bs[(kk0+7)*68+n]=x1.w;
    } else {
      int kk = t>>3, n8 = (t&7)*8;
      float bv[8];
      if (BMODE==0){
        int r = k0+kk; if (shuf) r = (r&7)*64 + (r>>3);
        const float* p = Bf + (size_t)r*NT;
        if (!rev){
          float4 x0 = *(const float4*)(p + n0+n8); float4 x1 = *(const float4*)(p + n0+n8+4);
          bv[0]=x0.x;bv[1]=x0.y;bv[2]=x0.z;bv[3]=x0.w;bv[4]=x1.x;bv[5]=x1.y;bv[6]=x1.z;bv[7]=x1.w;
        } else {
          const float* q = p + (4088 - n0 - n8);
          float4 x0 = *(const float4*)q; float4 x1 = *(const float4*)(q+4);
          bv[0]=x1.w;bv[1]=x1.z;bv[2]=x1.y;bv[3]=x1.x;bv[4]=x0.w;bv[5]=x0.z;bv[6]=x0.y;bv[7]=x0.x;
        }
      } else if (BMODE==1){
        int c = k0+kk;
        const float* p = (c<512) ? (Bc0 + (size_t)c*NT) : (Bc1 + (size_t)(c-512)*NT);
        float4 x0 = *(const float4*)(p + n0+n8); float4 x1 = *(const float4*)(p + n0+n8+4);
        bv[0]=x0.x;bv[1]=x0.y;bv[2]=x0.z;bv[3]=x0.w;bv[4]=x1.x;bv[5]=x1.y;bv[6]=x1.z;bv[7]=x1.w;
      } else {
        #pragma unroll
        for (int j=0;j<8;j++) bv[j] = 0.f;
      }
      *(float4*)&Bs[kk*68 + n8]   = make_float4(bv[0],bv[1],bv[2],bv[3]);
      *(float4*)&Bs[kk*68 + n8+4] = make_float4(bv[4],bv[5],bv[6],bv[7]);
    }
    __syncthreads();
    int ti = t>>4, tj = t&15;
    #pragma unroll
    for (int kk=0; kk<32; kk++){
      float4 a4 = *(const float4*)&As[kk*68 + ti*4];
      float4 b4 = *(const float4*)&Bs[kk*68 + tj*4];
      float aa[4] = {a4.x,a4.y,a4.z,a4.w};
      float bb[4] = {b4.x,b4.y,b4.z,b4.w};
      #pragma unroll
      for (int i=0;i<4;i++)
        #pragma unroll
        for (int j=0;j<4;j++) acc[i][j] += aa[i]*bb[j];
    }
  }

  int ti = t>>4, tj = t&15;
  if (!TRANSW){
    #pragma unroll
    for (int i=0;i<4;i++){
      int m = m0 + ti*4 + i;
      if (m >= M) continue;
      float bi = bias ? bias[m] : 0.f;
      float o4[4];
      #pragma unroll
      for (int j=0;j<4;j++){
        int n = n0 + tj*4 + j;
        float v = acc[i][j] + bi;
        if (EPI==1) v = geluf(v);
        else if (EPI==2) v = softplusf(v);
        else if (EPI==4) v = v + resf[(size_t)m*NT + n];
        else if (EPI==5){
          float cv = (m<512)? Bc0[(size_t)m*NT+n] : Bc1[(size_t)(m-512)*NT+n];
          v = cv * sigmf(v);
        }
        o4[j] = v;
      }
      *(float4*)&out[(size_t)m*NT + n0 + tj*4] = make_float4(o4[0],o4[1],o4[2],o4[3]);
    }
  } else {
    __syncthreads();
    #pragma unroll
    for (int i=0;i<4;i++)
      #pragma unroll
      for (int j=0;j<4;j++)
        smem[(tj*4+j)*68 + (ti*4+i)] = acc[i][j];
    __syncthreads();
    int nl = t>>2, c0 = (t&3)*16;
    #pragma unroll
    for (int g4=0; g4<4; g4++){
      float4 v = *(const float4*)&smem[nl*68 + c0 + g4*4];
      *(float4*)&out[(size_t)(n0+nl)*64 + c0 + g4*4] = v;
    }
  }
}

// ---------------------------------------------------------------------------
// f32 -> bf16 (RNE) flat convert: 8 per thread.
__global__ void k_cvt_bf16(const float* __restrict__ in, unsigned short* __restrict__ outp){
  size_t i = ((size_t)blockIdx.x*256 + threadIdx.x)*8;
  float4 a = *(const float4*)(in+i), b = *(const float4*)(in+i+4);
  unsigned short o[8] = { f2b(a.x),f2b(a.y),f2b(a.z),f2b(a.w),
                          f2b(b.x),f2b(b.y),f2b(b.z),f2b(b.w) };
  *(int4*)(outp+i) = *(int4*)o;
}

// ---------------------------------------------------------------------------
// channel-major f32 [512][4096] -> NHWC bf16 [4096][512] (optional shuffle
// on source channel). grid (64 ptile, 8 ctile), 256 threads.
__global__ void k_cvtT_bf16(const float* __restrict__ in, int shuf,
                            unsigned short* __restrict__ outp){
  __shared__ float tile[64*65];
  int t = threadIdx.x;
  int p0 = blockIdx.x*64, c0 = blockIdx.y*64;
  for (int it=0; it<16; it++){
    int idx = t + it*256; int yy = idx>>6, xx = idx&63;   // yy=c-local
    int c = c0 + yy; int src = shuf ? (c&7)*64 + (c>>3) : c;
    tile[yy*65+xx] = in[(size_t)src*NT + p0+xx];
  }
  __syncthreads();
  for (int it=0; it<16; it++){
    int idx = t + it*256; int r = idx>>6, s = idx&63;     // r=p-local, s=c-local
    outp[(size_t)(p0+r)*512 + c0+s] = f2b(tile[s*65+r]);
  }
}

// ---------------------------------------------------------------------------
// Row-major (M x lda f32) -> MFMA-fragment-linear bf16:
// idx = ((MT*KSn + KS)*64 + lane)*8 + j ; A[m=MT*16+(lane&15)][k=KS*32+(lane>>4)*8+j]
__global__ void k_cvt_wfrag(const float* __restrict__ w, int lda, int KSn,
                            unsigned short* __restrict__ outp){
  int tid = blockIdx.x*256 + threadIdx.x;
  int lane = tid & 63;
  int tmp = tid >> 6;
  int KS = tmp % KSn, MT = tmp / KSn;
  int m = MT*16 + (lane&15);
  int k = KS*32 + (lane>>4)*8;
  const float* p = w + (size_t)m*lda + k;
  float4 a = *(const float4*)p, b = *(const float4*)(p+4);
  unsigned short o[8] = { f2b(a.x),f2b(a.y),f2b(a.z),f2b(a.w),
                          f2b(b.x),f2b(b.y),f2b(b.z),f2b(b.w) };
  *(int4*)(outp + (size_t)tid*8) = *(int4*)o;
}

// ---------------------------------------------------------------------------
typedef __attribute__((ext_vector_type(8))) short bf16x8;
typedef __attribute__((ext_vector_type(4))) float f32x4;

// conv3x3 via bf16 MFMA 16x16x32. grid (32,4,8), block 256 = 4 waves (2x2).
__launch_bounds__(256)
__global__ void k_conv_mfma(const unsigned short* __restrict__ Wf,
                            const unsigned short* __restrict__ Bb,
                            float* __restrict__ outp){
  __shared__ unsigned short Bs[128*40];
  int t = threadIdx.x;
  int n0 = blockIdx.x*128, m0y = blockIdx.y;
  int kz = blockIdx.z;                          // K slice: 1152, 36 steps
  int w = t>>6, lane = t&63;
  int wm = (w>>1)*64, wn = (w&1)*64;
  int ln15 = lane&15, lhi = lane>>4;
  f32x4 acc[4][4] = {};
  int sn = t & 127, kh = t>>7;
  int p = n0 + sn, py = p>>6, px = p&63;

  for (int ks=0; ks<36; ks++){
    unsigned short tmp[16];
    int kbase = kz*1152 + ks*32 + kh*16;
    #pragma unroll
    for (int j=0;j<16;j++){
      int ka = kbase + j;
      int c = ka/9; int t9 = ka - c*9; int qy = t9/3;
      int dy = qy-1, dx = t9 - qy*3 - 1;
      int yy = py+dy, xx = px+dx;
      tmp[j] = (yy>=0 && yy<64 && xx>=0 && xx<64) ? Bb[(size_t)c*4096 + yy*64 + xx]
                                                  : (unsigned short)0;
    }
    __syncthreads();
    *(int4*)&Bs[sn*40 + kh*16]     = *(int4*)&tmp[0];
    *(int4*)&Bs[sn*40 + kh*16 + 8] = *(int4*)&tmp[8];
    __syncthreads();
    bf16x8 af[4], bf[4];
    int KSab = kz*36 + ks;
    #pragma unroll
    for (int fm=0; fm<4; fm++){
      int MT = m0y*8 + (w>>1)*4 + fm;
      af[fm] = *(const bf16x8*)&Wf[((size_t)MT*288 + KSab)*512 + lane*8];
    }
    #pragma unroll
    for (int fn=0; fn<4; fn++)
      bf[fn] = *(const bf16x8*)&Bs[(wn + fn*16 + ln15)*40 + lhi*8];
    #pragma unroll
    for (int fm=0; fm<4; fm++)
      #pragma unroll
      for (int fn=0; fn<4; fn++)
        acc[fm][fn] = __builtin_amdgcn_mfma_f32_16x16x32_bf16(af[fm], bf[fn], acc[fm][fn], 0,0,0);
  }
  float* op = outp + (size_t)kz*512*4096;
  #pragma unroll
  for (int fm=0; fm<4; fm++){
    #pragma unroll
    for (int fn=0; fn<4; fn++){
      int col = n0 + wn + fn*16 + ln15;
      int rowb = m0y*128 + wm + fm*16 + lhi*4;
      #pragma unroll
      for (int r=0; r<4; r++)
        op[(size_t)(rowb+r)*4096 + col] = acc[fm][fn][r];
    }
  }
}

// ---------------------------------------------------------------------------
// NHWC bf16 B GEMM via MFMA: out[m][n] = epi(acc + bias) (+res).
// grid (32, M/128). KSTEPS = K/32. EPI 0 plain | 1 gelu | 4 +res.
template<int KSTEPS, int EPI>
__launch_bounds__(256)
__global__ void k_nhwc_mfma(const unsigned short* __restrict__ Wf,
                            const unsigned short* __restrict__ Bb, int ldb,
                            const float* __restrict__ bias,
                            const float* __restrict__ resf,
                            float* __restrict__ outp){
  __shared__ unsigned short Bs[128*40];
  int t = threadIdx.x;
  int n0 = blockIdx.x*128, m0y = blockIdx.y;
  int w = t>>6, lane = t&63;
  int wm = (w>>1)*64, wn = (w&1)*64;
  int ln15 = lane&15, lhi = lane>>4;
  f32x4 acc[4][4] = {};
  int sn = t & 127, kh = t>>7;

  for (int ks=0; ks<KSTEPS; ks++){
    const unsigned short* src = Bb + (size_t)(n0+sn)*ldb + ks*32 + kh*16;
    int4 v0 = *(const int4*)src;
    int4 v1 = *(const int4*)(src+8);
    __syncthreads();
    *(int4*)&Bs[sn*40 + kh*16]     = v0;
    *(int4*)&Bs[sn*40 + kh*16 + 8] = v1;
    __syncthreads();
    bf16x8 af[4], bf[4];
    #pragma unroll
    for (int fm=0; fm<4; fm++){
      int MT = m0y*8 + (w>>1)*4 + fm;
      af[fm] = *(const bf16x8*)&Wf[((size_t)MT*KSTEPS + ks)*512 + lane*8];
    }
    #pragma unroll
    for (int fn=0; fn<4; fn++)
      bf[fn] = *(const bf16x8*)&Bs[(wn + fn*16 + ln15)*40 + lhi*8];
    #pragma unroll
    for (int fm=0; fm<4; fm++)
      #pragma unroll
      for (int fn=0; fn<4; fn++)
        acc[fm][fn] = __builtin_amdgcn_mfma_f32_16x16x32_bf16(af[fm], bf[fn], acc[fm][fn], 0,0,0);
  }
  #pragma unroll
  for (int fm=0; fm<4; fm++){
    #pragma unroll
    for (int fn=0; fn<4; fn++){
      int col = n0 + wn + fn*16 + ln15;
      int rowb = m0y*128 + wm + fm*16 + lhi*4;
      #pragma unroll
      for (int r=0; r<4; r++){
        int m = rowb + r;
        float v = acc[fm][fn][r] + (bias ? bias[m] : 0.f);
        if (EPI==1) v = geluf(v);
        else if (EPI==4) v += resf[(size_t)m*4096 + col];
        outp[(size_t)m*4096 + col] = v;
      }
    }
  }
}

// ---------------------------------------------------------------------------
// Depthwise 3x3 conv (dilated), optional SiLU. grid = C*16, block 256.
template<int DIL, int ACT>
__global__ void k_dwconv(const float* __restrict__ in, const float* __restrict__ w,
                         const float* __restrict__ b, float* __restrict__ out){
  int bid = blockIdx.x;
  int c = bid >> 4, yb = bid & 15;
  int t = threadIdx.x;
  int y = yb*4 + (t>>6), x = t&63;
  const float* pin = in + (size_t)c*NT;
  float acc = b[c];
  #pragma unroll
  for (int ky=0; ky<3; ky++){
    int yy = y + DIL*(ky-1);
    if (yy<0 || yy>=64) continue;
    #pragma unroll
    for (int kx=0; kx<3; kx++){
      int xx = x + DIL*(kx-1);
      if (xx<0 || xx>=64) continue;
      acc += w[c*9 + ky*3 + kx] * pin[yy*64+xx];
    }
  }
  if (ACT==1) acc = acc * sigmf(acc);
  out[(size_t)c*NT + y*64 + x] = acc;
}

// ---------------------------------------------------------------------------
// Global LN: sum 8 split-K partials -> h, partial stats -> final -> apply(gelu)
__global__ void k_red_part8(const float* __restrict__ hp, float* __restrict__ h,
                            float* __restrict__ part){
  __shared__ float ls[256], lq[256];
  int t = threadIdx.x; size_t base = (size_t)blockIdx.x*4096 + t;
  const size_t SL = (size_t)512*4096;
  float s=0, q=0;
  #pragma unroll
  for (int i=0;i<16;i++){
    size_t idx = base + i*256;
    float v = 0.f;
    #pragma unroll
    for (int z=0; z<8; z++) v += hp[idx + z*SL];
    h[idx] = v; s+=v; q+=v*v;
  }
  ls[t]=s; lq[t]=q; __syncthreads();
  for (int off=128; off; off>>=1){ if (t<off){ ls[t]+=ls[t+off]; lq[t]+=lq[t+off]; } __syncthreads(); }
  if (t==0){ part[blockIdx.x] = ls[0]; part[512 + blockIdx.x] = lq[0]; }
}
__global__ void k_red_fin(const float* __restrict__ part, float* __restrict__ stats){
  __shared__ float ls[256], lq[256];
  int t = threadIdx.x;
  ls[t] = part[t] + part[t+256];
  lq[t] = part[512+t] + part[768+t];
  __syncthreads();
  for (int off=128; off; off>>=1){ if (t<off){ ls[t]+=ls[t+off]; lq[t]+=lq[t+off]; } __syncthreads(); }
  if (t==0){
    float mu = ls[0] * (1.f/2097152.f);
    float var = lq[0]*(1.f/2097152.f) - mu*mu;
    stats[0]=mu; stats[1]=rsqrtf(var + 1e-5f);
  }
}
__global__ void k_ln_gelu(const float* __restrict__ h, const float* __restrict__ g,
                          const float* __restrict__ b, const float* __restrict__ stats,
                          float* __restrict__ out){
  size_t idx = ((size_t)blockIdx.x*256 + threadIdx.x)*4;
  float mu = stats[0], rs = stats[1];
  float4 hv = *(const float4*)(h + idx);
  float4 gv = *(const float4*)(g + idx);
  float4 bv = *(const float4*)(b + idx);
  float4 o;
  o.x = geluf((hv.x-mu)*rs*gv.x+bv.x);
  o.y = geluf((hv.y-mu)*rs*gv.y+bv.y);
  o.z = geluf((hv.z-mu)*rs*gv.z+bv.z);
  o.w = geluf((hv.w-mu)*rs*gv.w+bv.w);
  *(float4*)(out + idx) = o;
}

// ---------------------------------------------------------------------------
// Per-pixel LN over C=512 (stats), then apply+transpose to NHWC bf16 xnb(4096,512)
__global__ void k_ln1_stats(const float* __restrict__ fused, float* __restrict__ mu1,
                            float* __restrict__ rs1){
  __shared__ float ss[256], sq[256];
  int t = threadIdx.x; int ci = t>>6; int pj = t&63;
  int pos = blockIdx.x*64 + pj;
  float s=0,q=0;
  for (int c=ci; c<512; c+=4){ float v = fused[(size_t)c*NT + pos]; s+=v; q+=v*v; }
  ss[t]=s; sq[t]=q; __syncthreads();
  if (ci==0){
    float S = ss[pj]+ss[64+pj]+ss[128+pj]+ss[192+pj];
    float Q = sq[pj]+sq[64+pj]+sq[128+pj]+sq[192+pj];
    float mu = S*(1.f/512.f);
    mu1[pos]=mu; rs1[pos]=rsqrtf(Q*(1.f/512.f) - mu*mu + 1e-5f);
  }
}
__global__ void k_ln1_apply(const float* __restrict__ fused, const float* __restrict__ g,
                            const float* __restrict__ b, const float* __restrict__ mu1,
                            const float* __restrict__ rs1, unsigned short* __restrict__ xnb){
  __shared__ float tile[64*65];
  int t = threadIdx.x;
  int p0 = blockIdx.x*64, c0 = blockIdx.y*64;
  for (int it=0; it<16; it++){
    int idx = t + it*256; int yy = idx>>6, xx = idx&63;
    tile[yy*65+xx] = fused[(size_t)(c0+yy)*NT + p0+xx];
  }
  __syncthreads();
  for (int it=0; it<16; it++){
    int idx = t + it*256; int r = idx>>6, s = idx&63;
    float v = tile[s*65+r];
    int pos = p0+r, c = c0+s;
    xnb[(size_t)pos*512 + c] = f2b((v - mu1[pos])*rs1[pos]*g[c] + b[c]);
  }
}

// ---------------------------------------------------------------------------
// Per-channel 64x64 transpose: out[d][w*64+h] = in[d][h*64+w]. grid=1024.
__global__ void k_transpose64(const float* __restrict__ in, float* __restrict__ out){
  __shared__ float tile[64*65];
  int d = blockIdx.x; int t = threadIdx.x;
  const float* p = in + (size_t)d*NT; float* q = out + (size_t)d*NT;
  for (int it=0; it<16; it++){
    int idx = t+it*256; int yy = idx>>6, xx = idx&63;
    tile[yy*65+xx] = p[idx];
  }
  __syncthreads();
  for (int it=0; it<16; it++){
    int idx = t+it*256; int w = idx>>6, hh = idx&63;
    q[idx] = tile[hh*65+w];
  }
}

// ---------------------------------------------------------------------------
__global__ void k_zero(float* __restrict__ p){
  size_t i = ((size_t)blockIdx.x*256 + threadIdx.x)*4;
  *(float4*)(p+i) = make_float4(0,0,0,0);
}

// ---------------------------------------------------------------------------
// Chunked selective scan, phase A, LDS-staged delta/u.
// grid = 64 (k,dblk) * NCH, block 256 (4 waves, 64 d).
__launch_bounds__(256)
__global__ void k_scan_part(const float* __restrict__ delta, const float* __restrict__ xc,
                            const float* __restrict__ xcT, const float* __restrict__ xdblT,
                            const float* __restrict__ A_logs,
                            float* __restrict__ Pbuf, float* __restrict__ Sbuf){
  __shared__ float dtile[64*36], utile[64*36];
  int bid = blockIdx.x;
  int c    = bid % NCH;
  int rest = bid / NCH;
  int k    = rest >> 4;
  int dblk = rest & 15;
  int t = threadIdx.x;
  int w = t>>6, lane = t&63;
  int dsub = lane & 15, ngrp = lane >> 4;
  int dd = w*16 + dsub;
  int d = dblk*64 + dd;
  int ld_dd = t>>2, q = t&3;
  const bool rv = (k>=2);
  const float* dprow = delta + ((size_t)(k*1024 + dblk*64 + ld_dd))*NT;
  const float* uprow = ((k&1)? xcT : xc) + (size_t)(dblk*64 + ld_dd)*NT;
  const float* bc = xdblT + (size_t)k*NT*64;
  float A[4], S[4]={0,0,0,0}, P[4]={1.f,1.f,1.f,1.f};
  #pragma unroll
  for (int j=0;j<4;j++) A[j] = -__expf(A_logs[(size_t)(k*1024+d)*16 + ngrp*4 + j]);
  int base = c*CHL;
  for (int l0=0; l0<CHL; l0+=32){
    int L0 = base + l0;
    __syncthreads();
    {
      const float* dp8 = dprow + L0 + q*8;
      float4 a0 = *(const float4*)dp8, a1 = *(const float4*)(dp8+4);
      *(float4*)&dtile[ld_dd*36 + q*8]     = a0;
      *(float4*)&dtile[ld_dd*36 + q*8 + 4] = a1;
      int us = rv ? (4064 - L0) : L0;
      const float* up8 = uprow + us + q*8;
      float4 b0 = *(const float4*)up8, b1 = *(const float4*)(up8+4);
      *(float4*)&utile[ld_dd*36 + q*8]     = b0;
      *(float4*)&utile[ld_dd*36 + q*8 + 4] = b1;
    }
    __syncthreads();
    for (int s=0; s<32; s++){
      int l = L0 + s;
      float dt = dtile[dd*36 + s];
      float u  = utile[dd*36 + (rv ? 31-s : s)];
      float4 B4 = *(const float4*)(bc + (size_t)l*64 + 32 + ngrp*4);
      float xbu = dt*u;
      float Bv[4]={B4.x,B4.y,B4.z,B4.w};
      #pragma unroll
      for (int j=0;j<4;j++){
        float dA = __expf(dt*A[j]);
        S[j] = dA*S[j] + xbu*Bv[j];
        P[j] *= dA;
      }
    }
  }
  size_t o = ((size_t)(k*1024+d)*NCH + c)*16 + ngrp*4;
  *(float4*)&Pbuf[o] = make_float4(P[0],P[1],P[2],P[3]);
  *(float4*)&Sbuf[o] = make_float4(S[0],S[1],S[2],S[3]);
}

// ---------------------------------------------------------------------------
// Phase B: serial combine over chunks. grid=256, block=256.
__global__ void k_scan_comb(const float* __restrict__ Pbuf, const float* __restrict__ Sbuf,
                            float* __restrict__ Hbuf){
  int tid = blockIdx.x*256 + threadIdx.x;
  int scan = tid >> 4, n = tid & 15;
  size_t base = (size_t)scan*(NCH*16) + n;
  float h = 0.f;
  #pragma unroll
  for (int c=0;c<NCH;c++){
    Hbuf[base + c*16] = h;
    h = Pbuf[base + c*16]*h + Sbuf[base + c*16];
  }
}

// ---------------------------------------------------------------------------
// Phase C: re-run chunk from h_in, compute y, atomicAdd. LDS-staged delta/u.
__launch_bounds__(256)
__global__ void k_scan_fin(const float* __restrict__ delta, const float* __restrict__ xc,
                           const float* __restrict__ xcT, const float* __restrict__ xdblT,
                           const float* __restrict__ A_logs, const float* __restrict__ Ds,
                           const float* __restrict__ Hbuf, float* __restrict__ ycomb){
  __shared__ float dtile[64*36], utile[64*36];
  int bid = blockIdx.x;
  int c    = bid % NCH;
  int rest = bid / NCH;
  int k    = rest >> 4;
  int dblk = rest & 15;
  int t = threadIdx.x;
  int w = t>>6, lane = t&63;
  int dsub = lane & 15, ngrp = lane >> 4;
  int dd = w*16 + dsub;
  int d = dblk*64 + dd;
  int ld_dd = t>>2, q = t&3;
  const bool rv = (k>=2);
  const float* dprow = delta + ((size_t)(k*1024 + dblk*64 + ld_dd))*NT;
  const float* uprow = ((k&1)? xcT : xc) + (size_t)(dblk*64 + ld_dd)*NT;
  const float* bc = xdblT + (size_t)k*NT*64;
  float A[4], h[4];
  #pragma unroll
  for (int j=0;j<4;j++) A[j] = -__expf(A_logs[(size_t)(k*1024+d)*16 + ngrp*4 + j]);
  {
    size_t o = ((size_t)(k*1024+d)*NCH + c)*16 + ngrp*4;
    float4 h4 = *(const float4*)&Hbuf[o];
    h[0]=h4.x; h[1]=h4.y; h[2]=h4.z; h[3]=h4.w;
  }
  float Dv = Ds[k*1024+d];
  int base = c*CHL;
  for (int l0=0; l0<CHL; l0+=32){
    int L0 = base + l0;
    __syncthreads();
    {
      const float* dp8 = dprow + L0 + q*8;
      float4 a0 = *(const float4*)dp8, a1 = *(const float4*)(dp8+4);
      *(float4*)&dtile[ld_dd*36 + q*8]     = a0;
      *(float4*)&dtile[ld_dd*36 + q*8 + 4] = a1;
      int us = rv ? (4064 - L0) : L0;
      const float* up8 = uprow + us + q*8;
      float4 b0 = *(const float4*)up8, b1 = *(const float4*)(up8+4);
      *(float4*)&utile[ld_dd*36 + q*8]     = b0;
      *(float4*)&utile[ld_dd*36 + q*8 + 4] = b1;
    }
    __syncthreads();
    for (int s=0; s<32; s++){
      int l = L0 + s;
      float dt = dtile[dd*36 + s];
      float u  = utile[dd*36 + (rv ? 31-s : s)];
      float4 B4 = *(const float4*)(bc + (size_t)l*64 + 32 + ngrp*4);
      float4 C4 = *(const float4*)(bc + (size_t)l*64 + 48 + ngrp*4);
      float xbu = dt*u;
      float Bv[4]={B4.x,B4.y,B4.z,B4.w}, Cv[4]={C4.x,C4.y,C4.z,C4.w};
      float ys = 0.f;
      #pragma unroll
      for (int j=0;j<4;j++){
        float dA = __expf(dt*A[j]);
        h[j] = dA*h[j] + xbu*Bv[j];
        ys += h[j]*Cv[j];
      }
      ys += __shfl_xor(ys, 16);
      ys += __shfl_xor(ys, 32);
      if (ngrp==0){
        int pos;
        if (k==0) pos = l;
        else if (k==1) pos = ((l&63)<<6) | (l>>6);
        else if (k==2) pos = 4095-l;
        else { int tt = 4095-l; pos = ((tt&63)<<6) | (tt>>6); }
        atomicAdd(&ycomb[(size_t)pos*1024 + d], ys + Dv*u);
      }
    }
  }
}

// ---------------------------------------------------------------------------
// Combine: per-pixel LN over 1024 dirs-summed y, gate with silu(z),
// write yact as bf16 NHWC (feeds out_proj MFMA).
__global__ void k_combine(const float* __restrict__ ycomb, const float* __restrict__ xz,
                          const float* __restrict__ g, const float* __restrict__ b,
                          unsigned short* __restrict__ yactb){
  int pos = blockIdx.x, t = threadIdx.x;
  float v[4]; float s=0,q=0;
  #pragma unroll
  for (int i=0;i<4;i++){ v[i] = ycomb[(size_t)pos*1024 + t + i*256]; s+=v[i]; q+=v[i]*v[i]; }
  #pragma unroll
  for (int off=32; off>=1; off>>=1){ s += __shfl_xor(s,off); q += __shfl_xor(q,off); }
  __shared__ float red[8];
  int wid = t>>6;
  if ((t&63)==0){ red[wid*2]=s; red[wid*2+1]=q; }
  __syncthreads();
  float S = red[0]+red[2]+red[4]+red[6];
  float Q = red[1]+red[3]+red[5]+red[7];
  float mu = S*(1.f/1024.f), rs = rsqrtf(Q*(1.f/1024.f) - mu*mu + 1e-5f);
  #pragma unroll
  for (int i=0;i<4;i++){
    int dd = t + i*256;
    float z = xz[(size_t)(1024+dd)*NT + pos];
    float yv = (v[i]-mu)*rs*g[dd] + b[dd];
    yactb[(size_t)pos*1024 + dd] = f2b(yv * (z * sigmf(z)));
  }
}

// ---------------------------------------------------------------------------
// Final: out = avgblur3x3(attn) + fused, f32. grid=512*16.
__global__ void k_blur(const float* __restrict__ attn, const float* __restrict__ fused,
                       float* __restrict__ outp){
  int bid = blockIdx.x; int c = bid>>4, yb = bid&15; int t = threadIdx.x;
  int y = yb*4 + (t>>6), x = t&63;
  const float* p = attn + (size_t)c*NT;
  float s = 0;
  #pragma unroll
  for (int dy=-1; dy<=1; dy++){
    int yy = y+dy; if (yy<0||yy>=64) continue;
    #pragma unroll
    for (int dx=-1; dx<=1; dx++){
      int xx = x+dx; if (xx<0||xx>=64) continue;
      s += p[yy*64+xx];
    }
  }
  float val = s*(1.f/9.f) + fused[(size_t)c*NT + y*64 + x];
  outp[(size_t)c*NT + y*64 + x] = val;
}

// ---------------------------------------------------------------------------
extern "C" void kernel_launch(void* const* d_in, const int* in_sizes, int n_in,
                              void* d_out, int out_size, void* d_ws, size_t ws_size,
                              hipStream_t stream){
  const float* feat = (const float*)d_in[0];
  const float* lat  = (const float*)d_in[1];
  const float* fg_w1= (const float*)d_in[2];
  const float* fg_b1= (const float*)d_in[3];
  const float* fg_w2= (const float*)d_in[4];
  const float* fg_b2= (const float*)d_in[5];
  const float* fb_w1= (const float*)d_in[6];
  const float* ln_g = (const float*)d_in[7];
  const float* ln_b = (const float*)d_in[8];
  const float* dw_w = (const float*)d_in[9];
  const float* dw_b = (const float*)d_in[10];
  const float* pw1_w= (const float*)d_in[11];
  const float* pw1_b= (const float*)d_in[12];
  const float* pw2_w= (const float*)d_in[13];
  const float* pw2_b= (const float*)d_in[14];
  const float* ln1_g= (const float*)d_in[15];
  const float* ln1_b= (const float*)d_in[16];
  const float* inpw = (const float*)d_in[17];
  const float* dc_w = (const float*)d_in[18];
  const float* dc_b = (const float*)d_in[19];
  const float* xpw  = (const float*)d_in[20];
  const float* dtw  = (const float*)d_in[21];
  const float* dtb  = (const float*)d_in[22];
  const float* Alog = (const float*)d_in[23];
  const float* Dsp  = (const float*)d_in[24];
  const float* ong  = (const float*)d_in[25];
  const float* onb  = (const float*)d_in[26];
  const float* opw  = (const float*)d_in[27];
  float* outp = (float*)d_out;
  (void)in_sizes; (void)n_in; (void)out_size; (void)ws_size;

  // ---- workspace regions with reuse (sizes in floats) ------------------
  float* Wp = (float*)d_ws;
  size_t off = 0;
  auto alloc = [&](size_t n){ float* p = Wp + off; off += n; return p; };
  float* S0    = alloc((size_t)1024*NT);   // wf -> xnb -> (Pbuf/Sbuf) -> yactb
  float* S1    = alloc((size_t)512*NT);    // h -> h3 -> Hbuf -> attn
  float* P0    = alloc((size_t)512*NT);    // fused (persistent)
  float* P1    = alloc((size_t)2048*NT);   // h2 | wf_bf | w_frag -> xz
  float* P2    = alloc((size_t)1024*NT);   // h4 (front) -> xc
  float* P3    = alloc((size_t)1024*NT);   // xcT
  float* P4    = alloc((size_t)4*NT*64);   // xdblT
  float* P5    = alloc((size_t)4*1024*NT); // hpart -> pw frags/tiles -> w_frag2 -> delta -> w_frag3
  float* P6    = alloc((size_t)1024*NT);   // g1 (front) -> ycomb
  float* part  = alloc(1024);
  float* stats = alloc(4);
  float* mu1   = alloc(4096);
  float* rs1   = alloc(4096);
  // total ~47.2M floats = 189 MB

  float* wf    = S0;
  float* h     = S1;
  float* h2    = P1;                       // front 512*NT
  float* h3    = S1;
  float* h4    = P2;
  float* fused = P0;
  float* xz    = P1;
  float* xc    = P2;
  float* xcT   = P3;
  float* xdblT = P4;
  float* hpart = P5;                       // 8 planes x 512x4096 f32
  float* delta = P5;
  float* g1    = P6;
  float* ycomb = P6;
  float* attn  = S1;
  // bf16 staging
  unsigned short* wf_bf   = (unsigned short*)(P1 + (size_t)512*NT);   // conv B
  unsigned short* w_frag  = (unsigned short*)(P1 + (size_t)1024*NT);  // conv A frags
  unsigned short* xnb     = (unsigned short*)S0;                      // xn bf16 (4096x512)
  unsigned short* w_frag2 = (unsigned short*)P5;                      // in_proj A frags
  unsigned short* yactb   = (unsigned short*)S0;                      // yact bf16 (4096x1024)
  unsigned short* w_frag3 = (unsigned short*)P5;                      // out_proj A frags
  unsigned short* wfpw1   = (unsigned short*)P5;                      // pw1 A frags (512x512)
  unsigned short* wfpw2   = (unsigned short*)(P5 + (size_t)131072);   // pw2 A frags
  unsigned short* h3T     = (unsigned short*)(P5 + (size_t)1048576);  // h3 NHWC bf16
  unsigned short* h4T     = (unsigned short*)(P5 + (size_t)2097152);  // h4 NHWC bf16 (shuffled)
  // scan chunk buffers (after xnb dead at step 9):
  float* Pbuf  = S0;                       // 4096*NCH*16 = 2M floats
  float* Sbuf  = S0 + (size_t)2*1048576;   // 2M floats
  float* Hbuf  = S1;                       // 2M floats (h3 dead after step 6)

  // 1) g1 = gelu(fg1(concat))            M=32, K=1024
  hipLaunchKernelGGL((k_gemm<1,1,false>), dim3(64,1), dim3(256), 0, stream,
      32, 1024, 1024, 0, fg_w1, fg_b1, nullptr, feat, lat, 0,0, nullptr, g1);
  // 2) wf = concat * sigmoid(fg2(g1))    M=1024, K=32
  hipLaunchKernelGGL((k_gemm<0,5,false>), dim3(64,16), dim3(256), 0, stream,
      1024, 32, 32, 0, fg_w2, fg_b2, g1, feat, lat, 0,0, nullptr, wf);
  // 3) conv3x3 via bf16 MFMA, split-K x8
  hipLaunchKernelGGL(k_cvt_bf16, dim3(2048), dim3(256), 0, stream, wf, wf_bf);
  hipLaunchKernelGGL(k_cvt_wfrag, dim3(2304), dim3(256), 0, stream, fb_w1, 9216, 288, w_frag);
  hipLaunchKernelGGL(k_conv_mfma, dim3(32,4,8), dim3(256), 0, stream, w_frag, wf_bf, hpart);
  // 4) h = sum(hpart) ; h2 = gelu(LN_global(h))
  hipLaunchKernelGGL(k_red_part8, dim3(512), dim3(256), 0, stream, hpart, h, part);
  hipLaunchKernelGGL(k_red_fin,  dim3(1),   dim3(256), 0, stream, part, stats);
  hipLaunchKernelGGL(k_ln_gelu,  dim3(2048),dim3(256), 0, stream, h, ln_g, ln_b, stats, h2);
  // 5) h3 = dwconv3x3 dil2(h2)
  hipLaunchKernelGGL((k_dwconv<2,0>), dim3(512*16), dim3(256), 0, stream, h2, dw_w, dw_b, h3);
  // 6) h4 = gelu(pw1(h3)) via bf16 MFMA
  hipLaunchKernelGGL(k_cvtT_bf16, dim3(64,8), dim3(256), 0, stream, h3, 0, h3T);
  hipLaunchKernelGGL(k_cvt_wfrag, dim3(128), dim3(256), 0, stream, pw1_w, 512, 16, wfpw1);
  hipLaunchKernelGGL((k_nhwc_mfma<16,1>), dim3(32,4), dim3(256), 0, stream,
      wfpw1, h3T, 512, pw1_b, nullptr, h4);
  // 7) fused = pw2(shuffle(h4)) + feature via bf16 MFMA
  hipLaunchKernelGGL(k_cvtT_bf16, dim3(64,8), dim3(256), 0, stream, h4, 1, h4T);
  hipLaunchKernelGGL(k_cvt_wfrag, dim3(128), dim3(256), 0, stream, pw2_w, 512, 16, wfpw2);
  hipLaunchKernelGGL((k_nhwc_mfma<16,4>), dim3(32,4), dim3(256), 0, stream,
      wfpw2, h4T, 512, pw2_b, feat, fused);
  // 8) xnb = LN_c(fused^T) bf16 (NHWC)
  hipLaunchKernelGGL(k_ln1_stats, dim3(64), dim3(256), 0, stream, fused, mu1, rs1);
  hipLaunchKernelGGL(k_ln1_apply, dim3(64,8), dim3(256), 0, stream, fused, ln1_g, ln1_b, mu1, rs1, xnb);
  // 9) xz = in_proj @ xn^T via bf16 MFMA
  hipLaunchKernelGGL(k_cvt_wfrag, dim3(512), dim3(256), 0, stream, inpw, 512, 16, w_frag2);
  hipLaunchKernelGGL((k_nhwc_mfma<16,0>), dim3(32,16), dim3(256), 0, stream,
      w_frag2, xnb, 512, nullptr, nullptr, xz);
  // 10) xc = silu(dwconv3x3(xp))
  hipLaunchKernelGGL((k_dwconv<1,1>), dim3(1024*16), dim3(256), 0, stream, xz, dc_w, dc_b, xc);
  // 11) xcT
  hipLaunchKernelGGL(k_transpose64, dim3(1024), dim3(256), 0, stream, xc, xcT);
  // 12) xdblT[k] batched: grid.z = direction
  hipLaunchKernelGGL((k_gemm<0,0,true,1>), dim3(64,1,4), dim3(256), 0, stream,
      64, 1024, 1024, 0, xpw, nullptr, xc, xcT, nullptr, 0,0, nullptr, xdblT);
  // 13) delta[k] batched: grid.z = direction
  hipLaunchKernelGGL((k_gemm<2,2,false,2>), dim3(64,16,4), dim3(256), 0, stream,
      1024, 32, 32, 64, dtw, dtb, xdblT, nullptr,nullptr, 0,0, nullptr, delta);
  // 14) ycomb = 0
  hipLaunchKernelGGL(k_zero, dim3(4096), dim3(256), 0, stream, ycomb);
  // 15) chunked selective scan: partial -> combine -> final (LDS-staged)
  hipLaunchKernelGGL(k_scan_part, dim3(64*NCH), dim3(256), 0, stream,
      delta, xc, xcT, xdblT, Alog, Pbuf, Sbuf);
  hipLaunchKernelGGL(k_scan_comb, dim3(256), dim3(256), 0, stream, Pbuf, Sbuf, Hbuf);
  hipLaunchKernelGGL(k_scan_fin, dim3(64*NCH), dim3(256), 0, stream,
      delta, xc, xcT, xdblT, Alog, Dsp, Hbuf, ycomb);
  // 16) yactb = out_norm(ycomb) * silu(z)  (bf16 NHWC)
  hipLaunchKernelGGL(k_combine, dim3(4096), dim3(256), 0, stream, ycomb, xz, ong, onb, yactb);
  // 17) attn = fused + yact @ out_proj^T via bf16 MFMA
  hipLaunchKernelGGL(k_cvt_wfrag, dim3(256), dim3(256), 0, stream, opw, 1024, 32, w_frag3);
  hipLaunchKernelGGL((k_nhwc_mfma<32,4>), dim3(32,4), dim3(256), 0, stream,
      w_frag3, yactb, 1024, nullptr, fused, attn);
  // 18) out = blur3x3(attn) + fused  -> f32
  hipLaunchKernelGGL(k_blur, dim3(512*16), dim3(256), 0, stream, attn, fused, outp);
}